// Round 1
// baseline (447.626 us; speedup 1.0000x reference)
//
#include <hip/hip_runtime.h>
#include <hip/hip_bf16.h>

#define NU 50000
#define NI 20000
#define NN 70000
#define DD 128
#define BB 8192
#define EE 500000
#define ET 570000   // EE + NN self loops
#define NTASK 16384 // 2*BB

// ---------------- GEMM: C[M,N] = A[M,K] * B[N,K]^T (+bias) (+relu) ----------------
__global__ __launch_bounds__(256) void gemm_bt_kernel(
    const float* __restrict__ A, const float* __restrict__ B,
    const float* __restrict__ bias, float* __restrict__ C,
    int M, int N, int K, int act) {
  const int BM = 64, BN = 64, BK = 16;
  __shared__ float As[BK][BM + 1];
  __shared__ float Bs[BK][BN + 1];
  int tid = threadIdx.x;
  int tx = tid & 15, ty = tid >> 4;
  int bm = blockIdx.x * BM, bn = blockIdx.y * BN;
  int lm = tid >> 2;          // 0..63
  int lk = (tid & 3) * 4;     // 0,4,8,12
  float acc[4][4] = {};
  for (int k0 = 0; k0 < K; k0 += BK) {
    {
      int row = bm + lm;
      float4 v = make_float4(0.f, 0.f, 0.f, 0.f);
      if (row < M) v = *reinterpret_cast<const float4*>(&A[(size_t)row * K + k0 + lk]);
      As[lk + 0][lm] = v.x; As[lk + 1][lm] = v.y; As[lk + 2][lm] = v.z; As[lk + 3][lm] = v.w;
    }
    {
      int row = bn + lm;
      float4 v = make_float4(0.f, 0.f, 0.f, 0.f);
      if (row < N) v = *reinterpret_cast<const float4*>(&B[(size_t)row * K + k0 + lk]);
      Bs[lk + 0][lm] = v.x; Bs[lk + 1][lm] = v.y; Bs[lk + 2][lm] = v.z; Bs[lk + 3][lm] = v.w;
    }
    __syncthreads();
#pragma unroll
    for (int k = 0; k < BK; k++) {
      float a[4], b[4];
#pragma unroll
      for (int i = 0; i < 4; i++) a[i] = As[k][ty * 4 + i];
#pragma unroll
      for (int j = 0; j < 4; j++) b[j] = Bs[k][tx * 4 + j];
#pragma unroll
      for (int i = 0; i < 4; i++)
#pragma unroll
        for (int j = 0; j < 4; j++) acc[i][j] += a[i] * b[j];
    }
    __syncthreads();
  }
#pragma unroll
  for (int i = 0; i < 4; i++) {
    int row = bm + ty * 4 + i;
    if (row >= M) continue;
#pragma unroll
    for (int j = 0; j < 4; j++) {
      int cn = bn + tx * 4 + j;
      if (cn >= N) continue;
      float v = acc[i][j];
      if (bias) v += bias[cn];
      if (act == 1) v = fmaxf(v, 0.f);
      C[(size_t)row * N + cn] = v;
    }
  }
}

// ---------------- small kernels ----------------
__global__ void winner_kernel(const int* __restrict__ iid, int* __restrict__ winner) {
  int b = blockIdx.x * 256 + threadIdx.x;
  if (b >= BB) return;
  atomicMax(&winner[iid[b]], b);
}

__global__ void build_xa_kernel(const int* __restrict__ uid, const int* __restrict__ iid,
                                const int* __restrict__ winner,
                                const float* __restrict__ uemb, const float* __restrict__ iemb,
                                const float* __restrict__ cemb,
                                float* __restrict__ Xa, int* __restrict__ map) {
  int t = blockIdx.x;
  int lane = threadIdx.x;  // 64
  int c4 = lane * 4;
  float4 v = make_float4(0.f, 0.f, 0.f, 0.f);
  int node;
  if (t < BB) {
    int u = uid[t];
    node = u;
    if (c4 < DD) v = *reinterpret_cast<const float4*>(&uemb[(size_t)u * DD + c4]);
  } else {
    int b = t - BB;
    int it = iid[b];
    node = NU + it;
    if (c4 < DD) {
      v = *reinterpret_cast<const float4*>(&iemb[(size_t)it * DD + c4]);
    } else {
      int wb = winner[it];
      v = *reinterpret_cast<const float4*>(&cemb[(size_t)wb * DD + (c4 - DD)]);
    }
  }
  *reinterpret_cast<float4*>(&Xa[(size_t)t * 256 + c4]) = v;
  if (lane == 0) map[node] = t;  // duplicate tasks have identical rows -> benign
}

__global__ void deg_kernel(const int* __restrict__ ei, int* __restrict__ deg) {
  int e = blockIdx.x * 256 + threadIdx.x;
  if (e >= ET) return;
  int dst = (e < EE) ? ei[EE + e] : (e - EE);
  atomicAdd(&deg[dst], 1);
}

__global__ void rowstart_kernel(const int* __restrict__ deg, int* __restrict__ rowstart,
                                int* __restrict__ fill, int* __restrict__ counter) {
  int v = blockIdx.x * 256 + threadIdx.x;
  if (v >= NN) return;
  int s = atomicAdd(counter, deg[v]);
  rowstart[v] = s;
  fill[v] = s;
}

__global__ void fill_kernel(const int* __restrict__ ei, int* __restrict__ fill,
                            int* __restrict__ col) {
  int e = blockIdx.x * 256 + threadIdx.x;
  if (e >= ET) return;
  int src, dst;
  if (e < EE) { src = ei[e]; dst = ei[EE + e]; }
  else { src = e - EE; dst = src; }
  int pos = atomicAdd(&fill[dst], 1);
  col[pos] = src;
}

__global__ void a1_kernel(const int* __restrict__ uid, const int* __restrict__ iid,
                          const float* __restrict__ Ha,
                          const float* __restrict__ atts, const float* __restrict__ attd,
                          float* __restrict__ a1s, float* __restrict__ a1d) {
  int t = blockIdx.x, lane = threadIdx.x;  // 64
  int v = (t < BB) ? uid[t] : NU + iid[t - BB];
  int head = lane >> 5, c = (lane & 31) * 4;
  float4 hv = *reinterpret_cast<const float4*>(&Ha[(size_t)t * 256 + head * DD + c]);
  float4 sv = *reinterpret_cast<const float4*>(&atts[head * DD + c]);
  float4 dv = *reinterpret_cast<const float4*>(&attd[head * DD + c]);
  float ps = hv.x * sv.x + hv.y * sv.y + hv.z * sv.z + hv.w * sv.w;
  float pd = hv.x * dv.x + hv.y * dv.y + hv.z * dv.z + hv.w * dv.w;
  for (int o = 1; o < 32; o <<= 1) { ps += __shfl_xor(ps, o); pd += __shfl_xor(pd, o); }
  if ((lane & 31) == 0) {
    a1s[(size_t)v * 2 + head] = ps;
    a1d[(size_t)v * 2 + head] = pd;
  }
}

__device__ __forceinline__ float lrelu(float x) { return x > 0.f ? x : 0.2f * x; }

__global__ void conv1_agg_kernel(const int* __restrict__ col, const int* __restrict__ rowstart,
                                 const int* __restrict__ deg, const float* __restrict__ Ha,
                                 const int* __restrict__ map,
                                 const float* __restrict__ a1s, const float* __restrict__ a1d,
                                 const float* __restrict__ bias, float* __restrict__ x1) {
  int v = blockIdx.x;
  int lane = threadIdx.x;  // 64
  int d = deg[v], s0 = rowstart[v];
  float ad0 = a1d[(size_t)v * 2 + 0], ad1 = a1d[(size_t)v * 2 + 1];
  float m0 = -1e30f, m1 = -1e30f;
  for (int i = 0; i < d; i++) {
    int s = col[s0 + i];
    float as0 = a1s[(size_t)s * 2 + 0], as1 = a1s[(size_t)s * 2 + 1];
    m0 = fmaxf(m0, lrelu(as0 + ad0));
    m1 = fmaxf(m1, lrelu(as1 + ad1));
  }
  int head = lane >> 5;
  float m = head ? m1 : m0;
  float ad = head ? ad1 : ad0;
  float denom = 0.f;
  float4 acc = make_float4(0.f, 0.f, 0.f, 0.f);
  for (int i = 0; i < d; i++) {
    int s = col[s0 + i];
    float as = a1s[(size_t)s * 2 + head];
    float ex = __expf(0.f);  // placeholder avoided; compute properly below
    float al = lrelu(as + ad);
    ex = expf(al - m);
    denom += ex;
    int r = map[s];
    if (r >= 0) {
      float4 hv = *reinterpret_cast<const float4*>(&Ha[((size_t)r << 8) + (lane << 2)]);
      acc.x += ex * hv.x; acc.y += ex * hv.y; acc.z += ex * hv.z; acc.w += ex * hv.w;
    }
  }
  float inv = 1.f / denom;
  float4 b4 = *reinterpret_cast<const float4*>(&bias[lane << 2]);
  float4 o;
  o.x = acc.x * inv + b4.x;
  o.y = acc.y * inv + b4.y;
  o.z = acc.z * inv + b4.z;
  o.w = acc.w * inv + b4.w;
  // elu
  o.x = o.x > 0.f ? o.x : expm1f(o.x);
  o.y = o.y > 0.f ? o.y : expm1f(o.y);
  o.z = o.z > 0.f ? o.z : expm1f(o.z);
  o.w = o.w > 0.f ? o.w : expm1f(o.w);
  *reinterpret_cast<float4*>(&x1[((size_t)v << 8) + (lane << 2)]) = o;
}

__global__ void a2_kernel(const float* __restrict__ h2, const float* __restrict__ atts,
                          const float* __restrict__ attd,
                          float* __restrict__ a2s, float* __restrict__ a2d) {
  int v = blockIdx.x, lane = threadIdx.x;  // 64
  float2 hv = *reinterpret_cast<const float2*>(&h2[((size_t)v << 7) + (lane << 1)]);
  float2 sv = *reinterpret_cast<const float2*>(&atts[lane << 1]);
  float2 dv = *reinterpret_cast<const float2*>(&attd[lane << 1]);
  float ps = hv.x * sv.x + hv.y * sv.y;
  float pd = hv.x * dv.x + hv.y * dv.y;
  for (int o = 1; o < 64; o <<= 1) { ps += __shfl_xor(ps, o); pd += __shfl_xor(pd, o); }
  if (lane == 0) { a2s[v] = ps; a2d[v] = pd; }
}

__global__ void conv2_agg_kernel(const int* __restrict__ uid, const int* __restrict__ iid,
                                 const int* __restrict__ col, const int* __restrict__ rowstart,
                                 const int* __restrict__ deg, const float* __restrict__ h2,
                                 const float* __restrict__ a2s, const float* __restrict__ a2d,
                                 const float* __restrict__ bias, float* __restrict__ out2) {
  int t = blockIdx.x, lane = threadIdx.x;  // 64
  int v = (t < BB) ? uid[t] : NU + iid[t - BB];
  int d = deg[v], s0 = rowstart[v];
  float ad = a2d[v];
  float m = -1e30f;
  for (int i = 0; i < d; i++) m = fmaxf(m, lrelu(a2s[col[s0 + i]] + ad));
  float denom = 0.f;
  float2 acc = make_float2(0.f, 0.f);
  for (int i = 0; i < d; i++) {
    int s = col[s0 + i];
    float ex = expf(lrelu(a2s[s] + ad) - m);
    denom += ex;
    float2 hv = *reinterpret_cast<const float2*>(&h2[((size_t)s << 7) + (lane << 1)]);
    acc.x += ex * hv.x;
    acc.y += ex * hv.y;
  }
  float inv = 1.f / denom;
  float2 o;
  o.x = acc.x * inv + bias[lane * 2];
  o.y = acc.y * inv + bias[lane * 2 + 1];
  *reinterpret_cast<float2*>(&out2[((size_t)v << 7) + (lane << 1)]) = o;
}

__global__ void combined_kernel(const int* __restrict__ uid, const int* __restrict__ iid,
                                const float* __restrict__ uemb, const float* __restrict__ out2,
                                float* __restrict__ comb) {
  int idx = blockIdx.x * 256 + threadIdx.x;  // float4 index
  if (idx >= BB * 96) return;
  int b = idx / 96, c = idx % 96;
  int sec = c >> 5, off = (c & 31) * 4;
  float4 v;
  if (sec == 0) v = *reinterpret_cast<const float4*>(&uemb[(size_t)uid[b] * DD + off]);
  else if (sec == 1) v = *reinterpret_cast<const float4*>(&out2[(size_t)(NU + iid[b]) * DD + off]);
  else v = *reinterpret_cast<const float4*>(&out2[(size_t)uid[b] * DD + off]);
  *reinterpret_cast<float4*>(&comb[(size_t)b * 384 + c * 4]) = v;
}

__global__ void final_kernel(const float* __restrict__ ph, const float* __restrict__ w2,
                             const float* __restrict__ b2, float* __restrict__ out) {
  int b = blockIdx.x, lane = threadIdx.x;  // 64
  float2 hv = *reinterpret_cast<const float2*>(&ph[((size_t)b << 7) + (lane << 1)]);
  float2 wv = *reinterpret_cast<const float2*>(&w2[lane << 1]);
  float s = hv.x * wv.x + hv.y * wv.y;
  for (int o = 1; o < 64; o <<= 1) s += __shfl_xor(s, o);
  if (lane == 0) out[b] = s + b2[0];
}

// ---------------- launcher ----------------
extern "C" void kernel_launch(void* const* d_in, const int* in_sizes, int n_in,
                              void* d_out, int out_size, void* d_ws, size_t ws_size,
                              hipStream_t stream) {
  const int* uid = (const int*)d_in[0];
  const int* iid = (const int*)d_in[1];
  const float* content = (const float*)d_in[2];
  const int* ei = (const int*)d_in[3];
  const float* uemb = (const float*)d_in[4];
  const float* iemb = (const float*)d_in[5];
  const float* wc = (const float*)d_in[6];
  const float* bc = (const float*)d_in[7];
  const float* w1 = (const float*)d_in[8];
  const float* att1s = (const float*)d_in[9];
  const float* att1d = (const float*)d_in[10];
  const float* b1 = (const float*)d_in[11];
  const float* w2 = (const float*)d_in[12];
  const float* att2s = (const float*)d_in[13];
  const float* att2d = (const float*)d_in[14];
  const float* b2c = (const float*)d_in[15];
  const float* pw1 = (const float*)d_in[16];
  const float* pb1 = (const float*)d_in[17];
  const float* pw2 = (const float*)d_in[18];
  const float* pb2 = (const float*)d_in[19];
  float* out = (float*)d_out;
  char* ws = (char*)d_ws;

  size_t off = 0;
  auto alloc = [&](size_t bytes) {
    size_t o = off;
    off += (bytes + 255) & ~(size_t)255;
    return o;
  };
  size_t o_winner  = alloc(NI * 4);
  size_t o_map     = alloc(NN * 4);
  size_t o_a1s     = alloc((size_t)NN * 2 * 4);
  size_t o_a1d     = alloc((size_t)NN * 2 * 4);
  size_t o_deg     = alloc(NN * 4);
  size_t o_rs      = alloc(NN * 4);
  size_t o_fill    = alloc(NN * 4);
  size_t o_cnt     = alloc(4);
  size_t o_col     = alloc((size_t)ET * 4);
  size_t o_a2s     = alloc(NN * 4);
  size_t o_a2d     = alloc(NN * 4);
  // region R1: c_emb | Xa | Ha ; later reused for h2
  size_t o_r1      = alloc(4194304 + 16777216 + 16777216);
  size_t o_cemb = o_r1;
  size_t o_xa   = o_r1 + 4194304;
  size_t o_ha   = o_r1 + 4194304 + 16777216;
  size_t o_h2   = o_r1;  // aliases c_emb+Xa (dead by then)
  // region R2: x1 ; later reused for out2 | combined | pred_h
  size_t o_r2   = alloc((size_t)NN * 256 * 4);
  size_t o_x1   = o_r2;
  size_t o_out2 = o_r2;
  size_t o_comb = o_r2 + (size_t)NN * 128 * 4;
  size_t o_ph   = o_comb + (size_t)BB * 384 * 4;
  (void)ws_size; (void)in_sizes; (void)n_in; (void)out_size;

  int*   winner = (int*)(ws + o_winner);
  int*   map    = (int*)(ws + o_map);
  float* a1s    = (float*)(ws + o_a1s);
  float* a1d    = (float*)(ws + o_a1d);
  int*   deg    = (int*)(ws + o_deg);
  int*   rs     = (int*)(ws + o_rs);
  int*   fill   = (int*)(ws + o_fill);
  int*   cnt    = (int*)(ws + o_cnt);
  int*   col    = (int*)(ws + o_col);
  float* a2s    = (float*)(ws + o_a2s);
  float* a2d    = (float*)(ws + o_a2d);
  float* cemb   = (float*)(ws + o_cemb);
  float* Xa     = (float*)(ws + o_xa);
  float* Ha     = (float*)(ws + o_ha);
  float* h2     = (float*)(ws + o_h2);
  float* x1     = (float*)(ws + o_x1);
  float* out2   = (float*)(ws + o_out2);
  float* comb   = (float*)(ws + o_comb);
  float* ph     = (float*)(ws + o_ph);

  hipMemsetAsync(winner, 0xFF, NI * 4, stream);
  hipMemsetAsync(map, 0xFF, NN * 4, stream);
  hipMemsetAsync(a1s, 0, (size_t)NN * 2 * 4, stream);
  hipMemsetAsync(a1d, 0, (size_t)NN * 2 * 4, stream);
  hipMemsetAsync(deg, 0, NN * 4, stream);
  hipMemsetAsync(cnt, 0, 4, stream);

  winner_kernel<<<(BB + 255) / 256, 256, 0, stream>>>(iid, winner);
  // c_emb = content @ Wc^T + bc
  {
    dim3 g((BB + 63) / 64, (DD + 63) / 64);
    gemm_bt_kernel<<<g, 256, 0, stream>>>(content, wc, bc, cemb, BB, DD, 512, 0);
  }
  build_xa_kernel<<<NTASK, 64, 0, stream>>>(uid, iid, winner, uemb, iemb, cemb, Xa, map);
  deg_kernel<<<(ET + 255) / 256, 256, 0, stream>>>(ei, deg);
  rowstart_kernel<<<(NN + 255) / 256, 256, 0, stream>>>(deg, rs, fill, cnt);
  fill_kernel<<<(ET + 255) / 256, 256, 0, stream>>>(ei, fill, col);
  // Ha = Xa @ W1^T
  {
    dim3 g((NTASK + 63) / 64, (256 + 63) / 64);
    gemm_bt_kernel<<<g, 256, 0, stream>>>(Xa, w1, nullptr, Ha, NTASK, 256, 256, 0);
  }
  a1_kernel<<<NTASK, 64, 0, stream>>>(uid, iid, Ha, att1s, att1d, a1s, a1d);
  conv1_agg_kernel<<<NN, 64, 0, stream>>>(col, rs, deg, Ha, map, a1s, a1d, b1, x1);
  // h2 = x1 @ W2^T
  {
    dim3 g((NN + 63) / 64, (DD + 63) / 64);
    gemm_bt_kernel<<<g, 256, 0, stream>>>(x1, w2, nullptr, h2, NN, DD, 256, 0);
  }
  a2_kernel<<<NN, 64, 0, stream>>>(h2, att2s, att2d, a2s, a2d);
  conv2_agg_kernel<<<NTASK, 64, 0, stream>>>(uid, iid, col, rs, deg, h2, a2s, a2d, b2c, out2);
  combined_kernel<<<(BB * 96 + 255) / 256, 256, 0, stream>>>(uid, iid, uemb, out2, comb);
  // ph = relu(comb @ pw1^T + pb1)
  {
    dim3 g((BB + 63) / 64, (DD + 63) / 64);
    gemm_bt_kernel<<<g, 256, 0, stream>>>(comb, pw1, pb1, ph, BB, DD, 384, 1);
  }
  final_kernel<<<BB, 64, 0, stream>>>(ph, pw2, pb2, out);
}

// Round 2
// 353.849 us; speedup vs baseline: 1.2650x; 1.2650x over previous
//
#include <hip/hip_runtime.h>
#include <hip/hip_bf16.h>

#define NU 50000
#define NI 20000
#define NN 70000
#define DD 128
#define BB 8192
#define EE 500000
#define ET 570000   // EE + NN self loops
#define NTASK 16384 // 2*BB

// ---------------- GEMM: C[M,N] = A[M,K] * B[N,K]^T (+bias) (+relu) ----------------
// LDS pad +4 => rows 16B-aligned => fragment reads are ds_read_b128.
__global__ __launch_bounds__(256) void gemm_bt_kernel(
    const float* __restrict__ A, const float* __restrict__ B,
    const float* __restrict__ bias, float* __restrict__ C,
    int M, int N, int K, int act) {
  const int BM = 64, BN = 64, BK = 16;
  __shared__ float As[BK][BM + 4];
  __shared__ float Bs[BK][BN + 4];
  int tid = threadIdx.x;
  int tx = tid & 15, ty = tid >> 4;
  int bm = blockIdx.x * BM, bn = blockIdx.y * BN;
  int lm = tid >> 2;          // 0..63
  int lk = (tid & 3) * 4;     // 0,4,8,12
  float acc[4][4] = {};
  for (int k0 = 0; k0 < K; k0 += BK) {
    {
      int row = bm + lm;
      float4 v = make_float4(0.f, 0.f, 0.f, 0.f);
      if (row < M) v = *reinterpret_cast<const float4*>(&A[(size_t)row * K + k0 + lk]);
      As[lk + 0][lm] = v.x; As[lk + 1][lm] = v.y; As[lk + 2][lm] = v.z; As[lk + 3][lm] = v.w;
    }
    {
      int row = bn + lm;
      float4 v = make_float4(0.f, 0.f, 0.f, 0.f);
      if (row < N) v = *reinterpret_cast<const float4*>(&B[(size_t)row * K + k0 + lk]);
      Bs[lk + 0][lm] = v.x; Bs[lk + 1][lm] = v.y; Bs[lk + 2][lm] = v.z; Bs[lk + 3][lm] = v.w;
    }
    __syncthreads();
#pragma unroll
    for (int k = 0; k < BK; k++) {
      float4 a4 = *reinterpret_cast<const float4*>(&As[k][ty * 4]);
      float4 b4 = *reinterpret_cast<const float4*>(&Bs[k][tx * 4]);
      float a[4] = {a4.x, a4.y, a4.z, a4.w};
      float b[4] = {b4.x, b4.y, b4.z, b4.w};
#pragma unroll
      for (int i = 0; i < 4; i++)
#pragma unroll
        for (int j = 0; j < 4; j++) acc[i][j] += a[i] * b[j];
    }
    __syncthreads();
  }
#pragma unroll
  for (int i = 0; i < 4; i++) {
    int row = bm + ty * 4 + i;
    if (row >= M) continue;
#pragma unroll
    for (int j = 0; j < 4; j++) {
      int cn = bn + tx * 4 + j;
      if (cn >= N) continue;
      float v = acc[i][j];
      if (bias) v += bias[cn];
      if (act == 1) v = fmaxf(v, 0.f);
      C[(size_t)row * N + cn] = v;
    }
  }
}

// ---------------- small kernels ----------------
__global__ void winner_kernel(const int* __restrict__ iid, int* __restrict__ winner) {
  int b = blockIdx.x * 256 + threadIdx.x;
  if (b >= BB) return;
  atomicMax(&winner[iid[b]], b);
}

__global__ void build_xa_kernel(const int* __restrict__ uid, const int* __restrict__ iid,
                                const int* __restrict__ winner,
                                const float* __restrict__ uemb, const float* __restrict__ iemb,
                                const float* __restrict__ cemb,
                                float* __restrict__ Xa, int* __restrict__ map) {
  int t = blockIdx.x;
  int lane = threadIdx.x;  // 64
  int c4 = lane * 4;
  float4 v = make_float4(0.f, 0.f, 0.f, 0.f);
  int node;
  if (t < BB) {
    int u = uid[t];
    node = u;
    if (c4 < DD) v = *reinterpret_cast<const float4*>(&uemb[(size_t)u * DD + c4]);
  } else {
    int b = t - BB;
    int it = iid[b];
    node = NU + it;
    if (c4 < DD) {
      v = *reinterpret_cast<const float4*>(&iemb[(size_t)it * DD + c4]);
    } else {
      int wb = winner[it];
      v = *reinterpret_cast<const float4*>(&cemb[(size_t)wb * DD + (c4 - DD)]);
    }
  }
  *reinterpret_cast<float4*>(&Xa[(size_t)t * 256 + c4]) = v;
  if (lane == 0) map[node] = t;  // duplicate tasks have identical rows -> benign
}

__global__ void deg_kernel(const int* __restrict__ ei, int* __restrict__ deg) {
  int e = blockIdx.x * 256 + threadIdx.x;
  if (e >= ET) return;
  int dst = (e < EE) ? ei[EE + e] : (e - EE);
  atomicAdd(&deg[dst], 1);
}

__global__ void rowstart_kernel(const int* __restrict__ deg, int* __restrict__ rowstart,
                                int* __restrict__ fill, int* __restrict__ counter) {
  int v = blockIdx.x * 256 + threadIdx.x;
  if (v >= NN) return;
  int s = atomicAdd(counter, deg[v]);
  rowstart[v] = s;
  fill[v] = s;
}

__global__ void fill_kernel(const int* __restrict__ ei, int* __restrict__ fill,
                            int* __restrict__ col) {
  int e = blockIdx.x * 256 + threadIdx.x;
  if (e >= ET) return;
  int src, dst;
  if (e < EE) { src = ei[e]; dst = ei[EE + e]; }
  else { src = e - EE; dst = src; }
  int pos = atomicAdd(&fill[dst], 1);
  col[pos] = src;
}

__global__ void a1_kernel(const int* __restrict__ uid, const int* __restrict__ iid,
                          const float* __restrict__ Ha,
                          const float* __restrict__ atts, const float* __restrict__ attd,
                          float* __restrict__ a1s, float* __restrict__ a1d) {
  int t = blockIdx.x, lane = threadIdx.x;  // 64
  int v = (t < BB) ? uid[t] : NU + iid[t - BB];
  int head = lane >> 5, c = (lane & 31) * 4;
  float4 hv = *reinterpret_cast<const float4*>(&Ha[(size_t)t * 256 + head * DD + c]);
  float4 sv = *reinterpret_cast<const float4*>(&atts[head * DD + c]);
  float4 dv = *reinterpret_cast<const float4*>(&attd[head * DD + c]);
  float ps = hv.x * sv.x + hv.y * sv.y + hv.z * sv.z + hv.w * sv.w;
  float pd = hv.x * dv.x + hv.y * dv.y + hv.z * dv.z + hv.w * dv.w;
  for (int o = 1; o < 32; o <<= 1) { ps += __shfl_xor(ps, o); pd += __shfl_xor(pd, o); }
  if ((lane & 31) == 0) {
    a1s[(size_t)v * 2 + head] = ps;
    a1d[(size_t)v * 2 + head] = pd;
  }
}

__device__ __forceinline__ float lrelu(float x) { return x > 0.f ? x : 0.2f * x; }

__global__ void conv1_agg_kernel(const int* __restrict__ col, const int* __restrict__ rowstart,
                                 const int* __restrict__ deg, const float* __restrict__ Ha,
                                 const int* __restrict__ map,
                                 const float* __restrict__ a1s, const float* __restrict__ a1d,
                                 const float* __restrict__ bias, float* __restrict__ x1) {
  int v = blockIdx.x;
  int lane = threadIdx.x;  // 64
  int d = deg[v], s0 = rowstart[v];
  float ad0 = a1d[(size_t)v * 2 + 0], ad1 = a1d[(size_t)v * 2 + 1];
  float m0 = -1e30f, m1 = -1e30f;
  for (int i = 0; i < d; i++) {
    int s = col[s0 + i];
    float as0 = a1s[(size_t)s * 2 + 0], as1 = a1s[(size_t)s * 2 + 1];
    m0 = fmaxf(m0, lrelu(as0 + ad0));
    m1 = fmaxf(m1, lrelu(as1 + ad1));
  }
  int head = lane >> 5;
  float m = head ? m1 : m0;
  float ad = head ? ad1 : ad0;
  float denom = 0.f;
  float4 acc = make_float4(0.f, 0.f, 0.f, 0.f);
  for (int i = 0; i < d; i++) {
    int s = col[s0 + i];
    float as = a1s[(size_t)s * 2 + head];
    float ex = expf(lrelu(as + ad) - m);
    denom += ex;
    int r = map[s];
    if (r >= 0) {
      float4 hv = *reinterpret_cast<const float4*>(&Ha[((size_t)r << 8) + (lane << 2)]);
      acc.x += ex * hv.x; acc.y += ex * hv.y; acc.z += ex * hv.z; acc.w += ex * hv.w;
    }
  }
  float inv = 1.f / denom;
  float4 b4 = *reinterpret_cast<const float4*>(&bias[lane << 2]);
  float4 o;
  o.x = acc.x * inv + b4.x;
  o.y = acc.y * inv + b4.y;
  o.z = acc.z * inv + b4.z;
  o.w = acc.w * inv + b4.w;
  // elu
  o.x = o.x > 0.f ? o.x : expm1f(o.x);
  o.y = o.y > 0.f ? o.y : expm1f(o.y);
  o.z = o.z > 0.f ? o.z : expm1f(o.z);
  o.w = o.w > 0.f ? o.w : expm1f(o.w);
  *reinterpret_cast<float4*>(&x1[((size_t)v << 8) + (lane << 2)]) = o;
}

// q_s = W2^T att2_src, q_d = W2^T att2_dst  (256 each). One block, 256 threads.
__global__ void qvec_kernel(const float* __restrict__ w2, const float* __restrict__ atts,
                            const float* __restrict__ attd,
                            float* __restrict__ qs, float* __restrict__ qd) {
  int k = threadIdx.x;  // 0..255
  float s = 0.f, d = 0.f;
#pragma unroll 4
  for (int j = 0; j < DD; j++) {
    float w = w2[(size_t)j * 256 + k];
    s += atts[j] * w;
    d += attd[j] * w;
  }
  qs[k] = s;
  qd[k] = d;
}

// a2s[v] = x1[v].qs ; a2d[v] = x1[v].qd  for all nodes. 4 nodes per block (1 wave each).
__global__ __launch_bounds__(256) void a2x_kernel(const float* __restrict__ x1,
                                                  const float* __restrict__ qs,
                                                  const float* __restrict__ qd,
                                                  float* __restrict__ a2s, float* __restrict__ a2d) {
  int v = blockIdx.x * 4 + (threadIdx.x >> 6);
  if (v >= NN) return;
  int lane = threadIdx.x & 63;
  float4 xv = *reinterpret_cast<const float4*>(&x1[((size_t)v << 8) + (lane << 2)]);
  float4 sv = *reinterpret_cast<const float4*>(&qs[lane << 2]);
  float4 dv = *reinterpret_cast<const float4*>(&qd[lane << 2]);
  float ps = xv.x * sv.x + xv.y * sv.y + xv.z * sv.z + xv.w * sv.w;
  float pd = xv.x * dv.x + xv.y * dv.y + xv.z * dv.z + xv.w * dv.w;
  for (int o = 1; o < 64; o <<= 1) { ps += __shfl_xor(ps, o); pd += __shfl_xor(pd, o); }
  if (lane == 0) { a2s[v] = ps; a2d[v] = pd; }
}

// conv2 aggregation in x1-space (256-d), only for the 16384 batch tasks.
__global__ void conv2_aggx_kernel(const int* __restrict__ uid, const int* __restrict__ iid,
                                  const int* __restrict__ col, const int* __restrict__ rowstart,
                                  const int* __restrict__ deg, const float* __restrict__ x1,
                                  const float* __restrict__ a2s, const float* __restrict__ a2d,
                                  float* __restrict__ agg) {
  int t = blockIdx.x, lane = threadIdx.x;  // 64
  int v = (t < BB) ? uid[t] : NU + iid[t - BB];
  int d = deg[v], s0 = rowstart[v];
  float ad = a2d[v];
  float m = -1e30f;
  for (int i = 0; i < d; i++) m = fmaxf(m, lrelu(a2s[col[s0 + i]] + ad));
  float denom = 0.f;
  float4 acc = make_float4(0.f, 0.f, 0.f, 0.f);
  for (int i = 0; i < d; i++) {
    int s = col[s0 + i];
    float ex = expf(lrelu(a2s[s] + ad) - m);
    denom += ex;
    float4 hv = *reinterpret_cast<const float4*>(&x1[((size_t)s << 8) + (lane << 2)]);
    acc.x += ex * hv.x; acc.y += ex * hv.y; acc.z += ex * hv.z; acc.w += ex * hv.w;
  }
  float inv = 1.f / denom;
  float4 o = make_float4(acc.x * inv, acc.y * inv, acc.z * inv, acc.w * inv);
  *reinterpret_cast<float4*>(&agg[((size_t)t << 8) + (lane << 2)]) = o;
}

__global__ void combined_kernel(const int* __restrict__ uid,
                                const float* __restrict__ uemb, const float* __restrict__ out2c,
                                float* __restrict__ comb) {
  int idx = blockIdx.x * 256 + threadIdx.x;  // float4 index
  if (idx >= BB * 96) return;
  int b = idx / 96, c = idx % 96;
  int sec = c >> 5, off = (c & 31) * 4;
  float4 v;
  if (sec == 0) v = *reinterpret_cast<const float4*>(&uemb[(size_t)uid[b] * DD + off]);
  else if (sec == 1) v = *reinterpret_cast<const float4*>(&out2c[(size_t)(BB + b) * DD + off]);
  else v = *reinterpret_cast<const float4*>(&out2c[(size_t)b * DD + off]);
  *reinterpret_cast<float4*>(&comb[(size_t)b * 384 + c * 4]) = v;
}

__global__ void final_kernel(const float* __restrict__ ph, const float* __restrict__ w2,
                             const float* __restrict__ b2, float* __restrict__ out) {
  int b = blockIdx.x, lane = threadIdx.x;  // 64
  float2 hv = *reinterpret_cast<const float2*>(&ph[((size_t)b << 7) + (lane << 1)]);
  float2 wv = *reinterpret_cast<const float2*>(&w2[lane << 1]);
  float s = hv.x * wv.x + hv.y * wv.y;
  for (int o = 1; o < 64; o <<= 1) s += __shfl_xor(s, o);
  if (lane == 0) out[b] = s + b2[0];
}

// ---------------- launcher ----------------
extern "C" void kernel_launch(void* const* d_in, const int* in_sizes, int n_in,
                              void* d_out, int out_size, void* d_ws, size_t ws_size,
                              hipStream_t stream) {
  const int* uid = (const int*)d_in[0];
  const int* iid = (const int*)d_in[1];
  const float* content = (const float*)d_in[2];
  const int* ei = (const int*)d_in[3];
  const float* uemb = (const float*)d_in[4];
  const float* iemb = (const float*)d_in[5];
  const float* wc = (const float*)d_in[6];
  const float* bc = (const float*)d_in[7];
  const float* w1 = (const float*)d_in[8];
  const float* att1s = (const float*)d_in[9];
  const float* att1d = (const float*)d_in[10];
  const float* b1 = (const float*)d_in[11];
  const float* w2 = (const float*)d_in[12];
  const float* att2s = (const float*)d_in[13];
  const float* att2d = (const float*)d_in[14];
  const float* b2c = (const float*)d_in[15];
  const float* pw1 = (const float*)d_in[16];
  const float* pb1 = (const float*)d_in[17];
  const float* pw2 = (const float*)d_in[18];
  const float* pb2 = (const float*)d_in[19];
  float* out = (float*)d_out;
  char* ws = (char*)d_ws;

  size_t off = 0;
  auto alloc = [&](size_t bytes) {
    size_t o = off;
    off += (bytes + 255) & ~(size_t)255;
    return o;
  };
  size_t o_winner  = alloc(NI * 4);
  size_t o_map     = alloc(NN * 4);
  size_t o_a1s     = alloc((size_t)NN * 2 * 4);
  size_t o_a1d     = alloc((size_t)NN * 2 * 4);
  size_t o_deg     = alloc(NN * 4);
  size_t o_rs      = alloc(NN * 4);
  size_t o_fill    = alloc(NN * 4);
  size_t o_cnt     = alloc(4);
  size_t o_col     = alloc((size_t)ET * 4);
  size_t o_a2s     = alloc(NN * 4);
  size_t o_a2d     = alloc(NN * 4);
  size_t o_qs      = alloc(256 * 4);
  size_t o_qd      = alloc(256 * 4);
  // region R1 (37.75MB): cemb(4.19M) | Xa(16.78M) | Ha(16.78M)
  // reuse after conv1: agg(16.78M)@0 | out2c(8.39M)@16.78M | comb(12.58M)@25.17M | ph(4.19M)@0
  size_t o_r1      = alloc(4194304 + 16777216 + 16777216);
  size_t o_cemb  = o_r1;
  size_t o_xa    = o_r1 + 4194304;
  size_t o_ha    = o_r1 + 4194304 + 16777216;
  size_t o_agg   = o_r1;                       // alias cemb+Xa (dead)
  size_t o_out2c = o_r1 + 16777216;            // alias Ha start (dead)
  size_t o_comb  = o_r1 + 25165824;            // alias Ha rest (dead)
  size_t o_ph    = o_r1;                       // alias agg (dead after out2c GEMM)
  // region R2: x1 [NN,256]
  size_t o_x1    = alloc((size_t)NN * 256 * 4);
  (void)ws_size; (void)in_sizes; (void)n_in; (void)out_size;

  int*   winner = (int*)(ws + o_winner);
  int*   map    = (int*)(ws + o_map);
  float* a1s    = (float*)(ws + o_a1s);
  float* a1d    = (float*)(ws + o_a1d);
  int*   deg    = (int*)(ws + o_deg);
  int*   rs     = (int*)(ws + o_rs);
  int*   fill   = (int*)(ws + o_fill);
  int*   cnt    = (int*)(ws + o_cnt);
  int*   col    = (int*)(ws + o_col);
  float* a2s    = (float*)(ws + o_a2s);
  float* a2d    = (float*)(ws + o_a2d);
  float* qs     = (float*)(ws + o_qs);
  float* qd     = (float*)(ws + o_qd);
  float* cemb   = (float*)(ws + o_cemb);
  float* Xa     = (float*)(ws + o_xa);
  float* Ha     = (float*)(ws + o_ha);
  float* agg    = (float*)(ws + o_agg);
  float* out2c  = (float*)(ws + o_out2c);
  float* comb   = (float*)(ws + o_comb);
  float* ph     = (float*)(ws + o_ph);
  float* x1     = (float*)(ws + o_x1);

  hipMemsetAsync(winner, 0xFF, NI * 4, stream);
  hipMemsetAsync(map, 0xFF, NN * 4, stream);
  hipMemsetAsync(a1s, 0, (size_t)NN * 2 * 4, stream);
  hipMemsetAsync(a1d, 0, (size_t)NN * 2 * 4, stream);
  hipMemsetAsync(deg, 0, NN * 4, stream);
  hipMemsetAsync(cnt, 0, 4, stream);

  winner_kernel<<<(BB + 255) / 256, 256, 0, stream>>>(iid, winner);
  // c_emb = content @ Wc^T + bc
  {
    dim3 g((BB + 63) / 64, (DD + 63) / 64);
    gemm_bt_kernel<<<g, 256, 0, stream>>>(content, wc, bc, cemb, BB, DD, 512, 0);
  }
  build_xa_kernel<<<NTASK, 64, 0, stream>>>(uid, iid, winner, uemb, iemb, cemb, Xa, map);
  deg_kernel<<<(ET + 255) / 256, 256, 0, stream>>>(ei, deg);
  rowstart_kernel<<<(NN + 255) / 256, 256, 0, stream>>>(deg, rs, fill, cnt);
  fill_kernel<<<(ET + 255) / 256, 256, 0, stream>>>(ei, fill, col);
  // Ha = Xa @ W1^T
  {
    dim3 g((NTASK + 63) / 64, (256 + 63) / 64);
    gemm_bt_kernel<<<g, 256, 0, stream>>>(Xa, w1, nullptr, Ha, NTASK, 256, 256, 0);
  }
  a1_kernel<<<NTASK, 64, 0, stream>>>(uid, iid, Ha, att1s, att1d, a1s, a1d);
  conv1_agg_kernel<<<NN, 64, 0, stream>>>(col, rs, deg, Ha, map, a1s, a1d, b1, x1);
  // conv2 without full h2: scores from x1 via q-vectors; aggregate in x1-space; project 16384 rows.
  qvec_kernel<<<1, 256, 0, stream>>>(w2, att2s, att2d, qs, qd);
  a2x_kernel<<<(NN + 3) / 4, 256, 0, stream>>>(x1, qs, qd, a2s, a2d);
  conv2_aggx_kernel<<<NTASK, 64, 0, stream>>>(uid, iid, col, rs, deg, x1, a2s, a2d, agg);
  // out2c = agg @ W2^T + b2c   [16384,128]
  {
    dim3 g((NTASK + 63) / 64, (DD + 63) / 64);
    gemm_bt_kernel<<<g, 256, 0, stream>>>(agg, w2, b2c, out2c, NTASK, DD, 256, 0);
  }
  combined_kernel<<<(BB * 96 + 255) / 256, 256, 0, stream>>>(uid, uemb, out2c, comb);
  // ph = relu(comb @ pw1^T + pb1)
  {
    dim3 g((BB + 63) / 64, (DD + 63) / 64);
    gemm_bt_kernel<<<g, 256, 0, stream>>>(comb, pw1, pb1, ph, BB, DD, 384, 1);
  }
  final_kernel<<<BB, 64, 0, stream>>>(ph, pw2, pb2, out);
}

// Round 3
// 333.132 us; speedup vs baseline: 1.3437x; 1.0622x over previous
//
#include <hip/hip_runtime.h>
#include <hip/hip_bf16.h>

#define NU 50000
#define NI 20000
#define NN 70000
#define DD 128
#define BB 8192
#define EE 500000
#define ET 570000   // EE + NN self loops
#define NTASK 16384 // 2*BB

__device__ __forceinline__ float lrelu(float x) { return x > 0.f ? x : 0.2f * x; }

// ---------------- GEMM: C[M,N] = A[M,K] * B[N,K]^T (+bias) (+relu) ----------------
// Templated tile: 256 threads, per-thread TM x TN fragment.
template <int BM, int BN, int TM, int TN>
__global__ __launch_bounds__(256) void gemm_bt(
    const float* __restrict__ A, const float* __restrict__ B,
    const float* __restrict__ bias, float* __restrict__ C,
    int M, int N, int K, int act) {
  const int BK = 16;
  __shared__ float As[BK][BM + 4];
  __shared__ float Bs[BK][BN + 4];
  int tid = threadIdx.x;
  const int NTX = BN / TN;
  int tx = tid % NTX, ty = tid / NTX;
  int bm = blockIdx.x * BM, bn = blockIdx.y * BN;
  const int A4 = BM * BK / 1024;  // float4 stage loads per thread
  const int B4 = BN * BK / 1024;
  float acc[TM][TN] = {};
  for (int k0 = 0; k0 < K; k0 += BK) {
#pragma unroll
    for (int t = 0; t < A4; t++) {
      int f = tid + t * 256;
      int row = f >> 2, kk = (f & 3) * 4;
      float4 v = make_float4(0.f, 0.f, 0.f, 0.f);
      if (bm + row < M) v = *reinterpret_cast<const float4*>(&A[(size_t)(bm + row) * K + k0 + kk]);
      As[kk + 0][row] = v.x; As[kk + 1][row] = v.y; As[kk + 2][row] = v.z; As[kk + 3][row] = v.w;
    }
#pragma unroll
    for (int t = 0; t < B4; t++) {
      int f = tid + t * 256;
      int row = f >> 2, kk = (f & 3) * 4;
      float4 v = make_float4(0.f, 0.f, 0.f, 0.f);
      if (bn + row < N) v = *reinterpret_cast<const float4*>(&B[(size_t)(bn + row) * K + k0 + kk]);
      Bs[kk + 0][row] = v.x; Bs[kk + 1][row] = v.y; Bs[kk + 2][row] = v.z; Bs[kk + 3][row] = v.w;
    }
    __syncthreads();
#pragma unroll
    for (int k = 0; k < BK; k++) {
      float a[TM], b[TN];
#pragma unroll
      for (int i = 0; i < TM; i += 4) {
        float4 v = *reinterpret_cast<const float4*>(&As[k][ty * TM + i]);
        a[i] = v.x; a[i + 1] = v.y; a[i + 2] = v.z; a[i + 3] = v.w;
      }
#pragma unroll
      for (int j = 0; j < TN; j += 4) {
        float4 v = *reinterpret_cast<const float4*>(&Bs[k][tx * TN + j]);
        b[j] = v.x; b[j + 1] = v.y; b[j + 2] = v.z; b[j + 3] = v.w;
      }
#pragma unroll
      for (int i = 0; i < TM; i++)
#pragma unroll
        for (int j = 0; j < TN; j++) acc[i][j] += a[i] * b[j];
    }
    __syncthreads();
  }
#pragma unroll
  for (int i = 0; i < TM; i++) {
    int row = bm + ty * TM + i;
    if (row >= M) continue;
#pragma unroll
    for (int j = 0; j < TN; j++) {
      int cn = bn + tx * TN + j;
      if (cn >= N) continue;
      float v = acc[i][j];
      if (bias) v += bias[cn];
      if (act == 1) v = fmaxf(v, 0.f);
      C[(size_t)row * N + cn] = v;
    }
  }
}

// ---------------- small kernels ----------------
__global__ void winner_kernel(const int* __restrict__ iid, int* __restrict__ winner) {
  int b = blockIdx.x * 256 + threadIdx.x;
  if (b >= BB) return;
  atomicMax(&winner[iid[b]], b);
}

__global__ void build_xa_kernel(const int* __restrict__ uid, const int* __restrict__ iid,
                                const int* __restrict__ winner,
                                const float* __restrict__ uemb, const float* __restrict__ iemb,
                                const float* __restrict__ cemb,
                                float* __restrict__ Xa, int* __restrict__ map) {
  int t = blockIdx.x;
  int lane = threadIdx.x;  // 64
  int c4 = lane * 4;
  float4 v = make_float4(0.f, 0.f, 0.f, 0.f);
  int node;
  if (t < BB) {
    int u = uid[t];
    node = u;
    if (c4 < DD) v = *reinterpret_cast<const float4*>(&uemb[(size_t)u * DD + c4]);
  } else {
    int b = t - BB;
    int it = iid[b];
    node = NU + it;
    if (c4 < DD) {
      v = *reinterpret_cast<const float4*>(&iemb[(size_t)it * DD + c4]);
    } else {
      int wb = winner[it];
      v = *reinterpret_cast<const float4*>(&cemb[(size_t)wb * DD + (c4 - DD)]);
    }
  }
  *reinterpret_cast<float4*>(&Xa[(size_t)t * 256 + c4]) = v;
  if (lane == 0) map[node] = t;  // duplicate tasks have identical rows -> benign
}

__global__ void deg_kernel(const int* __restrict__ ei, int* __restrict__ deg) {
  int e = blockIdx.x * 256 + threadIdx.x;
  if (e >= ET) return;
  int dst = (e < EE) ? ei[EE + e] : (e - EE);
  atomicAdd(&deg[dst], 1);
}

__global__ void rowstart_kernel(const int* __restrict__ deg, int* __restrict__ rowstart,
                                int* __restrict__ fill, int* __restrict__ counter) {
  int v = blockIdx.x * 256 + threadIdx.x;
  if (v >= NN) return;
  int s = atomicAdd(counter, deg[v]);
  rowstart[v] = s;
  fill[v] = s;
}

__global__ void fill_kernel(const int* __restrict__ ei, int* __restrict__ fill,
                            int* __restrict__ col) {
  int e = blockIdx.x * 256 + threadIdx.x;
  if (e >= ET) return;
  int src, dst;
  if (e < EE) { src = ei[e]; dst = ei[EE + e]; }
  else { src = e - EE; dst = src; }
  int pos = atomicAdd(&fill[dst], 1);
  col[pos] = src;
}

__global__ void a1_kernel(const int* __restrict__ uid, const int* __restrict__ iid,
                          const float* __restrict__ Ha,
                          const float* __restrict__ atts, const float* __restrict__ attd,
                          float* __restrict__ a1s, float* __restrict__ a1d) {
  int t = blockIdx.x, lane = threadIdx.x;  // 64
  int v = (t < BB) ? uid[t] : NU + iid[t - BB];
  int head = lane >> 5, c = (lane & 31) * 4;
  float4 hv = *reinterpret_cast<const float4*>(&Ha[(size_t)t * 256 + head * DD + c]);
  float4 sv = *reinterpret_cast<const float4*>(&atts[head * DD + c]);
  float4 dv = *reinterpret_cast<const float4*>(&attd[head * DD + c]);
  float ps = hv.x * sv.x + hv.y * sv.y + hv.z * sv.z + hv.w * sv.w;
  float pd = hv.x * dv.x + hv.y * dv.y + hv.z * dv.z + hv.w * dv.w;
  for (int o = 1; o < 32; o <<= 1) { ps += __shfl_xor(ps, o); pd += __shfl_xor(pd, o); }
  if ((lane & 31) == 0) {
    a1s[(size_t)v * 2 + head] = ps;
    a1d[(size_t)v * 2 + head] = pd;
  }
}

// q_s = W2^T att2_src, q_d = W2^T att2_dst  (256 each). One block, 256 threads.
__global__ void qvec_kernel(const float* __restrict__ w2, const float* __restrict__ atts,
                            const float* __restrict__ attd,
                            float* __restrict__ qs, float* __restrict__ qd) {
  int k = threadIdx.x;  // 0..255
  float s = 0.f, d = 0.f;
#pragma unroll 4
  for (int j = 0; j < DD; j++) {
    float w = w2[(size_t)j * 256 + k];
    s += atts[j] * w;
    d += attd[j] * w;
  }
  qs[k] = s;
  qd[k] = d;
}

// conv1 aggregation: lane-parallel edges, online softmax, fused ELU+bias and
// fused conv2-score computation (a2s/a2d) in the epilogue. 4 nodes/block.
__global__ __launch_bounds__(256) void conv1_agg_kernel(
    const int* __restrict__ col, const int* __restrict__ rowstart,
    const int* __restrict__ deg, const float* __restrict__ Ha,
    const int* __restrict__ map,
    const float* __restrict__ a1s, const float* __restrict__ a1d,
    const float* __restrict__ bias,
    const float* __restrict__ qs, const float* __restrict__ qd,
    float* __restrict__ x1, float* __restrict__ a2s, float* __restrict__ a2d) {
  int v = blockIdx.x * 4 + (threadIdx.x >> 6);  // NN divisible by 4
  int lane = threadIdx.x & 63;
  int head = lane >> 5;
  int d = deg[v], s0 = rowstart[v];
  float2 adv = *reinterpret_cast<const float2*>(&a1d[(size_t)v * 2]);
  float m0 = -1e30f, m1 = -1e30f, den0 = 0.f, den1 = 0.f;
  float4 acc = make_float4(0.f, 0.f, 0.f, 0.f);
  for (int c0 = 0; c0 < d; c0 += 64) {
    int i = c0 + lane;
    bool act = i < d;
    int ci = act ? col[s0 + i] : 0;
    float2 asv = make_float2(0.f, 0.f);
    int ri = -1;
    if (act) {
      asv = *reinterpret_cast<const float2*>(&a1s[(size_t)ci * 2]);
      ri = map[ci];
    }
    float al0 = act ? lrelu(asv.x + adv.x) : -1e30f;
    float al1 = act ? lrelu(asv.y + adv.y) : -1e30f;
    float cm0 = al0, cm1 = al1;
#pragma unroll
    for (int o = 1; o < 64; o <<= 1) {
      cm0 = fmaxf(cm0, __shfl_xor(cm0, o));
      cm1 = fmaxf(cm1, __shfl_xor(cm1, o));
    }
    float nm0 = fmaxf(m0, cm0), nm1 = fmaxf(m1, cm1);
    float ex0 = act ? __expf(al0 - nm0) : 0.f;
    float ex1 = act ? __expf(al1 - nm1) : 0.f;
    float s0f = __expf(m0 - nm0), s1f = __expf(m1 - nm1);
    float cs0 = ex0, cs1 = ex1;
#pragma unroll
    for (int o = 1; o < 64; o <<= 1) {
      cs0 += __shfl_xor(cs0, o);
      cs1 += __shfl_xor(cs1, o);
    }
    den0 = den0 * s0f + cs0;
    den1 = den1 * s1f + cs1;
    float sc = head ? s1f : s0f;
    acc.x *= sc; acc.y *= sc; acc.z *= sc; acc.w *= sc;
    int n = min(64, d - c0);
    for (int i2 = 0; i2 < n; i2++) {
      int r = __shfl(ri, i2);
      if (r >= 0) {
        float e0 = __shfl(ex0, i2), e1 = __shfl(ex1, i2);
        float ex = head ? e1 : e0;
        float4 hv = *reinterpret_cast<const float4*>(&Ha[((size_t)r << 8) + (lane << 2)]);
        acc.x += ex * hv.x; acc.y += ex * hv.y; acc.z += ex * hv.z; acc.w += ex * hv.w;
      }
    }
    m0 = nm0; m1 = nm1;
  }
  float inv = 1.f / (head ? den1 : den0);
  float4 b4 = *reinterpret_cast<const float4*>(&bias[lane << 2]);
  float4 o;
  o.x = acc.x * inv + b4.x;
  o.y = acc.y * inv + b4.y;
  o.z = acc.z * inv + b4.z;
  o.w = acc.w * inv + b4.w;
  o.x = o.x > 0.f ? o.x : expm1f(o.x);
  o.y = o.y > 0.f ? o.y : expm1f(o.y);
  o.z = o.z > 0.f ? o.z : expm1f(o.z);
  o.w = o.w > 0.f ? o.w : expm1f(o.w);
  *reinterpret_cast<float4*>(&x1[((size_t)v << 8) + (lane << 2)]) = o;
  // fused conv2 scores: a2s[v] = x1[v].qs, a2d[v] = x1[v].qd
  float4 sv = *reinterpret_cast<const float4*>(&qs[lane << 2]);
  float4 dv = *reinterpret_cast<const float4*>(&qd[lane << 2]);
  float ps = o.x * sv.x + o.y * sv.y + o.z * sv.z + o.w * sv.w;
  float pd = o.x * dv.x + o.y * dv.y + o.z * dv.z + o.w * dv.w;
#pragma unroll
  for (int of = 1; of < 64; of <<= 1) { ps += __shfl_xor(ps, of); pd += __shfl_xor(pd, of); }
  if (lane == 0) { a2s[v] = ps; a2d[v] = pd; }
}

// conv2 aggregation in x1-space (256-d), batch tasks only. 4 tasks/block.
__global__ __launch_bounds__(256) void conv2_agg_kernel(
    const int* __restrict__ uid, const int* __restrict__ iid,
    const int* __restrict__ col, const int* __restrict__ rowstart,
    const int* __restrict__ deg, const float* __restrict__ x1,
    const float* __restrict__ a2s, const float* __restrict__ a2d,
    float* __restrict__ agg) {
  int t = blockIdx.x * 4 + (threadIdx.x >> 6);  // NTASK divisible by 4
  int lane = threadIdx.x & 63;
  int v = (t < BB) ? uid[t] : NU + iid[t - BB];
  int d = deg[v], s0 = rowstart[v];
  float ad = a2d[v];
  float m = -1e30f, den = 0.f;
  float4 acc = make_float4(0.f, 0.f, 0.f, 0.f);
  for (int c0 = 0; c0 < d; c0 += 64) {
    int i = c0 + lane;
    bool act = i < d;
    int ci = act ? col[s0 + i] : 0;
    float as = act ? a2s[ci] : 0.f;
    float al = act ? lrelu(as + ad) : -1e30f;
    float cm = al;
#pragma unroll
    for (int o = 1; o < 64; o <<= 1) cm = fmaxf(cm, __shfl_xor(cm, o));
    float nm = fmaxf(m, cm);
    float ex = act ? __expf(al - nm) : 0.f;
    float sf = __expf(m - nm);
    float cs = ex;
#pragma unroll
    for (int o = 1; o < 64; o <<= 1) cs += __shfl_xor(cs, o);
    den = den * sf + cs;
    acc.x *= sf; acc.y *= sf; acc.z *= sf; acc.w *= sf;
    int n = min(64, d - c0);
    for (int i2 = 0; i2 < n; i2++) {
      int r = __shfl(ci, i2);
      float e = __shfl(ex, i2);
      float4 hv = *reinterpret_cast<const float4*>(&x1[((size_t)r << 8) + (lane << 2)]);
      acc.x += e * hv.x; acc.y += e * hv.y; acc.z += e * hv.z; acc.w += e * hv.w;
    }
    m = nm;
  }
  float inv = 1.f / den;
  float4 o = make_float4(acc.x * inv, acc.y * inv, acc.z * inv, acc.w * inv);
  *reinterpret_cast<float4*>(&agg[((size_t)t << 8) + (lane << 2)]) = o;
}

__global__ void combined_kernel(const int* __restrict__ uid,
                                const float* __restrict__ uemb, const float* __restrict__ out2c,
                                float* __restrict__ comb) {
  int idx = blockIdx.x * 256 + threadIdx.x;  // float4 index
  if (idx >= BB * 96) return;
  int b = idx / 96, c = idx % 96;
  int sec = c >> 5, off = (c & 31) * 4;
  float4 v;
  if (sec == 0) v = *reinterpret_cast<const float4*>(&uemb[(size_t)uid[b] * DD + off]);
  else if (sec == 1) v = *reinterpret_cast<const float4*>(&out2c[(size_t)(BB + b) * DD + off]);
  else v = *reinterpret_cast<const float4*>(&out2c[(size_t)b * DD + off]);
  *reinterpret_cast<float4*>(&comb[(size_t)b * 384 + c * 4]) = v;
}

__global__ void final_kernel(const float* __restrict__ ph, const float* __restrict__ w2,
                             const float* __restrict__ b2, float* __restrict__ out) {
  int b = blockIdx.x, lane = threadIdx.x;  // 64
  float2 hv = *reinterpret_cast<const float2*>(&ph[((size_t)b << 7) + (lane << 1)]);
  float2 wv = *reinterpret_cast<const float2*>(&w2[lane << 1]);
  float s = hv.x * wv.x + hv.y * wv.y;
  for (int o = 1; o < 64; o <<= 1) s += __shfl_xor(s, o);
  if (lane == 0) out[b] = s + b2[0];
}

// ---------------- launcher ----------------
extern "C" void kernel_launch(void* const* d_in, const int* in_sizes, int n_in,
                              void* d_out, int out_size, void* d_ws, size_t ws_size,
                              hipStream_t stream) {
  const int* uid = (const int*)d_in[0];
  const int* iid = (const int*)d_in[1];
  const float* content = (const float*)d_in[2];
  const int* ei = (const int*)d_in[3];
  const float* uemb = (const float*)d_in[4];
  const float* iemb = (const float*)d_in[5];
  const float* wc = (const float*)d_in[6];
  const float* bc = (const float*)d_in[7];
  const float* w1 = (const float*)d_in[8];
  const float* att1s = (const float*)d_in[9];
  const float* att1d = (const float*)d_in[10];
  const float* b1 = (const float*)d_in[11];
  const float* w2 = (const float*)d_in[12];
  const float* att2s = (const float*)d_in[13];
  const float* att2d = (const float*)d_in[14];
  const float* b2c = (const float*)d_in[15];
  const float* pw1 = (const float*)d_in[16];
  const float* pb1 = (const float*)d_in[17];
  const float* pw2 = (const float*)d_in[18];
  const float* pb2 = (const float*)d_in[19];
  float* out = (float*)d_out;
  char* ws = (char*)d_ws;

  size_t off = 0;
  auto alloc = [&](size_t bytes) {
    size_t o = off;
    off += (bytes + 255) & ~(size_t)255;
    return o;
  };
  size_t o_winner  = alloc(NI * 4);
  size_t o_map     = alloc(NN * 4);
  size_t o_a1s     = alloc((size_t)NN * 2 * 4);
  size_t o_a1d     = alloc((size_t)NN * 2 * 4);
  size_t o_deg     = alloc(NN * 4);
  size_t o_rs      = alloc(NN * 4);
  size_t o_fill    = alloc(NN * 4);
  size_t o_cnt     = alloc(4);
  size_t o_col     = alloc((size_t)ET * 4);
  size_t o_a2s     = alloc(NN * 4);
  size_t o_a2d     = alloc(NN * 4);
  size_t o_qs      = alloc(256 * 4);
  size_t o_qd      = alloc(256 * 4);
  // region R1 (37.75MB): cemb(4.19M) | Xa(16.78M) | Ha(16.78M)
  // reuse after conv1: agg(16.78M)@0 | out2c(8.39M)@16.78M | comb(12.58M)@25.17M | ph(4.19M)@0
  size_t o_r1      = alloc(4194304 + 16777216 + 16777216);
  size_t o_cemb  = o_r1;
  size_t o_xa    = o_r1 + 4194304;
  size_t o_ha    = o_r1 + 4194304 + 16777216;
  size_t o_agg   = o_r1;                       // alias cemb+Xa (dead)
  size_t o_out2c = o_r1 + 16777216;            // alias Ha start (dead)
  size_t o_comb  = o_r1 + 25165824;            // alias Ha rest (dead)
  size_t o_ph    = o_r1;                       // alias agg (dead after out2c GEMM)
  // region R2: x1 [NN,256]
  size_t o_x1    = alloc((size_t)NN * 256 * 4);
  (void)ws_size; (void)in_sizes; (void)n_in; (void)out_size;

  int*   winner = (int*)(ws + o_winner);
  int*   map    = (int*)(ws + o_map);
  float* a1s    = (float*)(ws + o_a1s);
  float* a1d    = (float*)(ws + o_a1d);
  int*   deg    = (int*)(ws + o_deg);
  int*   rs     = (int*)(ws + o_rs);
  int*   fill   = (int*)(ws + o_fill);
  int*   cnt    = (int*)(ws + o_cnt);
  int*   col    = (int*)(ws + o_col);
  float* a2s    = (float*)(ws + o_a2s);
  float* a2d    = (float*)(ws + o_a2d);
  float* qs     = (float*)(ws + o_qs);
  float* qd     = (float*)(ws + o_qd);
  float* cemb   = (float*)(ws + o_cemb);
  float* Xa     = (float*)(ws + o_xa);
  float* Ha     = (float*)(ws + o_ha);
  float* agg    = (float*)(ws + o_agg);
  float* out2c  = (float*)(ws + o_out2c);
  float* comb   = (float*)(ws + o_comb);
  float* ph     = (float*)(ws + o_ph);
  float* x1     = (float*)(ws + o_x1);

  hipMemsetAsync(winner, 0xFF, NI * 4, stream);
  hipMemsetAsync(map, 0xFF, NN * 4, stream);
  hipMemsetAsync(a1s, 0, (size_t)NN * 2 * 4, stream);
  hipMemsetAsync(a1d, 0, (size_t)NN * 2 * 4, stream);
  hipMemsetAsync(deg, 0, NN * 4, stream);
  hipMemsetAsync(cnt, 0, 4, stream);

  winner_kernel<<<(BB + 255) / 256, 256, 0, stream>>>(iid, winner);
  // c_emb = content @ Wc^T + bc
  {
    dim3 g(BB / 64, DD / 64);
    gemm_bt<64, 64, 4, 4><<<g, 256, 0, stream>>>(content, wc, bc, cemb, BB, DD, 512, 0);
  }
  build_xa_kernel<<<NTASK, 64, 0, stream>>>(uid, iid, winner, uemb, iemb, cemb, Xa, map);
  deg_kernel<<<(ET + 255) / 256, 256, 0, stream>>>(ei, deg);
  rowstart_kernel<<<(NN + 255) / 256, 256, 0, stream>>>(deg, rs, fill, cnt);
  fill_kernel<<<(ET + 255) / 256, 256, 0, stream>>>(ei, fill, col);
  qvec_kernel<<<1, 256, 0, stream>>>(w2, att2s, att2d, qs, qd);
  // Ha = Xa @ W1^T   [16384,256] x [256,256]^T -> big tile
  {
    dim3 g(NTASK / 128, 256 / 128);
    gemm_bt<128, 128, 8, 8><<<g, 256, 0, stream>>>(Xa, w1, nullptr, Ha, NTASK, 256, 256, 0);
  }
  a1_kernel<<<NTASK, 64, 0, stream>>>(uid, iid, Ha, att1s, att1d, a1s, a1d);
  conv1_agg_kernel<<<NN / 4, 256, 0, stream>>>(col, rs, deg, Ha, map, a1s, a1d, b1,
                                               qs, qd, x1, a2s, a2d);
  conv2_agg_kernel<<<NTASK / 4, 256, 0, stream>>>(uid, iid, col, rs, deg, x1, a2s, a2d, agg);
  // out2c = agg @ W2^T + b2c   [16384,128]
  {
    dim3 g(NTASK / 64, DD / 64);
    gemm_bt<64, 64, 4, 4><<<g, 256, 0, stream>>>(agg, w2, b2c, out2c, NTASK, DD, 256, 0);
  }
  combined_kernel<<<(BB * 96 + 255) / 256, 256, 0, stream>>>(uid, uemb, out2c, comb);
  // ph = relu(comb @ pw1^T + pb1)
  {
    dim3 g(BB / 64, DD / 64);
    gemm_bt<64, 64, 4, 4><<<g, 256, 0, stream>>>(comb, pw1, pb1, ph, BB, DD, 384, 1);
  }
  final_kernel<<<BB, 64, 0, stream>>>(ph, pw2, pb2, out);
}

// Round 4
// 306.788 us; speedup vs baseline: 1.4591x; 1.0859x over previous
//
#include <hip/hip_runtime.h>
#include <hip/hip_bf16.h>

#define NU 50000
#define NI 20000
#define NN 70000
#define DD 128
#define BB 8192
#define EE 500000
#define ET 570000   // EE + NN self loops
#define NTASK 16384 // 2*BB

__device__ __forceinline__ float lrelu(float x) { return x > 0.f ? x : 0.2f * x; }

// ---------------- GEMM: C[M,N] = A[M,K] * B[N,K]^T (+bias) (+relu) ----------------
// 64x64 tile, BK=32, 256 threads, TM=TN=4.
// Register-prefetch + LDS double-buffer: ONE __syncthreads per K-iteration.
// All problem dims are exact multiples of the tile -> no bounds checks.
// GATHER=1: logical A row r is [uemb[uidx[r]] | gA1[BB+r] | gA1[r]] (128 cols each).
template <int GATHER>
__global__ __launch_bounds__(256) void gemm_bt(
    const float* __restrict__ A, const float* __restrict__ B,
    const float* __restrict__ bias, float* __restrict__ C,
    int M, int N, int K, int act,
    const int* __restrict__ uidx, const float* __restrict__ gA0,
    const float* __restrict__ gA1) {
  const int BM = 64, BN = 64, BK = 32;
  __shared__ float As[2][BK][BM + 4];
  __shared__ float Bs[2][BK][BN + 4];
  int tid = threadIdx.x;
  int tx = tid & 15, ty = tid >> 4;
  int bm = blockIdx.x * BM, bn = blockIdx.y * BN;
  float4 ra[2], rb[2];

  auto stage_load = [&](int k0) {
#pragma unroll
    for (int t = 0; t < 2; t++) {
      int f = tid + t * 256;          // 0..511 over 64x32/4 float4s
      int row = f >> 3, kk = (f & 7) << 2;
      if (GATHER) {
        int sec = k0 >> 7;
        int kc = (k0 & 127) + kk;
        int r = bm + row;
        const float* p;
        if (sec == 0)      p = &gA0[(size_t)uidx[r] * 128 + kc];
        else if (sec == 1) p = &gA1[((size_t)(BB + r)) * 128 + kc];
        else               p = &gA1[((size_t)r) * 128 + kc];
        ra[t] = *reinterpret_cast<const float4*>(p);
      } else {
        ra[t] = *reinterpret_cast<const float4*>(&A[(size_t)(bm + row) * K + k0 + kk]);
      }
      rb[t] = *reinterpret_cast<const float4*>(&B[(size_t)(bn + row) * K + k0 + kk]);
    }
  };
  auto stage_store = [&](int buf) {
#pragma unroll
    for (int t = 0; t < 2; t++) {
      int f = tid + t * 256;
      int row = f >> 3, kk = (f & 7) << 2;
      As[buf][kk + 0][row] = ra[t].x; As[buf][kk + 1][row] = ra[t].y;
      As[buf][kk + 2][row] = ra[t].z; As[buf][kk + 3][row] = ra[t].w;
      Bs[buf][kk + 0][row] = rb[t].x; Bs[buf][kk + 1][row] = rb[t].y;
      Bs[buf][kk + 2][row] = rb[t].z; Bs[buf][kk + 3][row] = rb[t].w;
    }
  };

  float acc[4][4] = {};
  int KT = K / BK;
  stage_load(0);
  stage_store(0);
  __syncthreads();
  for (int kt = 0; kt < KT; kt++) {
    int cur = kt & 1;
    if (kt + 1 < KT) stage_load((kt + 1) * BK);
#pragma unroll
    for (int k = 0; k < BK; k++) {
      float4 a4 = *reinterpret_cast<const float4*>(&As[cur][k][ty * 4]);
      float4 b4 = *reinterpret_cast<const float4*>(&Bs[cur][k][tx * 4]);
      float a[4] = {a4.x, a4.y, a4.z, a4.w};
      float b[4] = {b4.x, b4.y, b4.z, b4.w};
#pragma unroll
      for (int i = 0; i < 4; i++)
#pragma unroll
        for (int j = 0; j < 4; j++) acc[i][j] += a[i] * b[j];
    }
    if (kt + 1 < KT) {
      stage_store(cur ^ 1);
      __syncthreads();
    }
  }
  float4 bv = make_float4(0.f, 0.f, 0.f, 0.f);
  if (bias) bv = *reinterpret_cast<const float4*>(&bias[bn + tx * 4]);
#pragma unroll
  for (int i = 0; i < 4; i++) {
    int row = bm + ty * 4 + i;
    float4 v = make_float4(acc[i][0] + bv.x, acc[i][1] + bv.y,
                           acc[i][2] + bv.z, acc[i][3] + bv.w);
    if (act == 1) {
      v.x = fmaxf(v.x, 0.f); v.y = fmaxf(v.y, 0.f);
      v.z = fmaxf(v.z, 0.f); v.w = fmaxf(v.w, 0.f);
    }
    *reinterpret_cast<float4*>(&C[(size_t)row * N + bn + tx * 4]) = v;
  }
}

// ---------------- small kernels ----------------
__global__ void winner_kernel(const int* __restrict__ iid, int* __restrict__ winner) {
  int b = blockIdx.x * 256 + threadIdx.x;
  if (b >= BB) return;
  atomicMax(&winner[iid[b]], b);
}

__global__ void build_xa_kernel(const int* __restrict__ uid, const int* __restrict__ iid,
                                const int* __restrict__ winner,
                                const float* __restrict__ uemb, const float* __restrict__ iemb,
                                const float* __restrict__ cemb,
                                float* __restrict__ Xa, int* __restrict__ map) {
  int t = blockIdx.x;
  int lane = threadIdx.x;  // 64
  int c4 = lane * 4;
  float4 v = make_float4(0.f, 0.f, 0.f, 0.f);
  int node;
  if (t < BB) {
    int u = uid[t];
    node = u;
    if (c4 < DD) v = *reinterpret_cast<const float4*>(&uemb[(size_t)u * DD + c4]);
  } else {
    int b = t - BB;
    int it = iid[b];
    node = NU + it;
    if (c4 < DD) {
      v = *reinterpret_cast<const float4*>(&iemb[(size_t)it * DD + c4]);
    } else {
      int wb = winner[it];
      v = *reinterpret_cast<const float4*>(&cemb[(size_t)wb * DD + (c4 - DD)]);
    }
  }
  *reinterpret_cast<float4*>(&Xa[(size_t)t * 256 + c4]) = v;
  if (lane == 0) map[node] = t;  // duplicate tasks have identical rows -> benign
}

__global__ void deg_kernel(const int* __restrict__ ei, int* __restrict__ deg) {
  int e = blockIdx.x * 256 + threadIdx.x;
  if (e >= ET) return;
  int dst = (e < EE) ? ei[EE + e] : (e - EE);
  atomicAdd(&deg[dst], 1);
}

__global__ void rowstart_kernel(const int* __restrict__ deg, int* __restrict__ rowstart,
                                int* __restrict__ fill, int* __restrict__ counter) {
  int v = blockIdx.x * 256 + threadIdx.x;
  if (v >= NN) return;
  int s = atomicAdd(counter, deg[v]);
  rowstart[v] = s;
  fill[v] = s;
}

__global__ void fill_kernel(const int* __restrict__ ei, int* __restrict__ fill,
                            int* __restrict__ col) {
  int e = blockIdx.x * 256 + threadIdx.x;
  if (e >= ET) return;
  int src, dst;
  if (e < EE) { src = ei[e]; dst = ei[EE + e]; }
  else { src = e - EE; dst = src; }
  int pos = atomicAdd(&fill[dst], 1);
  col[pos] = src;
}

// a1 scores for the 16384 tasks; last 4 blocks compute the conv2 q-vectors.
__global__ void a1q_kernel(const int* __restrict__ uid, const int* __restrict__ iid,
                           const float* __restrict__ Ha,
                           const float* __restrict__ atts, const float* __restrict__ attd,
                           const float* __restrict__ w2,
                           const float* __restrict__ att2s, const float* __restrict__ att2d,
                           float* __restrict__ a1s, float* __restrict__ a1d,
                           float* __restrict__ qs, float* __restrict__ qd) {
  int t = blockIdx.x, lane = threadIdx.x;  // 64
  if (t >= NTASK) {
    int k = (t - NTASK) * 64 + lane;  // 0..255
    float s = 0.f, d = 0.f;
#pragma unroll 4
    for (int j = 0; j < DD; j++) {
      float w = w2[(size_t)j * 256 + k];
      s += att2s[j] * w;
      d += att2d[j] * w;
    }
    qs[k] = s;
    qd[k] = d;
    return;
  }
  int v = (t < BB) ? uid[t] : NU + iid[t - BB];
  int head = lane >> 5, c = (lane & 31) * 4;
  float4 hv = *reinterpret_cast<const float4*>(&Ha[(size_t)t * 256 + head * DD + c]);
  float4 sv = *reinterpret_cast<const float4*>(&atts[head * DD + c]);
  float4 dv = *reinterpret_cast<const float4*>(&attd[head * DD + c]);
  float ps = hv.x * sv.x + hv.y * sv.y + hv.z * sv.z + hv.w * sv.w;
  float pd = hv.x * dv.x + hv.y * dv.y + hv.z * dv.z + hv.w * dv.w;
  for (int o = 1; o < 32; o <<= 1) { ps += __shfl_xor(ps, o); pd += __shfl_xor(pd, o); }
  if ((lane & 31) == 0) {
    a1s[(size_t)v * 2 + head] = ps;
    a1d[(size_t)v * 2 + head] = pd;
  }
}

// conv1 aggregation: lane-parallel edges, online softmax, fused ELU+bias and
// fused conv2-score computation (a2s/a2d) in the epilogue. 4 nodes/block.
__global__ __launch_bounds__(256) void conv1_agg_kernel(
    const int* __restrict__ col, const int* __restrict__ rowstart,
    const int* __restrict__ deg, const float* __restrict__ Ha,
    const int* __restrict__ map,
    const float* __restrict__ a1s, const float* __restrict__ a1d,
    const float* __restrict__ bias,
    const float* __restrict__ qs, const float* __restrict__ qd,
    float* __restrict__ x1, float* __restrict__ a2s, float* __restrict__ a2d) {
  int v = blockIdx.x * 4 + (threadIdx.x >> 6);  // NN divisible by 4
  int lane = threadIdx.x & 63;
  int head = lane >> 5;
  int d = deg[v], s0 = rowstart[v];
  float2 adv = *reinterpret_cast<const float2*>(&a1d[(size_t)v * 2]);
  float m0 = -1e30f, m1 = -1e30f, den0 = 0.f, den1 = 0.f;
  float4 acc = make_float4(0.f, 0.f, 0.f, 0.f);
  for (int c0 = 0; c0 < d; c0 += 64) {
    int i = c0 + lane;
    bool act = i < d;
    int ci = act ? col[s0 + i] : 0;
    float2 asv = make_float2(0.f, 0.f);
    int ri = -1;
    if (act) {
      asv = *reinterpret_cast<const float2*>(&a1s[(size_t)ci * 2]);
      ri = map[ci];
    }
    float al0 = act ? lrelu(asv.x + adv.x) : -1e30f;
    float al1 = act ? lrelu(asv.y + adv.y) : -1e30f;
    float cm0 = al0, cm1 = al1;
#pragma unroll
    for (int o = 1; o < 64; o <<= 1) {
      cm0 = fmaxf(cm0, __shfl_xor(cm0, o));
      cm1 = fmaxf(cm1, __shfl_xor(cm1, o));
    }
    float nm0 = fmaxf(m0, cm0), nm1 = fmaxf(m1, cm1);
    float ex0 = act ? __expf(al0 - nm0) : 0.f;
    float ex1 = act ? __expf(al1 - nm1) : 0.f;
    float s0f = __expf(m0 - nm0), s1f = __expf(m1 - nm1);
    float cs0 = ex0, cs1 = ex1;
#pragma unroll
    for (int o = 1; o < 64; o <<= 1) {
      cs0 += __shfl_xor(cs0, o);
      cs1 += __shfl_xor(cs1, o);
    }
    den0 = den0 * s0f + cs0;
    den1 = den1 * s1f + cs1;
    float sc = head ? s1f : s0f;
    acc.x *= sc; acc.y *= sc; acc.z *= sc; acc.w *= sc;
    int n = min(64, d - c0);
    for (int i2 = 0; i2 < n; i2++) {
      int r = __shfl(ri, i2);
      if (r >= 0) {
        float e0 = __shfl(ex0, i2), e1 = __shfl(ex1, i2);
        float ex = head ? e1 : e0;
        float4 hv = *reinterpret_cast<const float4*>(&Ha[((size_t)r << 8) + (lane << 2)]);
        acc.x += ex * hv.x; acc.y += ex * hv.y; acc.z += ex * hv.z; acc.w += ex * hv.w;
      }
    }
    m0 = nm0; m1 = nm1;
  }
  float inv = 1.f / (head ? den1 : den0);
  float4 b4 = *reinterpret_cast<const float4*>(&bias[lane << 2]);
  float4 o;
  o.x = acc.x * inv + b4.x;
  o.y = acc.y * inv + b4.y;
  o.z = acc.z * inv + b4.z;
  o.w = acc.w * inv + b4.w;
  o.x = o.x > 0.f ? o.x : expm1f(o.x);
  o.y = o.y > 0.f ? o.y : expm1f(o.y);
  o.z = o.z > 0.f ? o.z : expm1f(o.z);
  o.w = o.w > 0.f ? o.w : expm1f(o.w);
  *reinterpret_cast<float4*>(&x1[((size_t)v << 8) + (lane << 2)]) = o;
  // fused conv2 scores: a2s[v] = x1[v].qs, a2d[v] = x1[v].qd
  float4 sv = *reinterpret_cast<const float4*>(&qs[lane << 2]);
  float4 dv = *reinterpret_cast<const float4*>(&qd[lane << 2]);
  float ps = o.x * sv.x + o.y * sv.y + o.z * sv.z + o.w * sv.w;
  float pd = o.x * dv.x + o.y * dv.y + o.z * dv.z + o.w * dv.w;
#pragma unroll
  for (int of = 1; of < 64; of <<= 1) { ps += __shfl_xor(ps, of); pd += __shfl_xor(pd, of); }
  if (lane == 0) { a2s[v] = ps; a2d[v] = pd; }
}

// conv2 aggregation in x1-space (256-d), batch tasks only. 4 tasks/block.
__global__ __launch_bounds__(256) void conv2_agg_kernel(
    const int* __restrict__ uid, const int* __restrict__ iid,
    const int* __restrict__ col, const int* __restrict__ rowstart,
    const int* __restrict__ deg, const float* __restrict__ x1,
    const float* __restrict__ a2s, const float* __restrict__ a2d,
    float* __restrict__ agg) {
  int t = blockIdx.x * 4 + (threadIdx.x >> 6);  // NTASK divisible by 4
  int lane = threadIdx.x & 63;
  int v = (t < BB) ? uid[t] : NU + iid[t - BB];
  int d = deg[v], s0 = rowstart[v];
  float ad = a2d[v];
  float m = -1e30f, den = 0.f;
  float4 acc = make_float4(0.f, 0.f, 0.f, 0.f);
  for (int c0 = 0; c0 < d; c0 += 64) {
    int i = c0 + lane;
    bool act = i < d;
    int ci = act ? col[s0 + i] : 0;
    float as = act ? a2s[ci] : 0.f;
    float al = act ? lrelu(as + ad) : -1e30f;
    float cm = al;
#pragma unroll
    for (int o = 1; o < 64; o <<= 1) cm = fmaxf(cm, __shfl_xor(cm, o));
    float nm = fmaxf(m, cm);
    float ex = act ? __expf(al - nm) : 0.f;
    float sf = __expf(m - nm);
    float cs = ex;
#pragma unroll
    for (int o = 1; o < 64; o <<= 1) cs += __shfl_xor(cs, o);
    den = den * sf + cs;
    acc.x *= sf; acc.y *= sf; acc.z *= sf; acc.w *= sf;
    int n = min(64, d - c0);
    for (int i2 = 0; i2 < n; i2++) {
      int r = __shfl(ci, i2);
      float e = __shfl(ex, i2);
      float4 hv = *reinterpret_cast<const float4*>(&x1[((size_t)r << 8) + (lane << 2)]);
      acc.x += e * hv.x; acc.y += e * hv.y; acc.z += e * hv.z; acc.w += e * hv.w;
    }
    m = nm;
  }
  float inv = 1.f / den;
  float4 o = make_float4(acc.x * inv, acc.y * inv, acc.z * inv, acc.w * inv);
  *reinterpret_cast<float4*>(&agg[((size_t)t << 8) + (lane << 2)]) = o;
}

__global__ void final_kernel(const float* __restrict__ ph, const float* __restrict__ w2,
                             const float* __restrict__ b2, float* __restrict__ out) {
  int b = blockIdx.x, lane = threadIdx.x;  // 64
  float2 hv = *reinterpret_cast<const float2*>(&ph[((size_t)b << 7) + (lane << 1)]);
  float2 wv = *reinterpret_cast<const float2*>(&w2[lane << 1]);
  float s = hv.x * wv.x + hv.y * wv.y;
  for (int o = 1; o < 64; o <<= 1) s += __shfl_xor(s, o);
  if (lane == 0) out[b] = s + b2[0];
}

// ---------------- launcher ----------------
extern "C" void kernel_launch(void* const* d_in, const int* in_sizes, int n_in,
                              void* d_out, int out_size, void* d_ws, size_t ws_size,
                              hipStream_t stream) {
  const int* uid = (const int*)d_in[0];
  const int* iid = (const int*)d_in[1];
  const float* content = (const float*)d_in[2];
  const int* ei = (const int*)d_in[3];
  const float* uemb = (const float*)d_in[4];
  const float* iemb = (const float*)d_in[5];
  const float* wc = (const float*)d_in[6];
  const float* bc = (const float*)d_in[7];
  const float* w1 = (const float*)d_in[8];
  const float* att1s = (const float*)d_in[9];
  const float* att1d = (const float*)d_in[10];
  const float* b1 = (const float*)d_in[11];
  const float* w2 = (const float*)d_in[12];
  const float* att2s = (const float*)d_in[13];
  const float* att2d = (const float*)d_in[14];
  const float* b2c = (const float*)d_in[15];
  const float* pw1 = (const float*)d_in[16];
  const float* pb1 = (const float*)d_in[17];
  const float* pw2 = (const float*)d_in[18];
  const float* pb2 = (const float*)d_in[19];
  float* out = (float*)d_out;
  char* ws = (char*)d_ws;

  size_t off = 0;
  auto alloc = [&](size_t bytes) {
    size_t o = off;
    off += (bytes + 255) & ~(size_t)255;
    return o;
  };
  size_t o_winner  = alloc(NI * 4);
  size_t o_map     = alloc(NN * 4);
  size_t o_a1s     = alloc((size_t)NN * 2 * 4);
  size_t o_a1d     = alloc((size_t)NN * 2 * 4);
  size_t o_deg     = alloc(NN * 4);
  size_t o_rs      = alloc(NN * 4);
  size_t o_fill    = alloc(NN * 4);
  size_t o_cnt     = alloc(4);
  size_t o_col     = alloc((size_t)ET * 4);
  size_t o_a2s     = alloc(NN * 4);
  size_t o_a2d     = alloc(NN * 4);
  size_t o_qs      = alloc(256 * 4);
  size_t o_qd      = alloc(256 * 4);
  // region R1 (37.75MB): cemb(4.19M) | Xa(16.78M) | Ha(16.78M)
  // reuse after conv1: agg(16.78M)@0 | out2c(8.39M)@16.78M | ph(4.19M)@0 (after out2c GEMM)
  size_t o_r1      = alloc(4194304 + 16777216 + 16777216);
  size_t o_cemb  = o_r1;
  size_t o_xa    = o_r1 + 4194304;
  size_t o_ha    = o_r1 + 4194304 + 16777216;
  size_t o_agg   = o_r1;                       // alias cemb+Xa (dead)
  size_t o_out2c = o_r1 + 16777216;            // alias Ha start (dead)
  size_t o_ph    = o_r1;                       // alias agg (dead after out2c GEMM)
  // region R2: x1 [NN,256]
  size_t o_x1    = alloc((size_t)NN * 256 * 4);
  (void)ws_size; (void)in_sizes; (void)n_in; (void)out_size;

  int*   winner = (int*)(ws + o_winner);
  int*   map    = (int*)(ws + o_map);
  float* a1s    = (float*)(ws + o_a1s);
  float* a1d    = (float*)(ws + o_a1d);
  int*   deg    = (int*)(ws + o_deg);
  int*   rs     = (int*)(ws + o_rs);
  int*   fill   = (int*)(ws + o_fill);
  int*   cnt    = (int*)(ws + o_cnt);
  int*   col    = (int*)(ws + o_col);
  float* a2s    = (float*)(ws + o_a2s);
  float* a2d    = (float*)(ws + o_a2d);
  float* qs     = (float*)(ws + o_qs);
  float* qd     = (float*)(ws + o_qd);
  float* cemb   = (float*)(ws + o_cemb);
  float* Xa     = (float*)(ws + o_xa);
  float* Ha     = (float*)(ws + o_ha);
  float* agg    = (float*)(ws + o_agg);
  float* out2c  = (float*)(ws + o_out2c);
  float* ph     = (float*)(ws + o_ph);
  float* x1     = (float*)(ws + o_x1);

  // merged memsets over adjacent regions (pad bytes are don't-care)
  hipMemsetAsync(ws + o_winner, 0xFF, o_map - o_winner + (size_t)NN * 4, stream);    // winner|map
  hipMemsetAsync(ws + o_a1s, 0, o_a1d - o_a1s + (size_t)NN * 2 * 4, stream);          // a1s|a1d
  hipMemsetAsync(ws + o_deg, 0, o_cnt - o_deg + 4, stream);                           // deg|rs|fill|cnt

  winner_kernel<<<(BB + 255) / 256, 256, 0, stream>>>(iid, winner);
  // c_emb = content @ Wc^T + bc
  {
    dim3 g(BB / 64, DD / 64);
    gemm_bt<0><<<g, 256, 0, stream>>>(content, wc, bc, cemb, BB, DD, 512, 0,
                                      nullptr, nullptr, nullptr);
  }
  build_xa_kernel<<<NTASK, 64, 0, stream>>>(uid, iid, winner, uemb, iemb, cemb, Xa, map);
  deg_kernel<<<(ET + 255) / 256, 256, 0, stream>>>(ei, deg);
  rowstart_kernel<<<(NN + 255) / 256, 256, 0, stream>>>(deg, rs, fill, cnt);
  fill_kernel<<<(ET + 255) / 256, 256, 0, stream>>>(ei, fill, col);
  // Ha = Xa @ W1^T   [16384,256] x [256,256]^T -> grid 1024 blocks
  {
    dim3 g(NTASK / 64, 256 / 64);
    gemm_bt<0><<<g, 256, 0, stream>>>(Xa, w1, nullptr, Ha, NTASK, 256, 256, 0,
                                      nullptr, nullptr, nullptr);
  }
  a1q_kernel<<<NTASK + 4, 64, 0, stream>>>(uid, iid, Ha, att1s, att1d,
                                           w2, att2s, att2d, a1s, a1d, qs, qd);
  conv1_agg_kernel<<<NN / 4, 256, 0, stream>>>(col, rs, deg, Ha, map, a1s, a1d, b1,
                                               qs, qd, x1, a2s, a2d);
  conv2_agg_kernel<<<NTASK / 4, 256, 0, stream>>>(uid, iid, col, rs, deg, x1, a2s, a2d, agg);
  // out2c = agg @ W2^T + b2c   [16384,128]
  {
    dim3 g(NTASK / 64, DD / 64);
    gemm_bt<0><<<g, 256, 0, stream>>>(agg, w2, b2c, out2c, NTASK, DD, 256, 0,
                                      nullptr, nullptr, nullptr);
  }
  // ph = relu([uemb[uid] | out2c_item | out2c_user] @ pw1^T + pb1)  (gathered A)
  {
    dim3 g(BB / 64, DD / 64);
    gemm_bt<1><<<g, 256, 0, stream>>>(nullptr, pw1, pb1, ph, BB, DD, 384, 1,
                                      uid, uemb, out2c);
  }
  final_kernel<<<BB, 64, 0, stream>>>(ph, pw2, pb2, out);
}

// Round 5
// 243.434 us; speedup vs baseline: 1.8388x; 1.2603x over previous
//
#include <hip/hip_runtime.h>
#include <hip/hip_bf16.h>

#define NU 50000
#define NI 20000
#define NN 70000
#define DD 128
#define BB 8192
#define EE 500000
#define ET 570000   // EE + NN self loops
#define NTASK 16384 // 2*BB

__device__ __forceinline__ float lrelu(float x) { return x > 0.f ? x : 0.2f * x; }

typedef __attribute__((ext_vector_type(8))) short bf16x8;   // 8 bf16 = 4 VGPRs
typedef __attribute__((ext_vector_type(8))) unsigned short u16x8;
typedef __attribute__((ext_vector_type(4))) float f32x4;

__device__ __forceinline__ unsigned short f2bf_rne(float f) {
  unsigned int u = __builtin_bit_cast(unsigned int, f);
  u += 0x7FFFu + ((u >> 16) & 1u);
  return (unsigned short)(u >> 16);
}
__device__ __forceinline__ float bf2f(unsigned short h) {
  unsigned int u = ((unsigned int)h) << 16;
  return __builtin_bit_cast(float, u);
}

// ---------------- split weights into bf16 hi/lo (4 segments, one launch) ----------
__global__ void split4_kernel(const float* __restrict__ w0, unsigned short* h0, unsigned short* l0, int n0,
                              const float* __restrict__ w1, unsigned short* h1, unsigned short* l1, int n1,
                              const float* __restrict__ w2, unsigned short* h2, unsigned short* l2, int n2,
                              const float* __restrict__ w3, unsigned short* h3, unsigned short* l3, int n3) {
  int i = blockIdx.x * 256 + threadIdx.x;
  const float* w; unsigned short* h; unsigned short* l; int idx;
  if (i < n0) { w = w0; h = h0; l = l0; idx = i; }
  else if (i < n0 + n1) { w = w1; h = h1; l = l1; idx = i - n0; }
  else if (i < n0 + n1 + n2) { w = w2; h = h2; l = l2; idx = i - n0 - n1; }
  else if (i < n0 + n1 + n2 + n3) { w = w3; h = h3; l = l3; idx = i - n0 - n1 - n2; }
  else return;
  float f = w[idx];
  unsigned short hh = f2bf_rne(f);
  h[idx] = hh;
  l[idx] = (unsigned short)(__builtin_bit_cast(unsigned int, f - bf2f(hh)) >> 16);
}

// ---------------- MFMA GEMM: C[M,N] = A[M,K] * Bt[N,K]^T (+bias)(+relu) -----------
// A f32 (split on the fly), Bt pre-split bf16 hi/lo. 64x64 tile, BK=64, 256 thr.
// 4 waves in 2x2; each wave 32x32 = 2x2 frags of mfma_f32_16x16x32_bf16.
// 3-term split product: hi*hi + hi*lo + lo*hi (f32 accumulate).
// LDS frag-major [kb][row][8] -> all ds_read_b128 conflict-free.
// GATHER=1: logical A row r = [gA0[uidx[r]] | gA1[BB+r] | gA1[r]] (128 cols each).
template <int GATHER>
__global__ __launch_bounds__(256) void gemm_mfma(
    const float* __restrict__ A,
    const unsigned short* __restrict__ Bh, const unsigned short* __restrict__ Bl,
    const float* __restrict__ bias, float* __restrict__ C,
    int M, int N, int K, int act,
    const int* __restrict__ uidx, const float* __restrict__ gA0,
    const float* __restrict__ gA1) {
  __shared__ __align__(16) unsigned short sAh[8][64][8];
  __shared__ __align__(16) unsigned short sAl[8][64][8];
  __shared__ __align__(16) unsigned short sBh[8][64][8];
  __shared__ __align__(16) unsigned short sBl[8][64][8];
  int tid = threadIdx.x;
  int bm = blockIdx.x * 64, bn = blockIdx.y * 64;
  int lane = tid & 63, w = tid >> 6;
  int wr = (w >> 1) * 32, wc = (w & 1) * 32;
  int fr = lane & 15, fk = lane >> 4;   // fragment row/col, k-octet
  f32x4 acc[2][2] = {};

  for (int k0 = 0; k0 < K; k0 += 64) {
    __syncthreads();
    // stage A (2 sub-steps) and B (2 sub-steps): 512 (row,kb) pairs each
#pragma unroll
    for (int t = 0; t < 2; t++) {
      int f = tid + t * 256;
      int row = f >> 3, kb = f & 7;
      int kg = k0 + kb * 8;
      const float* ap;
      if (GATHER) {
        int sec = kg >> 7;            // 64-tiles never straddle 128-col sections
        int kc = kg & 127;
        int r = bm + row;
        if (sec == 0)      ap = &gA0[(size_t)uidx[r] * 128 + kc];
        else if (sec == 1) ap = &gA1[((size_t)(BB + r)) * 128 + kc];
        else               ap = &gA1[((size_t)r) * 128 + kc];
      } else {
        ap = &A[(size_t)(bm + row) * K + kg];
      }
      float4 v0 = *reinterpret_cast<const float4*>(ap);
      float4 v1 = *reinterpret_cast<const float4*>(ap + 4);
      float vv[8] = {v0.x, v0.y, v0.z, v0.w, v1.x, v1.y, v1.z, v1.w};
      u16x8 hv, lv;
#pragma unroll
      for (int j = 0; j < 8; j++) {
        unsigned short hh = f2bf_rne(vv[j]);
        hv[j] = hh;
        lv[j] = (unsigned short)(__builtin_bit_cast(unsigned int, vv[j] - bf2f(hh)) >> 16);
      }
      *reinterpret_cast<u16x8*>(&sAh[kb][row][0]) = hv;
      *reinterpret_cast<u16x8*>(&sAl[kb][row][0]) = lv;
    }
#pragma unroll
    for (int t = 0; t < 2; t++) {
      int f = tid + t * 256;
      int row = f >> 3, kb = f & 7;
      int kg = k0 + kb * 8;
      *reinterpret_cast<u16x8*>(&sBh[kb][row][0]) =
          *reinterpret_cast<const u16x8*>(&Bh[(size_t)(bn + row) * K + kg]);
      *reinterpret_cast<u16x8*>(&sBl[kb][row][0]) =
          *reinterpret_cast<const u16x8*>(&Bl[(size_t)(bn + row) * K + kg]);
    }
    __syncthreads();
#pragma unroll
    for (int s = 0; s < 2; s++) {
      int kb = s * 4 + fk;
      bf16x8 ah0 = *reinterpret_cast<const bf16x8*>(&sAh[kb][wr + fr][0]);
      bf16x8 ah1 = *reinterpret_cast<const bf16x8*>(&sAh[kb][wr + 16 + fr][0]);
      bf16x8 al0 = *reinterpret_cast<const bf16x8*>(&sAl[kb][wr + fr][0]);
      bf16x8 al1 = *reinterpret_cast<const bf16x8*>(&sAl[kb][wr + 16 + fr][0]);
      bf16x8 bh0 = *reinterpret_cast<const bf16x8*>(&sBh[kb][wc + fr][0]);
      bf16x8 bh1 = *reinterpret_cast<const bf16x8*>(&sBh[kb][wc + 16 + fr][0]);
      bf16x8 bl0 = *reinterpret_cast<const bf16x8*>(&sBl[kb][wc + fr][0]);
      bf16x8 bl1 = *reinterpret_cast<const bf16x8*>(&sBl[kb][wc + 16 + fr][0]);
      acc[0][0] = __builtin_amdgcn_mfma_f32_16x16x32_bf16(al0, bh0, acc[0][0], 0, 0, 0);
      acc[0][0] = __builtin_amdgcn_mfma_f32_16x16x32_bf16(ah0, bl0, acc[0][0], 0, 0, 0);
      acc[0][0] = __builtin_amdgcn_mfma_f32_16x16x32_bf16(ah0, bh0, acc[0][0], 0, 0, 0);
      acc[0][1] = __builtin_amdgcn_mfma_f32_16x16x32_bf16(al0, bh1, acc[0][1], 0, 0, 0);
      acc[0][1] = __builtin_amdgcn_mfma_f32_16x16x32_bf16(ah0, bl1, acc[0][1], 0, 0, 0);
      acc[0][1] = __builtin_amdgcn_mfma_f32_16x16x32_bf16(ah0, bh1, acc[0][1], 0, 0, 0);
      acc[1][0] = __builtin_amdgcn_mfma_f32_16x16x32_bf16(al1, bh0, acc[1][0], 0, 0, 0);
      acc[1][0] = __builtin_amdgcn_mfma_f32_16x16x32_bf16(ah1, bl0, acc[1][0], 0, 0, 0);
      acc[1][0] = __builtin_amdgcn_mfma_f32_16x16x32_bf16(ah1, bh0, acc[1][0], 0, 0, 0);
      acc[1][1] = __builtin_amdgcn_mfma_f32_16x16x32_bf16(al1, bh1, acc[1][1], 0, 0, 0);
      acc[1][1] = __builtin_amdgcn_mfma_f32_16x16x32_bf16(ah1, bl1, acc[1][1], 0, 0, 0);
      acc[1][1] = __builtin_amdgcn_mfma_f32_16x16x32_bf16(ah1, bh1, acc[1][1], 0, 0, 0);
    }
  }
  // epilogue: C[bm+wr+i*16+fk*4+r][bn+wc+j*16+fr]
#pragma unroll
  for (int j = 0; j < 2; j++) {
    int col = bn + wc + j * 16 + fr;
    float bj = bias ? bias[col] : 0.f;
#pragma unroll
    for (int i = 0; i < 2; i++) {
#pragma unroll
      for (int r = 0; r < 4; r++) {
        int row = bm + wr + i * 16 + fk * 4 + r;
        float v = acc[i][j][r] + bj;
        if (act == 1) v = fmaxf(v, 0.f);
        C[(size_t)row * N + col] = v;
      }
    }
  }
}

// ---------------- small kernels ----------------
__global__ void winner_kernel(const int* __restrict__ iid, int* __restrict__ winner) {
  int b = blockIdx.x * 256 + threadIdx.x;
  if (b >= BB) return;
  atomicMax(&winner[iid[b]], b);
}

__global__ void build_xa_kernel(const int* __restrict__ uid, const int* __restrict__ iid,
                                const int* __restrict__ winner,
                                const float* __restrict__ uemb, const float* __restrict__ iemb,
                                const float* __restrict__ cemb,
                                float* __restrict__ Xa, int* __restrict__ map) {
  int t = blockIdx.x;
  int lane = threadIdx.x;  // 64
  int c4 = lane * 4;
  float4 v = make_float4(0.f, 0.f, 0.f, 0.f);
  int node;
  if (t < BB) {
    int u = uid[t];
    node = u;
    if (c4 < DD) v = *reinterpret_cast<const float4*>(&uemb[(size_t)u * DD + c4]);
  } else {
    int b = t - BB;
    int it = iid[b];
    node = NU + it;
    if (c4 < DD) {
      v = *reinterpret_cast<const float4*>(&iemb[(size_t)it * DD + c4]);
    } else {
      int wb = winner[it];
      v = *reinterpret_cast<const float4*>(&cemb[(size_t)wb * DD + (c4 - DD)]);
    }
  }
  *reinterpret_cast<float4*>(&Xa[(size_t)t * 256 + c4]) = v;
  if (lane == 0) map[node] = t;  // duplicate tasks have identical rows -> benign
}

__global__ void deg_kernel(const int* __restrict__ ei, int* __restrict__ deg) {
  int e = blockIdx.x * 256 + threadIdx.x;
  if (e >= ET) return;
  int dst = (e < EE) ? ei[EE + e] : (e - EE);
  atomicAdd(&deg[dst], 1);
}

__global__ void rowstart_kernel(const int* __restrict__ deg, int* __restrict__ rowstart,
                                int* __restrict__ fill, int* __restrict__ counter) {
  int v = blockIdx.x * 256 + threadIdx.x;
  if (v >= NN) return;
  int s = atomicAdd(counter, deg[v]);
  rowstart[v] = s;
  fill[v] = s;
}

__global__ void fill_kernel(const int* __restrict__ ei, int* __restrict__ fill,
                            int* __restrict__ col) {
  int e = blockIdx.x * 256 + threadIdx.x;
  if (e >= ET) return;
  int src, dst;
  if (e < EE) { src = ei[e]; dst = ei[EE + e]; }
  else { src = e - EE; dst = src; }
  int pos = atomicAdd(&fill[dst], 1);
  col[pos] = src;
}

// a1 scores for the 16384 tasks; last 4 blocks compute the conv2 q-vectors.
__global__ void a1q_kernel(const int* __restrict__ uid, const int* __restrict__ iid,
                           const float* __restrict__ Ha,
                           const float* __restrict__ atts, const float* __restrict__ attd,
                           const float* __restrict__ w2,
                           const float* __restrict__ att2s, const float* __restrict__ att2d,
                           float* __restrict__ a1s, float* __restrict__ a1d,
                           float* __restrict__ qs, float* __restrict__ qd) {
  int t = blockIdx.x, lane = threadIdx.x;  // 64
  if (t >= NTASK) {
    int k = (t - NTASK) * 64 + lane;  // 0..255
    float s = 0.f, d = 0.f;
#pragma unroll 4
    for (int j = 0; j < DD; j++) {
      float w = w2[(size_t)j * 256 + k];
      s += att2s[j] * w;
      d += att2d[j] * w;
    }
    qs[k] = s;
    qd[k] = d;
    return;
  }
  int v = (t < BB) ? uid[t] : NU + iid[t - BB];
  int head = lane >> 5, c = (lane & 31) * 4;
  float4 hv = *reinterpret_cast<const float4*>(&Ha[(size_t)t * 256 + head * DD + c]);
  float4 sv = *reinterpret_cast<const float4*>(&atts[head * DD + c]);
  float4 dv = *reinterpret_cast<const float4*>(&attd[head * DD + c]);
  float ps = hv.x * sv.x + hv.y * sv.y + hv.z * sv.z + hv.w * sv.w;
  float pd = hv.x * dv.x + hv.y * dv.y + hv.z * dv.z + hv.w * dv.w;
  for (int o = 1; o < 32; o <<= 1) { ps += __shfl_xor(ps, o); pd += __shfl_xor(pd, o); }
  if ((lane & 31) == 0) {
    a1s[(size_t)v * 2 + head] = ps;
    a1d[(size_t)v * 2 + head] = pd;
  }
}

// conv1 aggregation: lane-parallel edges, online softmax, fused ELU+bias and
// fused conv2-score computation (a2s/a2d) in the epilogue. 4 nodes/block.
__global__ __launch_bounds__(256) void conv1_agg_kernel(
    const int* __restrict__ col, const int* __restrict__ rowstart,
    const int* __restrict__ deg, const float* __restrict__ Ha,
    const int* __restrict__ map,
    const float* __restrict__ a1s, const float* __restrict__ a1d,
    const float* __restrict__ bias,
    const float* __restrict__ qs, const float* __restrict__ qd,
    float* __restrict__ x1, float* __restrict__ a2s, float* __restrict__ a2d) {
  int v = blockIdx.x * 4 + (threadIdx.x >> 6);  // NN divisible by 4
  int lane = threadIdx.x & 63;
  int head = lane >> 5;
  int d = deg[v], s0 = rowstart[v];
  float2 adv = *reinterpret_cast<const float2*>(&a1d[(size_t)v * 2]);
  float m0 = -1e30f, m1 = -1e30f, den0 = 0.f, den1 = 0.f;
  float4 acc = make_float4(0.f, 0.f, 0.f, 0.f);
  for (int c0 = 0; c0 < d; c0 += 64) {
    int i = c0 + lane;
    bool act = i < d;
    int ci = act ? col[s0 + i] : 0;
    float2 asv = make_float2(0.f, 0.f);
    int ri = -1;
    if (act) {
      asv = *reinterpret_cast<const float2*>(&a1s[(size_t)ci * 2]);
      ri = map[ci];
    }
    float al0 = act ? lrelu(asv.x + adv.x) : -1e30f;
    float al1 = act ? lrelu(asv.y + adv.y) : -1e30f;
    float cm0 = al0, cm1 = al1;
#pragma unroll
    for (int o = 1; o < 64; o <<= 1) {
      cm0 = fmaxf(cm0, __shfl_xor(cm0, o));
      cm1 = fmaxf(cm1, __shfl_xor(cm1, o));
    }
    float nm0 = fmaxf(m0, cm0), nm1 = fmaxf(m1, cm1);
    float ex0 = act ? __expf(al0 - nm0) : 0.f;
    float ex1 = act ? __expf(al1 - nm1) : 0.f;
    float s0f = __expf(m0 - nm0), s1f = __expf(m1 - nm1);
    float cs0 = ex0, cs1 = ex1;
#pragma unroll
    for (int o = 1; o < 64; o <<= 1) {
      cs0 += __shfl_xor(cs0, o);
      cs1 += __shfl_xor(cs1, o);
    }
    den0 = den0 * s0f + cs0;
    den1 = den1 * s1f + cs1;
    float sc = head ? s1f : s0f;
    acc.x *= sc; acc.y *= sc; acc.z *= sc; acc.w *= sc;
    int n = min(64, d - c0);
    for (int i2 = 0; i2 < n; i2++) {
      int r = __shfl(ri, i2);
      if (r >= 0) {
        float e0 = __shfl(ex0, i2), e1 = __shfl(ex1, i2);
        float ex = head ? e1 : e0;
        float4 hv = *reinterpret_cast<const float4*>(&Ha[((size_t)r << 8) + (lane << 2)]);
        acc.x += ex * hv.x; acc.y += ex * hv.y; acc.z += ex * hv.z; acc.w += ex * hv.w;
      }
    }
    m0 = nm0; m1 = nm1;
  }
  float inv = 1.f / (head ? den1 : den0);
  float4 b4 = *reinterpret_cast<const float4*>(&bias[lane << 2]);
  float4 o;
  o.x = acc.x * inv + b4.x;
  o.y = acc.y * inv + b4.y;
  o.z = acc.z * inv + b4.z;
  o.w = acc.w * inv + b4.w;
  o.x = o.x > 0.f ? o.x : expm1f(o.x);
  o.y = o.y > 0.f ? o.y : expm1f(o.y);
  o.z = o.z > 0.f ? o.z : expm1f(o.z);
  o.w = o.w > 0.f ? o.w : expm1f(o.w);
  *reinterpret_cast<float4*>(&x1[((size_t)v << 8) + (lane << 2)]) = o;
  // fused conv2 scores: a2s[v] = x1[v].qs, a2d[v] = x1[v].qd
  float4 sv = *reinterpret_cast<const float4*>(&qs[lane << 2]);
  float4 dv = *reinterpret_cast<const float4*>(&qd[lane << 2]);
  float ps = o.x * sv.x + o.y * sv.y + o.z * sv.z + o.w * sv.w;
  float pd = o.x * dv.x + o.y * dv.y + o.z * dv.z + o.w * dv.w;
#pragma unroll
  for (int of = 1; of < 64; of <<= 1) { ps += __shfl_xor(ps, of); pd += __shfl_xor(pd, of); }
  if (lane == 0) { a2s[v] = ps; a2d[v] = pd; }
}

// conv2 aggregation in x1-space (256-d), batch tasks only. 4 tasks/block.
__global__ __launch_bounds__(256) void conv2_agg_kernel(
    const int* __restrict__ uid, const int* __restrict__ iid,
    const int* __restrict__ col, const int* __restrict__ rowstart,
    const int* __restrict__ deg, const float* __restrict__ x1,
    const float* __restrict__ a2s, const float* __restrict__ a2d,
    float* __restrict__ agg) {
  int t = blockIdx.x * 4 + (threadIdx.x >> 6);  // NTASK divisible by 4
  int lane = threadIdx.x & 63;
  int v = (t < BB) ? uid[t] : NU + iid[t - BB];
  int d = deg[v], s0 = rowstart[v];
  float ad = a2d[v];
  float m = -1e30f, den = 0.f;
  float4 acc = make_float4(0.f, 0.f, 0.f, 0.f);
  for (int c0 = 0; c0 < d; c0 += 64) {
    int i = c0 + lane;
    bool act = i < d;
    int ci = act ? col[s0 + i] : 0;
    float as = act ? a2s[ci] : 0.f;
    float al = act ? lrelu(as + ad) : -1e30f;
    float cm = al;
#pragma unroll
    for (int o = 1; o < 64; o <<= 1) cm = fmaxf(cm, __shfl_xor(cm, o));
    float nm = fmaxf(m, cm);
    float ex = act ? __expf(al - nm) : 0.f;
    float sf = __expf(m - nm);
    float cs = ex;
#pragma unroll
    for (int o = 1; o < 64; o <<= 1) cs += __shfl_xor(cs, o);
    den = den * sf + cs;
    acc.x *= sf; acc.y *= sf; acc.z *= sf; acc.w *= sf;
    int n = min(64, d - c0);
    for (int i2 = 0; i2 < n; i2++) {
      int r = __shfl(ci, i2);
      float e = __shfl(ex, i2);
      float4 hv = *reinterpret_cast<const float4*>(&x1[((size_t)r << 8) + (lane << 2)]);
      acc.x += e * hv.x; acc.y += e * hv.y; acc.z += e * hv.z; acc.w += e * hv.w;
    }
    m = nm;
  }
  float inv = 1.f / den;
  float4 o = make_float4(acc.x * inv, acc.y * inv, acc.z * inv, acc.w * inv);
  *reinterpret_cast<float4*>(&agg[((size_t)t << 8) + (lane << 2)]) = o;
}

__global__ void final_kernel(const float* __restrict__ ph, const float* __restrict__ w2,
                             const float* __restrict__ b2, float* __restrict__ out) {
  int b = blockIdx.x, lane = threadIdx.x;  // 64
  float2 hv = *reinterpret_cast<const float2*>(&ph[((size_t)b << 7) + (lane << 1)]);
  float2 wv = *reinterpret_cast<const float2*>(&w2[lane << 1]);
  float s = hv.x * wv.x + hv.y * wv.y;
  for (int o = 1; o < 64; o <<= 1) s += __shfl_xor(s, o);
  if (lane == 0) out[b] = s + b2[0];
}

// ---------------- launcher ----------------
extern "C" void kernel_launch(void* const* d_in, const int* in_sizes, int n_in,
                              void* d_out, int out_size, void* d_ws, size_t ws_size,
                              hipStream_t stream) {
  const int* uid = (const int*)d_in[0];
  const int* iid = (const int*)d_in[1];
  const float* content = (const float*)d_in[2];
  const int* ei = (const int*)d_in[3];
  const float* uemb = (const float*)d_in[4];
  const float* iemb = (const float*)d_in[5];
  const float* wc = (const float*)d_in[6];
  const float* bc = (const float*)d_in[7];
  const float* w1 = (const float*)d_in[8];
  const float* att1s = (const float*)d_in[9];
  const float* att1d = (const float*)d_in[10];
  const float* b1 = (const float*)d_in[11];
  const float* w2 = (const float*)d_in[12];
  const float* att2s = (const float*)d_in[13];
  const float* att2d = (const float*)d_in[14];
  const float* b2c = (const float*)d_in[15];
  const float* pw1 = (const float*)d_in[16];
  const float* pb1 = (const float*)d_in[17];
  const float* pw2 = (const float*)d_in[18];
  const float* pb2 = (const float*)d_in[19];
  float* out = (float*)d_out;
  char* ws = (char*)d_ws;

  size_t off = 0;
  auto alloc = [&](size_t bytes) {
    size_t o = off;
    off += (bytes + 255) & ~(size_t)255;
    return o;
  };
  size_t o_winner  = alloc(NI * 4);
  size_t o_map     = alloc(NN * 4);
  size_t o_a1s     = alloc((size_t)NN * 2 * 4);
  size_t o_a1d     = alloc((size_t)NN * 2 * 4);
  size_t o_deg     = alloc(NN * 4);
  size_t o_rs      = alloc(NN * 4);
  size_t o_fill    = alloc(NN * 4);
  size_t o_cnt     = alloc(4);
  size_t o_col     = alloc((size_t)ET * 4);
  size_t o_a2s     = alloc(NN * 4);
  size_t o_a2d     = alloc(NN * 4);
  size_t o_qs      = alloc(256 * 4);
  size_t o_qd      = alloc(256 * 4);
  // split weights (bf16 hi/lo): wc 128x512, w1 256x256, w2 128x256, pw1 128x384
  size_t o_wch = alloc(65536 * 2),  o_wcl = alloc(65536 * 2);
  size_t o_w1h = alloc(65536 * 2),  o_w1l = alloc(65536 * 2);
  size_t o_w2h = alloc(32768 * 2),  o_w2l = alloc(32768 * 2);
  size_t o_p1h = alloc(49152 * 2),  o_p1l = alloc(49152 * 2);
  // region R1 (37.75MB): cemb(4.19M) | Xa(16.78M) | Ha(16.78M)
  // reuse after conv1: agg(16.78M)@0 | out2c(8.39M)@16.78M | ph(4.19M)@0 (after out2c GEMM)
  size_t o_r1      = alloc(4194304 + 16777216 + 16777216);
  size_t o_cemb  = o_r1;
  size_t o_xa    = o_r1 + 4194304;
  size_t o_ha    = o_r1 + 4194304 + 16777216;
  size_t o_agg   = o_r1;                       // alias cemb+Xa (dead)
  size_t o_out2c = o_r1 + 16777216;            // alias Ha start (dead)
  size_t o_ph    = o_r1;                       // alias agg (dead after out2c GEMM)
  // region R2: x1 [NN,256]
  size_t o_x1    = alloc((size_t)NN * 256 * 4);
  (void)ws_size; (void)in_sizes; (void)n_in; (void)out_size;

  int*   winner = (int*)(ws + o_winner);
  int*   map    = (int*)(ws + o_map);
  float* a1s    = (float*)(ws + o_a1s);
  float* a1d    = (float*)(ws + o_a1d);
  int*   deg    = (int*)(ws + o_deg);
  int*   rs     = (int*)(ws + o_rs);
  int*   fill   = (int*)(ws + o_fill);
  int*   cnt    = (int*)(ws + o_cnt);
  int*   col    = (int*)(ws + o_col);
  float* a2s    = (float*)(ws + o_a2s);
  float* a2d    = (float*)(ws + o_a2d);
  float* qs     = (float*)(ws + o_qs);
  float* qd     = (float*)(ws + o_qd);
  unsigned short* wch = (unsigned short*)(ws + o_wch);
  unsigned short* wcl = (unsigned short*)(ws + o_wcl);
  unsigned short* w1h = (unsigned short*)(ws + o_w1h);
  unsigned short* w1l = (unsigned short*)(ws + o_w1l);
  unsigned short* w2h = (unsigned short*)(ws + o_w2h);
  unsigned short* w2l = (unsigned short*)(ws + o_w2l);
  unsigned short* p1h = (unsigned short*)(ws + o_p1h);
  unsigned short* p1l = (unsigned short*)(ws + o_p1l);
  float* cemb   = (float*)(ws + o_cemb);
  float* Xa     = (float*)(ws + o_xa);
  float* Ha     = (float*)(ws + o_ha);
  float* agg    = (float*)(ws + o_agg);
  float* out2c  = (float*)(ws + o_out2c);
  float* ph     = (float*)(ws + o_ph);
  float* x1     = (float*)(ws + o_x1);

  // merged memsets over adjacent regions (pad bytes are don't-care)
  hipMemsetAsync(ws + o_winner, 0xFF, o_map - o_winner + (size_t)NN * 4, stream);    // winner|map
  hipMemsetAsync(ws + o_a1s, 0, o_a1d - o_a1s + (size_t)NN * 2 * 4, stream);          // a1s|a1d
  hipMemsetAsync(ws + o_deg, 0, o_cnt - o_deg + 4, stream);                           // deg|rs|fill|cnt

  // split the four weight matrices into bf16 hi/lo
  {
    int total = 65536 + 65536 + 32768 + 49152;
    split4_kernel<<<(total + 255) / 256, 256, 0, stream>>>(
        wc, wch, wcl, 65536, w1, w1h, w1l, 65536,
        w2, w2h, w2l, 32768, pw1, p1h, p1l, 49152);
  }
  winner_kernel<<<(BB + 255) / 256, 256, 0, stream>>>(iid, winner);
  // c_emb = content @ Wc^T + bc
  {
    dim3 g(BB / 64, DD / 64);
    gemm_mfma<0><<<g, 256, 0, stream>>>(content, wch, wcl, bc, cemb, BB, DD, 512, 0,
                                        nullptr, nullptr, nullptr);
  }
  build_xa_kernel<<<NTASK, 64, 0, stream>>>(uid, iid, winner, uemb, iemb, cemb, Xa, map);
  deg_kernel<<<(ET + 255) / 256, 256, 0, stream>>>(ei, deg);
  rowstart_kernel<<<(NN + 255) / 256, 256, 0, stream>>>(deg, rs, fill, cnt);
  fill_kernel<<<(ET + 255) / 256, 256, 0, stream>>>(ei, fill, col);
  // Ha = Xa @ W1^T   [16384,256] x [256,256]^T -> grid 1024 blocks
  {
    dim3 g(NTASK / 64, 256 / 64);
    gemm_mfma<0><<<g, 256, 0, stream>>>(Xa, w1h, w1l, nullptr, Ha, NTASK, 256, 256, 0,
                                        nullptr, nullptr, nullptr);
  }
  a1q_kernel<<<NTASK + 4, 64, 0, stream>>>(uid, iid, Ha, att1s, att1d,
                                           w2, att2s, att2d, a1s, a1d, qs, qd);
  conv1_agg_kernel<<<NN / 4, 256, 0, stream>>>(col, rs, deg, Ha, map, a1s, a1d, b1,
                                               qs, qd, x1, a2s, a2d);
  conv2_agg_kernel<<<NTASK / 4, 256, 0, stream>>>(uid, iid, col, rs, deg, x1, a2s, a2d, agg);
  // out2c = agg @ W2^T + b2c   [16384,128]
  {
    dim3 g(NTASK / 64, DD / 64);
    gemm_mfma<0><<<g, 256, 0, stream>>>(agg, w2h, w2l, b2c, out2c, NTASK, DD, 256, 0,
                                        nullptr, nullptr, nullptr);
  }
  // ph = relu([uemb[uid] | out2c_item | out2c_user] @ pw1^T + pb1)  (gathered A)
  {
    dim3 g(BB / 64, DD / 64);
    gemm_mfma<1><<<g, 256, 0, stream>>>(nullptr, p1h, p1l, pb1, ph, BB, DD, 384, 1,
                                        uid, uemb, out2c);
  }
  final_kernel<<<BB, 64, 0, stream>>>(ph, pw2, pb2, out);
}

// Round 6
// 230.492 us; speedup vs baseline: 1.9420x; 1.0562x over previous
//
#include <hip/hip_runtime.h>
#include <hip/hip_bf16.h>

#define NU 50000
#define NI 20000
#define NN 70000
#define DD 128
#define BB 8192
#define EE 500000
#define ET 570000   // EE + NN self loops
#define NTASK 16384 // 2*BB

__device__ __forceinline__ float lrelu(float x) { return x > 0.f ? x : 0.2f * x; }

typedef __attribute__((ext_vector_type(8))) short bf16x8;   // 8 bf16 = 4 VGPRs
typedef __attribute__((ext_vector_type(8))) unsigned short u16x8;
typedef __attribute__((ext_vector_type(4))) float f32x4;

__device__ __forceinline__ unsigned short f2bf_rne(float f) {
  unsigned int u = __builtin_bit_cast(unsigned int, f);
  u += 0x7FFFu + ((u >> 16) & 1u);
  return (unsigned short)(u >> 16);
}
__device__ __forceinline__ float bf2f(unsigned short h) {
  unsigned int u = ((unsigned int)h) << 16;
  return __builtin_bit_cast(float, u);
}

// ---------------- split weights into bf16 hi/lo (4 segments, one launch) ----------
__global__ void split4_kernel(const float* __restrict__ w0, unsigned short* h0, unsigned short* l0, int n0,
                              const float* __restrict__ w1, unsigned short* h1, unsigned short* l1, int n1,
                              const float* __restrict__ w2, unsigned short* h2, unsigned short* l2, int n2,
                              const float* __restrict__ w3, unsigned short* h3, unsigned short* l3, int n3) {
  int i = blockIdx.x * 256 + threadIdx.x;
  const float* w; unsigned short* h; unsigned short* l; int idx;
  if (i < n0) { w = w0; h = h0; l = l0; idx = i; }
  else if (i < n0 + n1) { w = w1; h = h1; l = l1; idx = i - n0; }
  else if (i < n0 + n1 + n2) { w = w2; h = h2; l = l2; idx = i - n0 - n1; }
  else if (i < n0 + n1 + n2 + n3) { w = w3; h = h3; l = l3; idx = i - n0 - n1 - n2; }
  else return;
  float f = w[idx];
  unsigned short hh = f2bf_rne(f);
  h[idx] = hh;
  l[idx] = (unsigned short)(__builtin_bit_cast(unsigned int, f - bf2f(hh)) >> 16);
}

// ---------------- MFMA GEMM: C[M,N] = A[M,K] * Bt[N,K]^T (+bias)(+relu) -----------
// (unchanged from R5 — verified working)
template <int GATHER>
__global__ __launch_bounds__(256) void gemm_mfma(
    const float* __restrict__ A,
    const unsigned short* __restrict__ Bh, const unsigned short* __restrict__ Bl,
    const float* __restrict__ bias, float* __restrict__ C,
    int M, int N, int K, int act,
    const int* __restrict__ uidx, const float* __restrict__ gA0,
    const float* __restrict__ gA1) {
  __shared__ __align__(16) unsigned short sAh[8][64][8];
  __shared__ __align__(16) unsigned short sAl[8][64][8];
  __shared__ __align__(16) unsigned short sBh[8][64][8];
  __shared__ __align__(16) unsigned short sBl[8][64][8];
  int tid = threadIdx.x;
  int bm = blockIdx.x * 64, bn = blockIdx.y * 64;
  int lane = tid & 63, w = tid >> 6;
  int wr = (w >> 1) * 32, wc = (w & 1) * 32;
  int fr = lane & 15, fk = lane >> 4;
  f32x4 acc[2][2] = {};

  for (int k0 = 0; k0 < K; k0 += 64) {
    __syncthreads();
#pragma unroll
    for (int t = 0; t < 2; t++) {
      int f = tid + t * 256;
      int row = f >> 3, kb = f & 7;
      int kg = k0 + kb * 8;
      const float* ap;
      if (GATHER) {
        int sec = kg >> 7;
        int kc = kg & 127;
        int r = bm + row;
        if (sec == 0)      ap = &gA0[(size_t)uidx[r] * 128 + kc];
        else if (sec == 1) ap = &gA1[((size_t)(BB + r)) * 128 + kc];
        else               ap = &gA1[((size_t)r) * 128 + kc];
      } else {
        ap = &A[(size_t)(bm + row) * K + kg];
      }
      float4 v0 = *reinterpret_cast<const float4*>(ap);
      float4 v1 = *reinterpret_cast<const float4*>(ap + 4);
      float vv[8] = {v0.x, v0.y, v0.z, v0.w, v1.x, v1.y, v1.z, v1.w};
      u16x8 hv, lv;
#pragma unroll
      for (int j = 0; j < 8; j++) {
        unsigned short hh = f2bf_rne(vv[j]);
        hv[j] = hh;
        lv[j] = (unsigned short)(__builtin_bit_cast(unsigned int, vv[j] - bf2f(hh)) >> 16);
      }
      *reinterpret_cast<u16x8*>(&sAh[kb][row][0]) = hv;
      *reinterpret_cast<u16x8*>(&sAl[kb][row][0]) = lv;
    }
#pragma unroll
    for (int t = 0; t < 2; t++) {
      int f = tid + t * 256;
      int row = f >> 3, kb = f & 7;
      int kg = k0 + kb * 8;
      *reinterpret_cast<u16x8*>(&sBh[kb][row][0]) =
          *reinterpret_cast<const u16x8*>(&Bh[(size_t)(bn + row) * K + kg]);
      *reinterpret_cast<u16x8*>(&sBl[kb][row][0]) =
          *reinterpret_cast<const u16x8*>(&Bl[(size_t)(bn + row) * K + kg]);
    }
    __syncthreads();
#pragma unroll
    for (int s = 0; s < 2; s++) {
      int kb = s * 4 + fk;
      bf16x8 ah0 = *reinterpret_cast<const bf16x8*>(&sAh[kb][wr + fr][0]);
      bf16x8 ah1 = *reinterpret_cast<const bf16x8*>(&sAh[kb][wr + 16 + fr][0]);
      bf16x8 al0 = *reinterpret_cast<const bf16x8*>(&sAl[kb][wr + fr][0]);
      bf16x8 al1 = *reinterpret_cast<const bf16x8*>(&sAl[kb][wr + 16 + fr][0]);
      bf16x8 bh0 = *reinterpret_cast<const bf16x8*>(&sBh[kb][wc + fr][0]);
      bf16x8 bh1 = *reinterpret_cast<const bf16x8*>(&sBh[kb][wc + 16 + fr][0]);
      bf16x8 bl0 = *reinterpret_cast<const bf16x8*>(&sBl[kb][wc + fr][0]);
      bf16x8 bl1 = *reinterpret_cast<const bf16x8*>(&sBl[kb][wc + 16 + fr][0]);
      acc[0][0] = __builtin_amdgcn_mfma_f32_16x16x32_bf16(al0, bh0, acc[0][0], 0, 0, 0);
      acc[0][0] = __builtin_amdgcn_mfma_f32_16x16x32_bf16(ah0, bl0, acc[0][0], 0, 0, 0);
      acc[0][0] = __builtin_amdgcn_mfma_f32_16x16x32_bf16(ah0, bh0, acc[0][0], 0, 0, 0);
      acc[0][1] = __builtin_amdgcn_mfma_f32_16x16x32_bf16(al0, bh1, acc[0][1], 0, 0, 0);
      acc[0][1] = __builtin_amdgcn_mfma_f32_16x16x32_bf16(ah0, bl1, acc[0][1], 0, 0, 0);
      acc[0][1] = __builtin_amdgcn_mfma_f32_16x16x32_bf16(ah0, bh1, acc[0][1], 0, 0, 0);
      acc[1][0] = __builtin_amdgcn_mfma_f32_16x16x32_bf16(al1, bh0, acc[1][0], 0, 0, 0);
      acc[1][0] = __builtin_amdgcn_mfma_f32_16x16x32_bf16(ah1, bl0, acc[1][0], 0, 0, 0);
      acc[1][0] = __builtin_amdgcn_mfma_f32_16x16x32_bf16(ah1, bh0, acc[1][0], 0, 0, 0);
      acc[1][1] = __builtin_amdgcn_mfma_f32_16x16x32_bf16(al1, bh1, acc[1][1], 0, 0, 0);
      acc[1][1] = __builtin_amdgcn_mfma_f32_16x16x32_bf16(ah1, bl1, acc[1][1], 0, 0, 0);
      acc[1][1] = __builtin_amdgcn_mfma_f32_16x16x32_bf16(ah1, bh1, acc[1][1], 0, 0, 0);
    }
  }
#pragma unroll
  for (int j = 0; j < 2; j++) {
    int col = bn + wc + j * 16 + fr;
    float bj = bias ? bias[col] : 0.f;
#pragma unroll
    for (int i = 0; i < 2; i++) {
#pragma unroll
      for (int r = 0; r < 4; r++) {
        int row = bm + wr + i * 16 + fk * 4 + r;
        float v = acc[i][j][r] + bj;
        if (act == 1) v = fmaxf(v, 0.f);
        C[(size_t)row * N + col] = v;
      }
    }
  }
}

// ---------------- small kernels ----------------
// deg over all edges + winner over the batch (merged launch)
__global__ void deg_winner_kernel(const int* __restrict__ ei, const int* __restrict__ iid,
                                  int* __restrict__ deg, int* __restrict__ winner) {
  int e = blockIdx.x * 256 + threadIdx.x;
  if (e < BB) atomicMax(&winner[iid[e]], e);
  if (e >= ET) return;
  int dst = (e < EE) ? ei[EE + e] : (e - EE);
  atomicAdd(&deg[dst], 1);
}

__global__ void build_xa_kernel(const int* __restrict__ uid, const int* __restrict__ iid,
                                const int* __restrict__ winner,
                                const float* __restrict__ uemb, const float* __restrict__ iemb,
                                const float* __restrict__ cemb,
                                float* __restrict__ Xa, int* __restrict__ map) {
  int t = blockIdx.x;
  int lane = threadIdx.x;  // 64
  int c4 = lane * 4;
  float4 v = make_float4(0.f, 0.f, 0.f, 0.f);
  int node;
  if (t < BB) {
    int u = uid[t];
    node = u;
    if (c4 < DD) v = *reinterpret_cast<const float4*>(&uemb[(size_t)u * DD + c4]);
  } else {
    int b = t - BB;
    int it = iid[b];
    node = NU + it;
    if (c4 < DD) {
      v = *reinterpret_cast<const float4*>(&iemb[(size_t)it * DD + c4]);
    } else {
      int wb = winner[it];
      v = *reinterpret_cast<const float4*>(&cemb[(size_t)wb * DD + (c4 - DD)]);
    }
  }
  *reinterpret_cast<float4*>(&Xa[(size_t)t * 256 + c4]) = v;
  if (lane == 0) map[node] = t;
}

// mark nodes whose x1 row is actually consumed by conv2 (sources of batch-dst edges)
__global__ void mark_kernel(const int* __restrict__ ei, const int* __restrict__ map,
                            unsigned char* __restrict__ needed) {
  int e = blockIdx.x * 256 + threadIdx.x;
  if (e >= ET) return;
  int src, dst;
  if (e < EE) { src = ei[e]; dst = ei[EE + e]; }
  else { src = e - EE; dst = src; }
  if (map[dst] >= 0) needed[src] = 1;
}

__global__ void rowstart_kernel(const int* __restrict__ deg, int* __restrict__ rowstart,
                                int* __restrict__ fill, int* __restrict__ counter) {
  int v = blockIdx.x * 256 + threadIdx.x;
  if (v >= NN) return;
  int s = atomicAdd(counter, deg[v]);
  rowstart[v] = s;
  fill[v] = s;
}

__global__ void fill_kernel(const int* __restrict__ ei, int* __restrict__ fill,
                            int* __restrict__ col) {
  int e = blockIdx.x * 256 + threadIdx.x;
  if (e >= ET) return;
  int src, dst;
  if (e < EE) { src = ei[e]; dst = ei[EE + e]; }
  else { src = e - EE; dst = src; }
  int pos = atomicAdd(&fill[dst], 1);
  col[pos] = src;
}

// a1 scores (4 tasks/block); the last block computes the conv2 q-vectors.
__global__ __launch_bounds__(256) void a1q_kernel(
    const int* __restrict__ uid, const int* __restrict__ iid,
    const float* __restrict__ Ha,
    const float* __restrict__ atts, const float* __restrict__ attd,
    const float* __restrict__ w2,
    const float* __restrict__ att2s, const float* __restrict__ att2d,
    float* __restrict__ a1s, float* __restrict__ a1d,
    float* __restrict__ qs, float* __restrict__ qd) {
  int t = blockIdx.x * 4 + (threadIdx.x >> 6);
  int lane = threadIdx.x & 63;
  if (t >= NTASK) {
    int k = (t - NTASK) * 64 + lane;  // 0..255
    float s = 0.f, d = 0.f;
#pragma unroll 4
    for (int j = 0; j < DD; j++) {
      float w = w2[(size_t)j * 256 + k];
      s += att2s[j] * w;
      d += att2d[j] * w;
    }
    qs[k] = s;
    qd[k] = d;
    return;
  }
  int v = (t < BB) ? uid[t] : NU + iid[t - BB];
  int head = lane >> 5, c = (lane & 31) * 4;
  float4 hv = *reinterpret_cast<const float4*>(&Ha[(size_t)t * 256 + head * DD + c]);
  float4 sv = *reinterpret_cast<const float4*>(&atts[head * DD + c]);
  float4 dv = *reinterpret_cast<const float4*>(&attd[head * DD + c]);
  float ps = hv.x * sv.x + hv.y * sv.y + hv.z * sv.z + hv.w * sv.w;
  float pd = hv.x * dv.x + hv.y * dv.y + hv.z * dv.z + hv.w * dv.w;
  for (int o = 1; o < 32; o <<= 1) { ps += __shfl_xor(ps, o); pd += __shfl_xor(pd, o); }
  if ((lane & 31) == 0) {
    a1s[(size_t)v * 2 + head] = ps;
    a1d[(size_t)v * 2 + head] = pd;
  }
}

// conv1 aggregation. Simple path for deg<=64 (no online rescale), chunked fallback.
// Writes x1 as bf16; fused a2s/a2d from f32 values.
__global__ __launch_bounds__(256) void conv1_agg_kernel(
    const int* __restrict__ col, const int* __restrict__ rowstart,
    const int* __restrict__ deg, const float* __restrict__ Ha,
    const int* __restrict__ map, const unsigned char* __restrict__ needed,
    const float* __restrict__ a1s, const float* __restrict__ a1d,
    const float* __restrict__ bias,
    const float* __restrict__ qs, const float* __restrict__ qd,
    unsigned short* __restrict__ x1b, float* __restrict__ a2s, float* __restrict__ a2d) {
  int v = blockIdx.x * 4 + (threadIdx.x >> 6);  // NN divisible by 4
  int lane = threadIdx.x & 63;
  if (!needed[v]) return;
  int head = lane >> 5;
  int d = deg[v], s0 = rowstart[v];
  float2 adv = *reinterpret_cast<const float2*>(&a1d[(size_t)v * 2]);
  float4 acc = make_float4(0.f, 0.f, 0.f, 0.f);
  float den;
  if (d <= 64) {
    bool act = lane < d;
    int ci = act ? col[s0 + lane] : 0;
    float2 asv = make_float2(0.f, 0.f);
    int ri = -1;
    if (act) {
      asv = *reinterpret_cast<const float2*>(&a1s[(size_t)ci * 2]);
      ri = map[ci];
    }
    float al0 = act ? lrelu(asv.x + adv.x) : -1e30f;
    float al1 = act ? lrelu(asv.y + adv.y) : -1e30f;
    float m0 = al0, m1 = al1;
#pragma unroll
    for (int o = 1; o < 64; o <<= 1) {
      m0 = fmaxf(m0, __shfl_xor(m0, o));
      m1 = fmaxf(m1, __shfl_xor(m1, o));
    }
    float ex0 = act ? __expf(al0 - m0) : 0.f;
    float ex1 = act ? __expf(al1 - m1) : 0.f;
    float cs0 = ex0, cs1 = ex1;
#pragma unroll
    for (int o = 1; o < 64; o <<= 1) {
      cs0 += __shfl_xor(cs0, o);
      cs1 += __shfl_xor(cs1, o);
    }
    den = head ? cs1 : cs0;
    for (int i2 = 0; i2 < d; i2++) {
      int r = __shfl(ri, i2);
      if (r >= 0) {
        float e0 = __shfl(ex0, i2), e1 = __shfl(ex1, i2);
        float ex = head ? e1 : e0;
        float4 hv = *reinterpret_cast<const float4*>(&Ha[((size_t)r << 8) + (lane << 2)]);
        acc.x += ex * hv.x; acc.y += ex * hv.y; acc.z += ex * hv.z; acc.w += ex * hv.w;
      }
    }
  } else {
    float m0 = -1e30f, m1 = -1e30f, den0 = 0.f, den1 = 0.f;
    for (int c0 = 0; c0 < d; c0 += 64) {
      int i = c0 + lane;
      bool act = i < d;
      int ci = act ? col[s0 + i] : 0;
      float2 asv = make_float2(0.f, 0.f);
      int ri = -1;
      if (act) {
        asv = *reinterpret_cast<const float2*>(&a1s[(size_t)ci * 2]);
        ri = map[ci];
      }
      float al0 = act ? lrelu(asv.x + adv.x) : -1e30f;
      float al1 = act ? lrelu(asv.y + adv.y) : -1e30f;
      float cm0 = al0, cm1 = al1;
#pragma unroll
      for (int o = 1; o < 64; o <<= 1) {
        cm0 = fmaxf(cm0, __shfl_xor(cm0, o));
        cm1 = fmaxf(cm1, __shfl_xor(cm1, o));
      }
      float nm0 = fmaxf(m0, cm0), nm1 = fmaxf(m1, cm1);
      float ex0 = act ? __expf(al0 - nm0) : 0.f;
      float ex1 = act ? __expf(al1 - nm1) : 0.f;
      float s0f = __expf(m0 - nm0), s1f = __expf(m1 - nm1);
      float cs0 = ex0, cs1 = ex1;
#pragma unroll
      for (int o = 1; o < 64; o <<= 1) {
        cs0 += __shfl_xor(cs0, o);
        cs1 += __shfl_xor(cs1, o);
      }
      den0 = den0 * s0f + cs0;
      den1 = den1 * s1f + cs1;
      float sc = head ? s1f : s0f;
      acc.x *= sc; acc.y *= sc; acc.z *= sc; acc.w *= sc;
      int n = min(64, d - c0);
      for (int i2 = 0; i2 < n; i2++) {
        int r = __shfl(ri, i2);
        if (r >= 0) {
          float e0 = __shfl(ex0, i2), e1 = __shfl(ex1, i2);
          float ex = head ? e1 : e0;
          float4 hv = *reinterpret_cast<const float4*>(&Ha[((size_t)r << 8) + (lane << 2)]);
          acc.x += ex * hv.x; acc.y += ex * hv.y; acc.z += ex * hv.z; acc.w += ex * hv.w;
        }
      }
      m0 = nm0; m1 = nm1;
    }
    den = head ? den1 : den0;
  }
  float inv = 1.f / den;
  float4 b4 = *reinterpret_cast<const float4*>(&bias[lane << 2]);
  float4 o;
  o.x = fmaf(acc.x, inv, b4.x);
  o.y = fmaf(acc.y, inv, b4.y);
  o.z = fmaf(acc.z, inv, b4.z);
  o.w = fmaf(acc.w, inv, b4.w);
  o.x = o.x > 0.f ? o.x : __expf(o.x) - 1.f;
  o.y = o.y > 0.f ? o.y : __expf(o.y) - 1.f;
  o.z = o.z > 0.f ? o.z : __expf(o.z) - 1.f;
  o.w = o.w > 0.f ? o.w : __expf(o.w) - 1.f;
  ushort4 st;
  st.x = f2bf_rne(o.x); st.y = f2bf_rne(o.y);
  st.z = f2bf_rne(o.z); st.w = f2bf_rne(o.w);
  *reinterpret_cast<ushort4*>(&x1b[((size_t)v << 8) + (lane << 2)]) = st;
  // fused conv2 scores from f32 values (pre-rounding)
  float4 sv = *reinterpret_cast<const float4*>(&qs[lane << 2]);
  float4 dv = *reinterpret_cast<const float4*>(&qd[lane << 2]);
  float ps = o.x * sv.x + o.y * sv.y + o.z * sv.z + o.w * sv.w;
  float pd = o.x * dv.x + o.y * dv.y + o.z * dv.z + o.w * dv.w;
#pragma unroll
  for (int of = 1; of < 64; of <<= 1) { ps += __shfl_xor(ps, of); pd += __shfl_xor(pd, of); }
  if (lane == 0) { a2s[v] = ps; a2d[v] = pd; }
}

// conv2 aggregation in x1-space (bf16 gather), batch tasks only. 4 tasks/block.
__global__ __launch_bounds__(256) void conv2_agg_kernel(
    const int* __restrict__ uid, const int* __restrict__ iid,
    const int* __restrict__ col, const int* __restrict__ rowstart,
    const int* __restrict__ deg, const unsigned short* __restrict__ x1b,
    const float* __restrict__ a2s, const float* __restrict__ a2d,
    float* __restrict__ agg) {
  int t = blockIdx.x * 4 + (threadIdx.x >> 6);  // NTASK divisible by 4
  int lane = threadIdx.x & 63;
  int v = (t < BB) ? uid[t] : NU + iid[t - BB];
  int d = deg[v], s0 = rowstart[v];
  float ad = a2d[v];
  float4 acc = make_float4(0.f, 0.f, 0.f, 0.f);
  float den;
  if (d <= 64) {
    bool act = lane < d;
    int ci = act ? col[s0 + lane] : 0;
    float as = act ? a2s[ci] : 0.f;
    float al = act ? lrelu(as + ad) : -1e30f;
    float m = al;
#pragma unroll
    for (int o = 1; o < 64; o <<= 1) m = fmaxf(m, __shfl_xor(m, o));
    float ex = act ? __expf(al - m) : 0.f;
    float cs = ex;
#pragma unroll
    for (int o = 1; o < 64; o <<= 1) cs += __shfl_xor(cs, o);
    den = cs;
    for (int i2 = 0; i2 < d; i2++) {
      int r = __shfl(ci, i2);
      float e = __shfl(ex, i2);
      ushort4 hv = *reinterpret_cast<const ushort4*>(&x1b[((size_t)r << 8) + (lane << 2)]);
      acc.x += e * bf2f(hv.x); acc.y += e * bf2f(hv.y);
      acc.z += e * bf2f(hv.z); acc.w += e * bf2f(hv.w);
    }
  } else {
    float m = -1e30f; den = 0.f;
    for (int c0 = 0; c0 < d; c0 += 64) {
      int i = c0 + lane;
      bool act = i < d;
      int ci = act ? col[s0 + i] : 0;
      float as = act ? a2s[ci] : 0.f;
      float al = act ? lrelu(as + ad) : -1e30f;
      float cm = al;
#pragma unroll
      for (int o = 1; o < 64; o <<= 1) cm = fmaxf(cm, __shfl_xor(cm, o));
      float nm = fmaxf(m, cm);
      float ex = act ? __expf(al - nm) : 0.f;
      float sf = __expf(m - nm);
      float cs = ex;
#pragma unroll
      for (int o = 1; o < 64; o <<= 1) cs += __shfl_xor(cs, o);
      den = den * sf + cs;
      acc.x *= sf; acc.y *= sf; acc.z *= sf; acc.w *= sf;
      int n = min(64, d - c0);
      for (int i2 = 0; i2 < n; i2++) {
        int r = __shfl(ci, i2);
        float e = __shfl(ex, i2);
        ushort4 hv = *reinterpret_cast<const ushort4*>(&x1b[((size_t)r << 8) + (lane << 2)]);
        acc.x += e * bf2f(hv.x); acc.y += e * bf2f(hv.y);
        acc.z += e * bf2f(hv.z); acc.w += e * bf2f(hv.w);
      }
      m = nm;
    }
  }
  float inv = 1.f / den;
  float4 o = make_float4(acc.x * inv, acc.y * inv, acc.z * inv, acc.w * inv);
  *reinterpret_cast<float4*>(&agg[((size_t)t << 8) + (lane << 2)]) = o;
}

__global__ __launch_bounds__(256) void final_kernel(
    const float* __restrict__ ph, const float* __restrict__ w2,
    const float* __restrict__ b2, float* __restrict__ out) {
  int b = blockIdx.x * 4 + (threadIdx.x >> 6);
  int lane = threadIdx.x & 63;
  float2 hv = *reinterpret_cast<const float2*>(&ph[((size_t)b << 7) + (lane << 1)]);
  float2 wv = *reinterpret_cast<const float2*>(&w2[lane << 1]);
  float s = hv.x * wv.x + hv.y * wv.y;
  for (int o = 1; o < 64; o <<= 1) s += __shfl_xor(s, o);
  if (lane == 0) out[b] = s + b2[0];
}

// ---------------- launcher ----------------
extern "C" void kernel_launch(void* const* d_in, const int* in_sizes, int n_in,
                              void* d_out, int out_size, void* d_ws, size_t ws_size,
                              hipStream_t stream) {
  const int* uid = (const int*)d_in[0];
  const int* iid = (const int*)d_in[1];
  const float* content = (const float*)d_in[2];
  const int* ei = (const int*)d_in[3];
  const float* uemb = (const float*)d_in[4];
  const float* iemb = (const float*)d_in[5];
  const float* wc = (const float*)d_in[6];
  const float* bc = (const float*)d_in[7];
  const float* w1 = (const float*)d_in[8];
  const float* att1s = (const float*)d_in[9];
  const float* att1d = (const float*)d_in[10];
  const float* b1 = (const float*)d_in[11];
  const float* w2 = (const float*)d_in[12];
  const float* att2s = (const float*)d_in[13];
  const float* att2d = (const float*)d_in[14];
  const float* b2c = (const float*)d_in[15];
  const float* pw1 = (const float*)d_in[16];
  const float* pb1 = (const float*)d_in[17];
  const float* pw2 = (const float*)d_in[18];
  const float* pb2 = (const float*)d_in[19];
  float* out = (float*)d_out;
  char* ws = (char*)d_ws;

  size_t off = 0;
  auto alloc = [&](size_t bytes) {
    size_t o = off;
    off += (bytes + 255) & ~(size_t)255;
    return o;
  };
  size_t o_winner  = alloc(NI * 4);
  size_t o_map     = alloc(NN * 4);
  size_t o_a1s     = alloc((size_t)NN * 2 * 4);
  size_t o_a1d     = alloc((size_t)NN * 2 * 4);
  size_t o_deg     = alloc(NN * 4);
  size_t o_rs      = alloc(NN * 4);
  size_t o_fill    = alloc(NN * 4);
  size_t o_cnt     = alloc(4);
  size_t o_needed  = alloc(NN);
  size_t o_col     = alloc((size_t)ET * 4);
  size_t o_a2s     = alloc(NN * 4);
  size_t o_a2d     = alloc(NN * 4);
  size_t o_qs      = alloc(256 * 4);
  size_t o_qd      = alloc(256 * 4);
  // split weights (bf16 hi/lo)
  size_t o_wch = alloc(65536 * 2),  o_wcl = alloc(65536 * 2);
  size_t o_w1h = alloc(65536 * 2),  o_w1l = alloc(65536 * 2);
  size_t o_w2h = alloc(32768 * 2),  o_w2l = alloc(32768 * 2);
  size_t o_p1h = alloc(49152 * 2),  o_p1l = alloc(49152 * 2);
  // region R1 (37.75MB): cemb(4.19M) | Xa(16.78M) | Ha(16.78M)
  size_t o_r1      = alloc(4194304 + 16777216 + 16777216);
  size_t o_cemb  = o_r1;
  size_t o_xa    = o_r1 + 4194304;
  size_t o_ha    = o_r1 + 4194304 + 16777216;
  size_t o_agg   = o_r1;                       // alias cemb+Xa (dead)
  size_t o_out2c = o_r1 + 16777216;            // alias Ha start (dead)
  size_t o_ph    = o_r1;                       // alias agg (dead after out2c GEMM)
  // region R2: x1 bf16 [NN,256]
  size_t o_x1b   = alloc((size_t)NN * 256 * 2);
  (void)ws_size; (void)in_sizes; (void)n_in; (void)out_size;

  int*   winner = (int*)(ws + o_winner);
  int*   map    = (int*)(ws + o_map);
  float* a1s    = (float*)(ws + o_a1s);
  float* a1d    = (float*)(ws + o_a1d);
  int*   deg    = (int*)(ws + o_deg);
  int*   rs     = (int*)(ws + o_rs);
  int*   fill   = (int*)(ws + o_fill);
  int*   cnt    = (int*)(ws + o_cnt);
  unsigned char* needed = (unsigned char*)(ws + o_needed);
  int*   col    = (int*)(ws + o_col);
  float* a2s    = (float*)(ws + o_a2s);
  float* a2d    = (float*)(ws + o_a2d);
  float* qs     = (float*)(ws + o_qs);
  float* qd     = (float*)(ws + o_qd);
  unsigned short* wch = (unsigned short*)(ws + o_wch);
  unsigned short* wcl = (unsigned short*)(ws + o_wcl);
  unsigned short* w1h = (unsigned short*)(ws + o_w1h);
  unsigned short* w1l = (unsigned short*)(ws + o_w1l);
  unsigned short* w2h = (unsigned short*)(ws + o_w2h);
  unsigned short* w2l = (unsigned short*)(ws + o_w2l);
  unsigned short* p1h = (unsigned short*)(ws + o_p1h);
  unsigned short* p1l = (unsigned short*)(ws + o_p1l);
  float* cemb   = (float*)(ws + o_cemb);
  float* Xa     = (float*)(ws + o_xa);
  float* Ha     = (float*)(ws + o_ha);
  float* agg    = (float*)(ws + o_agg);
  float* out2c  = (float*)(ws + o_out2c);
  float* ph     = (float*)(ws + o_ph);
  unsigned short* x1b = (unsigned short*)(ws + o_x1b);

  // merged memsets over adjacent regions (pad bytes are don't-care)
  hipMemsetAsync(ws + o_winner, 0xFF, o_map - o_winner + (size_t)NN * 4, stream);   // winner|map
  hipMemsetAsync(ws + o_a1s, 0, o_a1d - o_a1s + (size_t)NN * 2 * 4, stream);         // a1s|a1d
  hipMemsetAsync(ws + o_deg, 0, o_needed - o_deg + NN, stream);                      // deg|rs|fill|cnt|needed

  {
    int total = 65536 + 65536 + 32768 + 49152;
    split4_kernel<<<(total + 255) / 256, 256, 0, stream>>>(
        wc, wch, wcl, 65536, w1, w1h, w1l, 65536,
        w2, w2h, w2l, 32768, pw1, p1h, p1l, 49152);
  }
  deg_winner_kernel<<<(ET + 255) / 256, 256, 0, stream>>>(ei, iid, deg, winner);
  // c_emb = content @ Wc^T + bc
  {
    dim3 g(BB / 64, DD / 64);
    gemm_mfma<0><<<g, 256, 0, stream>>>(content, wch, wcl, bc, cemb, BB, DD, 512, 0,
                                        nullptr, nullptr, nullptr);
  }
  build_xa_kernel<<<NTASK, 64, 0, stream>>>(uid, iid, winner, uemb, iemb, cemb, Xa, map);
  mark_kernel<<<(ET + 255) / 256, 256, 0, stream>>>(ei, map, needed);
  rowstart_kernel<<<(NN + 255) / 256, 256, 0, stream>>>(deg, rs, fill, cnt);
  fill_kernel<<<(ET + 255) / 256, 256, 0, stream>>>(ei, fill, col);
  // Ha = Xa @ W1^T
  {
    dim3 g(NTASK / 64, 256 / 64);
    gemm_mfma<0><<<g, 256, 0, stream>>>(Xa, w1h, w1l, nullptr, Ha, NTASK, 256, 256, 0,
                                        nullptr, nullptr, nullptr);
  }
  a1q_kernel<<<NTASK / 4 + 1, 256, 0, stream>>>(uid, iid, Ha, att1s, att1d,
                                                w2, att2s, att2d, a1s, a1d, qs, qd);
  conv1_agg_kernel<<<NN / 4, 256, 0, stream>>>(col, rs, deg, Ha, map, needed,
                                               a1s, a1d, b1, qs, qd, x1b, a2s, a2d);
  conv2_agg_kernel<<<NTASK / 4, 256, 0, stream>>>(uid, iid, col, rs, deg, x1b, a2s, a2d, agg);
  // out2c = agg @ W2^T + b2c
  {
    dim3 g(NTASK / 64, DD / 64);
    gemm_mfma<0><<<g, 256, 0, stream>>>(agg, w2h, w2l, b2c, out2c, NTASK, DD, 256, 0,
                                        nullptr, nullptr, nullptr);
  }
  // ph = relu([uemb[uid] | out2c_item | out2c_user] @ pw1^T + pb1)
  {
    dim3 g(BB / 64, DD / 64);
    gemm_mfma<1><<<g, 256, 0, stream>>>(nullptr, p1h, p1l, pb1, ph, BB, DD, 384, 1,
                                        uid, uemb, out2c);
  }
  final_kernel<<<BB / 4, 256, 0, stream>>>(ph, pw2, pb2, out);
}

// Round 7
// 224.150 us; speedup vs baseline: 1.9970x; 1.0283x over previous
//
#include <hip/hip_runtime.h>
#include <hip/hip_bf16.h>

#define NU 50000
#define NI 20000
#define NN 70000
#define DD 128
#define BB 8192
#define EE 500000
#define ET 570000   // EE + NN self loops
#define NTASK 16384 // 2*BB

__device__ __forceinline__ float lrelu(float x) { return x > 0.f ? x : 0.2f * x; }

typedef __attribute__((ext_vector_type(8))) short bf16x8;   // 8 bf16 = 4 VGPRs
typedef __attribute__((ext_vector_type(8))) unsigned short u16x8;
typedef __attribute__((ext_vector_type(4))) float f32x4;

__device__ __forceinline__ unsigned short f2bf_rne(float f) {
  unsigned int u = __builtin_bit_cast(unsigned int, f);
  u += 0x7FFFu + ((u >> 16) & 1u);
  return (unsigned short)(u >> 16);
}
__device__ __forceinline__ float bf2f(unsigned short h) {
  unsigned int u = ((unsigned int)h) << 16;
  return __builtin_bit_cast(float, u);
}

// ---------------- MFMA GEMM: C[M,N] = A[M,K] * Bt[N,K]^T (+bias)(+relu) -----------
// GATHER=0: A linear. GATHER=1: ph-style 3-section row gather via map.
// GATHER=2: A row r = gA0[idx0[r]] (full K row gather). C has row stride ldc.
template <int GATHER>
__global__ __launch_bounds__(256) void gemm_mfma(
    const float* __restrict__ A,
    const unsigned short* __restrict__ Bh, const unsigned short* __restrict__ Bl,
    const float* __restrict__ bias, float* __restrict__ C, int ldc,
    int M, int N, int K, int act,
    const int* __restrict__ idx0, const int* __restrict__ idx1,
    const int* __restrict__ mapv,
    const float* __restrict__ gA0, const float* __restrict__ gA1) {
  __shared__ __align__(16) unsigned short sAh[8][64][8];
  __shared__ __align__(16) unsigned short sAl[8][64][8];
  __shared__ __align__(16) unsigned short sBh[8][64][8];
  __shared__ __align__(16) unsigned short sBl[8][64][8];
  int tid = threadIdx.x;
  int bm = blockIdx.x * 64, bn = blockIdx.y * 64;
  int lane = tid & 63, w = tid >> 6;
  int wr = (w >> 1) * 32, wc = (w & 1) * 32;
  int fr = lane & 15, fk = lane >> 4;
  f32x4 acc[2][2] = {};

  for (int k0 = 0; k0 < K; k0 += 64) {
    __syncthreads();
#pragma unroll
    for (int t = 0; t < 2; t++) {
      int f = tid + t * 256;
      int row = f >> 3, kb = f & 7;
      int kg = k0 + kb * 8;
      const float* ap;
      if (GATHER == 1) {
        int sec = kg >> 7;           // 64-tiles never straddle 128-col sections
        int kc = kg & 127;
        int r = bm + row;
        if (sec == 0)      ap = &gA0[(size_t)idx0[r] * 128 + kc];
        else if (sec == 1) ap = &gA1[(size_t)mapv[NU + idx1[r]] * 128 + kc];
        else               ap = &gA1[(size_t)mapv[idx0[r]] * 128 + kc];
      } else if (GATHER == 2) {
        ap = &gA0[(size_t)idx0[bm + row] * K + kg];
      } else {
        ap = &A[(size_t)(bm + row) * K + kg];
      }
      float4 v0 = *reinterpret_cast<const float4*>(ap);
      float4 v1 = *reinterpret_cast<const float4*>(ap + 4);
      float vv[8] = {v0.x, v0.y, v0.z, v0.w, v1.x, v1.y, v1.z, v1.w};
      u16x8 hv, lv;
#pragma unroll
      for (int j = 0; j < 8; j++) {
        unsigned short hh = f2bf_rne(vv[j]);
        hv[j] = hh;
        lv[j] = (unsigned short)(__builtin_bit_cast(unsigned int, vv[j] - bf2f(hh)) >> 16);
      }
      *reinterpret_cast<u16x8*>(&sAh[kb][row][0]) = hv;
      *reinterpret_cast<u16x8*>(&sAl[kb][row][0]) = lv;
    }
#pragma unroll
    for (int t = 0; t < 2; t++) {
      int f = tid + t * 256;
      int row = f >> 3, kb = f & 7;
      int kg = k0 + kb * 8;
      *reinterpret_cast<u16x8*>(&sBh[kb][row][0]) =
          *reinterpret_cast<const u16x8*>(&Bh[(size_t)(bn + row) * K + kg]);
      *reinterpret_cast<u16x8*>(&sBl[kb][row][0]) =
          *reinterpret_cast<const u16x8*>(&Bl[(size_t)(bn + row) * K + kg]);
    }
    __syncthreads();
#pragma unroll
    for (int s = 0; s < 2; s++) {
      int kb = s * 4 + fk;
      bf16x8 ah0 = *reinterpret_cast<const bf16x8*>(&sAh[kb][wr + fr][0]);
      bf16x8 ah1 = *reinterpret_cast<const bf16x8*>(&sAh[kb][wr + 16 + fr][0]);
      bf16x8 al0 = *reinterpret_cast<const bf16x8*>(&sAl[kb][wr + fr][0]);
      bf16x8 al1 = *reinterpret_cast<const bf16x8*>(&sAl[kb][wr + 16 + fr][0]);
      bf16x8 bh0 = *reinterpret_cast<const bf16x8*>(&sBh[kb][wc + fr][0]);
      bf16x8 bh1 = *reinterpret_cast<const bf16x8*>(&sBh[kb][wc + 16 + fr][0]);
      bf16x8 bl0 = *reinterpret_cast<const bf16x8*>(&sBl[kb][wc + fr][0]);
      bf16x8 bl1 = *reinterpret_cast<const bf16x8*>(&sBl[kb][wc + 16 + fr][0]);
      acc[0][0] = __builtin_amdgcn_mfma_f32_16x16x32_bf16(al0, bh0, acc[0][0], 0, 0, 0);
      acc[0][0] = __builtin_amdgcn_mfma_f32_16x16x32_bf16(ah0, bl0, acc[0][0], 0, 0, 0);
      acc[0][0] = __builtin_amdgcn_mfma_f32_16x16x32_bf16(ah0, bh0, acc[0][0], 0, 0, 0);
      acc[0][1] = __builtin_amdgcn_mfma_f32_16x16x32_bf16(al0, bh1, acc[0][1], 0, 0, 0);
      acc[0][1] = __builtin_amdgcn_mfma_f32_16x16x32_bf16(ah0, bl1, acc[0][1], 0, 0, 0);
      acc[0][1] = __builtin_amdgcn_mfma_f32_16x16x32_bf16(ah0, bh1, acc[0][1], 0, 0, 0);
      acc[1][0] = __builtin_amdgcn_mfma_f32_16x16x32_bf16(al1, bh0, acc[1][0], 0, 0, 0);
      acc[1][0] = __builtin_amdgcn_mfma_f32_16x16x32_bf16(ah1, bl0, acc[1][0], 0, 0, 0);
      acc[1][0] = __builtin_amdgcn_mfma_f32_16x16x32_bf16(ah1, bh0, acc[1][0], 0, 0, 0);
      acc[1][1] = __builtin_amdgcn_mfma_f32_16x16x32_bf16(al1, bh1, acc[1][1], 0, 0, 0);
      acc[1][1] = __builtin_amdgcn_mfma_f32_16x16x32_bf16(ah1, bl1, acc[1][1], 0, 0, 0);
      acc[1][1] = __builtin_amdgcn_mfma_f32_16x16x32_bf16(ah1, bh1, acc[1][1], 0, 0, 0);
    }
  }
#pragma unroll
  for (int j = 0; j < 2; j++) {
    int col = bn + wc + j * 16 + fr;
    float bj = bias ? bias[col] : 0.f;
#pragma unroll
    for (int i = 0; i < 2; i++) {
#pragma unroll
      for (int r = 0; r < 4; r++) {
        int row = bm + wr + i * 16 + fk * 4 + r;
        float v = acc[i][j][r] + bj;
        if (act == 1) v = fmaxf(v, 0.f);
        C[(size_t)row * ldc + col] = v;
      }
    }
  }
}

// ---------------- mega-setup: deg+winner atomics | weight split | Xa-emb+map ------
#define EB 2227    // ceil(ET/256)
#define SPLB 832   // (65536+65536+32768+49152)/256
#define XAB 4096   // NTASK/4
__global__ __launch_bounds__(256) void setup_kernel(
    const int* __restrict__ ei, const int* __restrict__ uid, const int* __restrict__ iid,
    int* __restrict__ deg, int* __restrict__ winner,
    const float* __restrict__ wc, unsigned short* wch, unsigned short* wcl,
    const float* __restrict__ w1, unsigned short* w1h, unsigned short* w1l,
    const float* __restrict__ w2, unsigned short* w2h, unsigned short* w2l,
    const float* __restrict__ pw1, unsigned short* p1h, unsigned short* p1l,
    const float* __restrict__ uemb, const float* __restrict__ iemb,
    float* __restrict__ Xa, int* __restrict__ map) {
  int bid = blockIdx.x, tid = threadIdx.x;
  if (bid < EB) {
    int e = bid * 256 + tid;
    if (e < BB) atomicMax(&winner[iid[e]], e);
    if (e >= ET) return;
    int dst = (e < EE) ? ei[EE + e] : (e - EE);
    atomicAdd(&deg[dst], 1);
    return;
  }
  if (bid < EB + SPLB) {
    int i = (bid - EB) * 256 + tid;
    const float* w; unsigned short* h; unsigned short* l; int idx;
    if (i < 65536) { w = wc; h = wch; l = wcl; idx = i; }
    else if (i < 131072) { w = w1; h = w1h; l = w1l; idx = i - 65536; }
    else if (i < 163840) { w = w2; h = w2h; l = w2l; idx = i - 131072; }
    else { w = pw1; h = p1h; l = p1l; idx = i - 163840; }
    float f = w[idx];
    unsigned short hh = f2bf_rne(f);
    h[idx] = hh;
    l[idx] = (unsigned short)(__builtin_bit_cast(unsigned int, f - bf2f(hh)) >> 16);
    return;
  }
  // Xa embedding parts + map (content section filled later by gather-A GEMM)
  int t = (bid - EB - SPLB) * 4 + (tid >> 6);
  int lane = tid & 63;
  int c4 = lane * 4;
  if (t < BB) {
    int u = uid[t];
    float4 v = make_float4(0.f, 0.f, 0.f, 0.f);
    if (c4 < DD) v = *reinterpret_cast<const float4*>(&uemb[(size_t)u * DD + c4]);
    *reinterpret_cast<float4*>(&Xa[(size_t)t * 256 + c4]) = v;
    if (lane == 0) map[u] = t;
  } else {
    int it = iid[t - BB];
    if (c4 < DD) {
      float4 v = *reinterpret_cast<const float4*>(&iemb[(size_t)it * DD + c4]);
      *reinterpret_cast<float4*>(&Xa[(size_t)t * 256 + c4]) = v;
    }
    if (lane == 0) map[NU + it] = t;
  }
}

// rowstart + widx (widx[b] = winner[iid[b]] for the content gather GEMM)
__global__ void rowstart_kernel(const int* __restrict__ deg, const int* __restrict__ winner,
                                const int* __restrict__ iid,
                                int* __restrict__ rowstart, int* __restrict__ fill,
                                int* __restrict__ counter, int* __restrict__ widx) {
  int v = blockIdx.x * 256 + threadIdx.x;
  if (v < BB) widx[v] = winner[iid[v]];
  if (v >= NN) return;
  int s = atomicAdd(counter, deg[v]);
  rowstart[v] = s;
  fill[v] = s;
}

// CSR fill + needed-mark (sources of batch-dst edges), one edge pass
__global__ void fill_mark_kernel(const int* __restrict__ ei, int* __restrict__ fill,
                                 int* __restrict__ col, const int* __restrict__ map,
                                 unsigned char* __restrict__ needed) {
  int e = blockIdx.x * 256 + threadIdx.x;
  if (e >= ET) return;
  int src, dst;
  if (e < EE) { src = ei[e]; dst = ei[EE + e]; }
  else { src = e - EE; dst = src; }
  int pos = atomicAdd(&fill[dst], 1);
  col[pos] = src;
  if (map[dst] >= 0) needed[src] = 1;
}

// a1 scores (4 tasks/block); the last block computes the conv2 q-vectors.
__global__ __launch_bounds__(256) void a1q_kernel(
    const int* __restrict__ uid, const int* __restrict__ iid,
    const float* __restrict__ Ha,
    const float* __restrict__ atts, const float* __restrict__ attd,
    const float* __restrict__ w2,
    const float* __restrict__ att2s, const float* __restrict__ att2d,
    float* __restrict__ a1s, float* __restrict__ a1d,
    float* __restrict__ qs, float* __restrict__ qd) {
  int t = blockIdx.x * 4 + (threadIdx.x >> 6);
  int lane = threadIdx.x & 63;
  if (t >= NTASK) {
    int k = (t - NTASK) * 64 + lane;  // 0..255
    float s = 0.f, d = 0.f;
#pragma unroll 4
    for (int j = 0; j < DD; j++) {
      float w = w2[(size_t)j * 256 + k];
      s += att2s[j] * w;
      d += att2d[j] * w;
    }
    qs[k] = s;
    qd[k] = d;
    return;
  }
  int v = (t < BB) ? uid[t] : NU + iid[t - BB];
  int head = lane >> 5, c = (lane & 31) * 4;
  float4 hv = *reinterpret_cast<const float4*>(&Ha[(size_t)t * 256 + head * DD + c]);
  float4 sv = *reinterpret_cast<const float4*>(&atts[head * DD + c]);
  float4 dv = *reinterpret_cast<const float4*>(&attd[head * DD + c]);
  float ps = hv.x * sv.x + hv.y * sv.y + hv.z * sv.z + hv.w * sv.w;
  float pd = hv.x * dv.x + hv.y * dv.y + hv.z * dv.z + hv.w * dv.w;
  for (int o = 1; o < 32; o <<= 1) { ps += __shfl_xor(ps, o); pd += __shfl_xor(pd, o); }
  if ((lane & 31) == 0) {
    a1s[(size_t)v * 2 + head] = ps;
    a1d[(size_t)v * 2 + head] = pd;
  }
}

// conv1 aggregation (unchanged from R6 — bf16 x1, needed-skip, fused a2 scores)
__global__ __launch_bounds__(256) void conv1_agg_kernel(
    const int* __restrict__ col, const int* __restrict__ rowstart,
    const int* __restrict__ deg, const float* __restrict__ Ha,
    const int* __restrict__ map, const unsigned char* __restrict__ needed,
    const float* __restrict__ a1s, const float* __restrict__ a1d,
    const float* __restrict__ bias,
    const float* __restrict__ qs, const float* __restrict__ qd,
    unsigned short* __restrict__ x1b, float* __restrict__ a2s, float* __restrict__ a2d) {
  int v = blockIdx.x * 4 + (threadIdx.x >> 6);
  int lane = threadIdx.x & 63;
  if (!needed[v]) return;
  int head = lane >> 5;
  int d = deg[v], s0 = rowstart[v];
  float2 adv = *reinterpret_cast<const float2*>(&a1d[(size_t)v * 2]);
  float4 acc = make_float4(0.f, 0.f, 0.f, 0.f);
  float den;
  if (d <= 64) {
    bool act = lane < d;
    int ci = act ? col[s0 + lane] : 0;
    float2 asv = make_float2(0.f, 0.f);
    int ri = -1;
    if (act) {
      asv = *reinterpret_cast<const float2*>(&a1s[(size_t)ci * 2]);
      ri = map[ci];
    }
    float al0 = act ? lrelu(asv.x + adv.x) : -1e30f;
    float al1 = act ? lrelu(asv.y + adv.y) : -1e30f;
    float m0 = al0, m1 = al1;
#pragma unroll
    for (int o = 1; o < 64; o <<= 1) {
      m0 = fmaxf(m0, __shfl_xor(m0, o));
      m1 = fmaxf(m1, __shfl_xor(m1, o));
    }
    float ex0 = act ? __expf(al0 - m0) : 0.f;
    float ex1 = act ? __expf(al1 - m1) : 0.f;
    float cs0 = ex0, cs1 = ex1;
#pragma unroll
    for (int o = 1; o < 64; o <<= 1) {
      cs0 += __shfl_xor(cs0, o);
      cs1 += __shfl_xor(cs1, o);
    }
    den = head ? cs1 : cs0;
    for (int i2 = 0; i2 < d; i2++) {
      int r = __shfl(ri, i2);
      if (r >= 0) {
        float e0 = __shfl(ex0, i2), e1 = __shfl(ex1, i2);
        float ex = head ? e1 : e0;
        float4 hv = *reinterpret_cast<const float4*>(&Ha[((size_t)r << 8) + (lane << 2)]);
        acc.x += ex * hv.x; acc.y += ex * hv.y; acc.z += ex * hv.z; acc.w += ex * hv.w;
      }
    }
  } else {
    float m0 = -1e30f, m1 = -1e30f, den0 = 0.f, den1 = 0.f;
    for (int c0 = 0; c0 < d; c0 += 64) {
      int i = c0 + lane;
      bool act = i < d;
      int ci = act ? col[s0 + i] : 0;
      float2 asv = make_float2(0.f, 0.f);
      int ri = -1;
      if (act) {
        asv = *reinterpret_cast<const float2*>(&a1s[(size_t)ci * 2]);
        ri = map[ci];
      }
      float al0 = act ? lrelu(asv.x + adv.x) : -1e30f;
      float al1 = act ? lrelu(asv.y + adv.y) : -1e30f;
      float cm0 = al0, cm1 = al1;
#pragma unroll
      for (int o = 1; o < 64; o <<= 1) {
        cm0 = fmaxf(cm0, __shfl_xor(cm0, o));
        cm1 = fmaxf(cm1, __shfl_xor(cm1, o));
      }
      float nm0 = fmaxf(m0, cm0), nm1 = fmaxf(m1, cm1);
      float ex0 = act ? __expf(al0 - nm0) : 0.f;
      float ex1 = act ? __expf(al1 - nm1) : 0.f;
      float s0f = __expf(m0 - nm0), s1f = __expf(m1 - nm1);
      float cs0 = ex0, cs1 = ex1;
#pragma unroll
      for (int o = 1; o < 64; o <<= 1) {
        cs0 += __shfl_xor(cs0, o);
        cs1 += __shfl_xor(cs1, o);
      }
      den0 = den0 * s0f + cs0;
      den1 = den1 * s1f + cs1;
      float sc = head ? s1f : s0f;
      acc.x *= sc; acc.y *= sc; acc.z *= sc; acc.w *= sc;
      int n = min(64, d - c0);
      for (int i2 = 0; i2 < n; i2++) {
        int r = __shfl(ri, i2);
        if (r >= 0) {
          float e0 = __shfl(ex0, i2), e1 = __shfl(ex1, i2);
          float ex = head ? e1 : e0;
          float4 hv = *reinterpret_cast<const float4*>(&Ha[((size_t)r << 8) + (lane << 2)]);
          acc.x += ex * hv.x; acc.y += ex * hv.y; acc.z += ex * hv.z; acc.w += ex * hv.w;
        }
      }
      m0 = nm0; m1 = nm1;
    }
    den = head ? den1 : den0;
  }
  float inv = 1.f / den;
  float4 b4 = *reinterpret_cast<const float4*>(&bias[lane << 2]);
  float4 o;
  o.x = fmaf(acc.x, inv, b4.x);
  o.y = fmaf(acc.y, inv, b4.y);
  o.z = fmaf(acc.z, inv, b4.z);
  o.w = fmaf(acc.w, inv, b4.w);
  o.x = o.x > 0.f ? o.x : __expf(o.x) - 1.f;
  o.y = o.y > 0.f ? o.y : __expf(o.y) - 1.f;
  o.z = o.z > 0.f ? o.z : __expf(o.z) - 1.f;
  o.w = o.w > 0.f ? o.w : __expf(o.w) - 1.f;
  ushort4 st;
  st.x = f2bf_rne(o.x); st.y = f2bf_rne(o.y);
  st.z = f2bf_rne(o.z); st.w = f2bf_rne(o.w);
  *reinterpret_cast<ushort4*>(&x1b[((size_t)v << 8) + (lane << 2)]) = st;
  float4 sv = *reinterpret_cast<const float4*>(&qs[lane << 2]);
  float4 dv = *reinterpret_cast<const float4*>(&qd[lane << 2]);
  float ps = o.x * sv.x + o.y * sv.y + o.z * sv.z + o.w * sv.w;
  float pd = o.x * dv.x + o.y * dv.y + o.z * dv.z + o.w * dv.w;
#pragma unroll
  for (int of = 1; of < 64; of <<= 1) { ps += __shfl_xor(ps, of); pd += __shfl_xor(pd, of); }
  if (lane == 0) { a2s[v] = ps; a2d[v] = pd; }
}

// conv2 aggregation, representative tasks only (map[v]==t); bf16 x1 gather.
__global__ __launch_bounds__(256) void conv2_agg_kernel(
    const int* __restrict__ uid, const int* __restrict__ iid,
    const int* __restrict__ col, const int* __restrict__ rowstart,
    const int* __restrict__ deg, const int* __restrict__ map,
    const unsigned short* __restrict__ x1b,
    const float* __restrict__ a2s, const float* __restrict__ a2d,
    float* __restrict__ agg) {
  int t = blockIdx.x * 4 + (threadIdx.x >> 6);
  int lane = threadIdx.x & 63;
  int v = (t < BB) ? uid[t] : NU + iid[t - BB];
  if (map[v] != t) return;  // duplicates gather the rep's row via map in the ph GEMM
  int d = deg[v], s0 = rowstart[v];
  float ad = a2d[v];
  float4 acc = make_float4(0.f, 0.f, 0.f, 0.f);
  float den;
  if (d <= 64) {
    bool act = lane < d;
    int ci = act ? col[s0 + lane] : 0;
    float as = act ? a2s[ci] : 0.f;
    float al = act ? lrelu(as + ad) : -1e30f;
    float m = al;
#pragma unroll
    for (int o = 1; o < 64; o <<= 1) m = fmaxf(m, __shfl_xor(m, o));
    float ex = act ? __expf(al - m) : 0.f;
    float cs = ex;
#pragma unroll
    for (int o = 1; o < 64; o <<= 1) cs += __shfl_xor(cs, o);
    den = cs;
    for (int i2 = 0; i2 < d; i2++) {
      int r = __shfl(ci, i2);
      float e = __shfl(ex, i2);
      ushort4 hv = *reinterpret_cast<const ushort4*>(&x1b[((size_t)r << 8) + (lane << 2)]);
      acc.x += e * bf2f(hv.x); acc.y += e * bf2f(hv.y);
      acc.z += e * bf2f(hv.z); acc.w += e * bf2f(hv.w);
    }
  } else {
    float m = -1e30f; den = 0.f;
    for (int c0 = 0; c0 < d; c0 += 64) {
      int i = c0 + lane;
      bool act = i < d;
      int ci = act ? col[s0 + i] : 0;
      float as = act ? a2s[ci] : 0.f;
      float al = act ? lrelu(as + ad) : -1e30f;
      float cm = al;
#pragma unroll
      for (int o = 1; o < 64; o <<= 1) cm = fmaxf(cm, __shfl_xor(cm, o));
      float nm = fmaxf(m, cm);
      float ex = act ? __expf(al - nm) : 0.f;
      float sf = __expf(m - nm);
      float cs = ex;
#pragma unroll
      for (int o = 1; o < 64; o <<= 1) cs += __shfl_xor(cs, o);
      den = den * sf + cs;
      acc.x *= sf; acc.y *= sf; acc.z *= sf; acc.w *= sf;
      int n = min(64, d - c0);
      for (int i2 = 0; i2 < n; i2++) {
        int r = __shfl(ci, i2);
        float e = __shfl(ex, i2);
        ushort4 hv = *reinterpret_cast<const ushort4*>(&x1b[((size_t)r << 8) + (lane << 2)]);
        acc.x += e * bf2f(hv.x); acc.y += e * bf2f(hv.y);
        acc.z += e * bf2f(hv.z); acc.w += e * bf2f(hv.w);
      }
      m = nm;
    }
  }
  float inv = 1.f / den;
  float4 o = make_float4(acc.x * inv, acc.y * inv, acc.z * inv, acc.w * inv);
  *reinterpret_cast<float4*>(&agg[((size_t)t << 8) + (lane << 2)]) = o;
}

__global__ __launch_bounds__(256) void final_kernel(
    const float* __restrict__ ph, const float* __restrict__ w2,
    const float* __restrict__ b2, float* __restrict__ out) {
  int b = blockIdx.x * 4 + (threadIdx.x >> 6);
  int lane = threadIdx.x & 63;
  float2 hv = *reinterpret_cast<const float2*>(&ph[((size_t)b << 7) + (lane << 1)]);
  float2 wv = *reinterpret_cast<const float2*>(&w2[lane << 1]);
  float s = hv.x * wv.x + hv.y * wv.y;
  for (int o = 1; o < 64; o <<= 1) s += __shfl_xor(s, o);
  if (lane == 0) out[b] = s + b2[0];
}

// ---------------- launcher ----------------
extern "C" void kernel_launch(void* const* d_in, const int* in_sizes, int n_in,
                              void* d_out, int out_size, void* d_ws, size_t ws_size,
                              hipStream_t stream) {
  const int* uid = (const int*)d_in[0];
  const int* iid = (const int*)d_in[1];
  const float* content = (const float*)d_in[2];
  const int* ei = (const int*)d_in[3];
  const float* uemb = (const float*)d_in[4];
  const float* iemb = (const float*)d_in[5];
  const float* wc = (const float*)d_in[6];
  const float* bc = (const float*)d_in[7];
  const float* w1 = (const float*)d_in[8];
  const float* att1s = (const float*)d_in[9];
  const float* att1d = (const float*)d_in[10];
  const float* b1 = (const float*)d_in[11];
  const float* w2 = (const float*)d_in[12];
  const float* att2s = (const float*)d_in[13];
  const float* att2d = (const float*)d_in[14];
  const float* b2c = (const float*)d_in[15];
  const float* pw1 = (const float*)d_in[16];
  const float* pb1 = (const float*)d_in[17];
  const float* pw2 = (const float*)d_in[18];
  const float* pb2 = (const float*)d_in[19];
  float* out = (float*)d_out;
  char* ws = (char*)d_ws;

  size_t off = 0;
  auto alloc = [&](size_t bytes) {
    size_t o = off;
    off += (bytes + 255) & ~(size_t)255;
    return o;
  };
  size_t o_winner  = alloc(NI * 4);
  size_t o_map     = alloc(NN * 4);
  size_t o_a1s     = alloc((size_t)NN * 2 * 4);
  size_t o_a1d     = alloc((size_t)NN * 2 * 4);
  size_t o_deg     = alloc(NN * 4);
  size_t o_rs      = alloc(NN * 4);
  size_t o_fill    = alloc(NN * 4);
  size_t o_cnt     = alloc(4);
  size_t o_needed  = alloc(NN);
  size_t o_col     = alloc((size_t)ET * 4);
  size_t o_a2s     = alloc(NN * 4);
  size_t o_a2d     = alloc(NN * 4);
  size_t o_qs      = alloc(256 * 4);
  size_t o_qd      = alloc(256 * 4);
  size_t o_widx    = alloc(BB * 4);
  // split weights (bf16 hi/lo)
  size_t o_wch = alloc(65536 * 2),  o_wcl = alloc(65536 * 2);
  size_t o_w1h = alloc(65536 * 2),  o_w1l = alloc(65536 * 2);
  size_t o_w2h = alloc(32768 * 2),  o_w2l = alloc(32768 * 2);
  size_t o_p1h = alloc(49152 * 2),  o_p1l = alloc(49152 * 2);
  // region R1 (33.5MB): Xa(16.78M) | Ha(16.78M)
  // reuse: agg @ Xa (dead after Ha GEMM); out2c @ Ha (dead after conv1/a1q);
  //        ph @ agg (dead after out2c GEMM)
  size_t o_r1    = alloc(16777216 + 16777216);
  size_t o_xa    = o_r1;
  size_t o_ha    = o_r1 + 16777216;
  size_t o_agg   = o_r1;
  size_t o_out2c = o_r1 + 16777216;
  size_t o_ph    = o_r1;
  // region R2: x1 bf16 [NN,256]
  size_t o_x1b   = alloc((size_t)NN * 256 * 2);
  (void)ws_size; (void)in_sizes; (void)n_in; (void)out_size;

  int*   winner = (int*)(ws + o_winner);
  int*   map    = (int*)(ws + o_map);
  float* a1s    = (float*)(ws + o_a1s);
  float* a1d    = (float*)(ws + o_a1d);
  int*   deg    = (int*)(ws + o_deg);
  int*   rs     = (int*)(ws + o_rs);
  int*   fill   = (int*)(ws + o_fill);
  int*   cnt    = (int*)(ws + o_cnt);
  unsigned char* needed = (unsigned char*)(ws + o_needed);
  int*   col    = (int*)(ws + o_col);
  float* a2s    = (float*)(ws + o_a2s);
  float* a2d    = (float*)(ws + o_a2d);
  float* qs     = (float*)(ws + o_qs);
  float* qd     = (float*)(ws + o_qd);
  int*   widx   = (int*)(ws + o_widx);
  unsigned short* wch = (unsigned short*)(ws + o_wch);
  unsigned short* wcl = (unsigned short*)(ws + o_wcl);
  unsigned short* w1h = (unsigned short*)(ws + o_w1h);
  unsigned short* w1l = (unsigned short*)(ws + o_w1l);
  unsigned short* w2h = (unsigned short*)(ws + o_w2h);
  unsigned short* w2l = (unsigned short*)(ws + o_w2l);
  unsigned short* p1h = (unsigned short*)(ws + o_p1h);
  unsigned short* p1l = (unsigned short*)(ws + o_p1l);
  float* Xa     = (float*)(ws + o_xa);
  float* Ha     = (float*)(ws + o_ha);
  float* agg    = (float*)(ws + o_agg);
  float* out2c  = (float*)(ws + o_out2c);
  float* ph     = (float*)(ws + o_ph);
  unsigned short* x1b = (unsigned short*)(ws + o_x1b);

  // merged memsets over adjacent regions (pad bytes are don't-care)
  hipMemsetAsync(ws + o_winner, 0xFF, o_map - o_winner + (size_t)NN * 4, stream);   // winner|map
  hipMemsetAsync(ws + o_a1s, 0, o_a1d - o_a1s + (size_t)NN * 2 * 4, stream);         // a1s|a1d
  hipMemsetAsync(ws + o_deg, 0, o_needed - o_deg + NN, stream);                      // deg|rs|fill|cnt|needed

  // mega-setup: edge deg+winner | weight split | Xa emb parts + map
  setup_kernel<<<EB + SPLB + XAB, 256, 0, stream>>>(
      ei, uid, iid, deg, winner,
      wc, wch, wcl, w1, w1h, w1l, w2, w2h, w2l, pw1, p1h, p1l,
      uemb, iemb, Xa, map);
  rowstart_kernel<<<(NN + 255) / 256, 256, 0, stream>>>(deg, winner, iid, rs, fill, cnt, widx);
  // content section of Xa: rows BB..2BB, cols 128..256 = content[widx[r]] @ Wc^T + bc
  {
    dim3 g(BB / 64, DD / 64);
    gemm_mfma<2><<<g, 256, 0, stream>>>(nullptr, wch, wcl, bc, Xa + (size_t)BB * 256 + 128,
                                        256, BB, DD, 512, 0,
                                        widx, nullptr, nullptr, content, nullptr);
  }
  fill_mark_kernel<<<(ET + 255) / 256, 256, 0, stream>>>(ei, fill, col, map, needed);
  // Ha = Xa @ W1^T
  {
    dim3 g(NTASK / 64, 256 / 64);
    gemm_mfma<0><<<g, 256, 0, stream>>>(Xa, w1h, w1l, nullptr, Ha, 256, NTASK, 256, 256, 0,
                                        nullptr, nullptr, nullptr, nullptr, nullptr);
  }
  a1q_kernel<<<NTASK / 4 + 1, 256, 0, stream>>>(uid, iid, Ha, att1s, att1d,
                                                w2, att2s, att2d, a1s, a1d, qs, qd);
  conv1_agg_kernel<<<NN / 4, 256, 0, stream>>>(col, rs, deg, Ha, map, needed,
                                               a1s, a1d, b1, qs, qd, x1b, a2s, a2d);
  conv2_agg_kernel<<<NTASK / 4, 256, 0, stream>>>(uid, iid, col, rs, deg, map,
                                                  x1b, a2s, a2d, agg);
  // out2c = agg @ W2^T + b2c (non-rep rows are garbage, never read downstream)
  {
    dim3 g(NTASK / 64, DD / 64);
    gemm_mfma<0><<<g, 256, 0, stream>>>(agg, w2h, w2l, b2c, out2c, 128, NTASK, DD, 256, 0,
                                        nullptr, nullptr, nullptr, nullptr, nullptr);
  }
  // ph = relu([uemb[uid] | out2c[map[item]] | out2c[map[user]]] @ pw1^T + pb1)
  {
    dim3 g(BB / 64, DD / 64);
    gemm_mfma<1><<<g, 256, 0, stream>>>(nullptr, p1h, p1l, pb1, ph, 128, BB, DD, 384, 1,
                                        uid, iid, map, uemb, out2c);
  }
  final_kernel<<<BB / 4, 256, 0, stream>>>(ph, pw2, pb2, out);
}

// Round 8
// 220.536 us; speedup vs baseline: 2.0297x; 1.0164x over previous
//
#include <hip/hip_runtime.h>
#include <hip/hip_bf16.h>

#define NU 50000
#define NI 20000
#define NN 70000
#define DD 128
#define BB 8192
#define EE 500000
#define ET 570000   // EE + NN self loops
#define NTASK 16384 // 2*BB

__device__ __forceinline__ float lrelu(float x) { return x > 0.f ? x : 0.2f * x; }

typedef __attribute__((ext_vector_type(8))) short bf16x8;   // 8 bf16 = 4 VGPRs
typedef __attribute__((ext_vector_type(8))) unsigned short u16x8;
typedef __attribute__((ext_vector_type(4))) float f32x4;

__device__ __forceinline__ unsigned short f2bf_rne(float f) {
  unsigned int u = __builtin_bit_cast(unsigned int, f);
  u += 0x7FFFu + ((u >> 16) & 1u);
  return (unsigned short)(u >> 16);
}
__device__ __forceinline__ float bf2f(unsigned short h) {
  unsigned int u = ((unsigned int)h) << 16;
  return __builtin_bit_cast(float, u);
}

// ---------------- MFMA GEMM: C[M,N] = A[M,K] * Bt[N,K]^T (+bias)(+relu) -----------
// GATHER=0: A linear. GATHER=1: ph-style 3-section row gather via map.
// GATHER=2: A row r = gA0[idx0[r]] (full K row gather).
// MODE=0: write f32 C (ldc stride). MODE=1 (Ha GEMM): write bf16 Cb only, and
//         fuse the a1 attention scores: per-row dot with att_s/att_d (flat [N]),
//         16-lane reduce, rep-task-only atomicAdd into a1s/a1d (zero-init'd).
template <int GATHER, int MODE>
__global__ __launch_bounds__(256) void gemm_mfma(
    const float* __restrict__ A,
    const unsigned short* __restrict__ Bh, const unsigned short* __restrict__ Bl,
    const float* __restrict__ bias, float* __restrict__ C,
    unsigned short* __restrict__ Cb, int ldc,
    int M, int N, int K, int act,
    const int* __restrict__ idx0, const int* __restrict__ idx1,
    const int* __restrict__ mapv,
    const float* __restrict__ gA0, const float* __restrict__ gA1,
    const float* __restrict__ att_s, const float* __restrict__ att_d,
    float* __restrict__ a1s, float* __restrict__ a1d) {
  __shared__ __align__(16) unsigned short sAh[8][64][8];
  __shared__ __align__(16) unsigned short sAl[8][64][8];
  __shared__ __align__(16) unsigned short sBh[8][64][8];
  __shared__ __align__(16) unsigned short sBl[8][64][8];
  int tid = threadIdx.x;
  int bm = blockIdx.x * 64, bn = blockIdx.y * 64;
  int lane = tid & 63, w = tid >> 6;
  int wr = (w >> 1) * 32, wc = (w & 1) * 32;
  int fr = lane & 15, fk = lane >> 4;
  f32x4 acc[2][2] = {};

  for (int k0 = 0; k0 < K; k0 += 64) {
    __syncthreads();
#pragma unroll
    for (int t = 0; t < 2; t++) {
      int f = tid + t * 256;
      int row = f >> 3, kb = f & 7;
      int kg = k0 + kb * 8;
      const float* ap;
      if (GATHER == 1) {
        int sec = kg >> 7;           // 64-tiles never straddle 128-col sections
        int kc = kg & 127;
        int r = bm + row;
        if (sec == 0)      ap = &gA0[(size_t)idx0[r] * 128 + kc];
        else if (sec == 1) ap = &gA1[(size_t)mapv[NU + idx1[r]] * 128 + kc];
        else               ap = &gA1[(size_t)mapv[idx0[r]] * 128 + kc];
      } else if (GATHER == 2) {
        ap = &gA0[(size_t)idx0[bm + row] * K + kg];
      } else {
        ap = &A[(size_t)(bm + row) * K + kg];
      }
      float4 v0 = *reinterpret_cast<const float4*>(ap);
      float4 v1 = *reinterpret_cast<const float4*>(ap + 4);
      float vv[8] = {v0.x, v0.y, v0.z, v0.w, v1.x, v1.y, v1.z, v1.w};
      u16x8 hv, lv;
#pragma unroll
      for (int j = 0; j < 8; j++) {
        unsigned short hh = f2bf_rne(vv[j]);
        hv[j] = hh;
        lv[j] = (unsigned short)(__builtin_bit_cast(unsigned int, vv[j] - bf2f(hh)) >> 16);
      }
      *reinterpret_cast<u16x8*>(&sAh[kb][row][0]) = hv;
      *reinterpret_cast<u16x8*>(&sAl[kb][row][0]) = lv;
    }
#pragma unroll
    for (int t = 0; t < 2; t++) {
      int f = tid + t * 256;
      int row = f >> 3, kb = f & 7;
      int kg = k0 + kb * 8;
      *reinterpret_cast<u16x8*>(&sBh[kb][row][0]) =
          *reinterpret_cast<const u16x8*>(&Bh[(size_t)(bn + row) * K + kg]);
      *reinterpret_cast<u16x8*>(&sBl[kb][row][0]) =
          *reinterpret_cast<const u16x8*>(&Bl[(size_t)(bn + row) * K + kg]);
    }
    __syncthreads();
#pragma unroll
    for (int s = 0; s < 2; s++) {
      int kb = s * 4 + fk;
      bf16x8 ah0 = *reinterpret_cast<const bf16x8*>(&sAh[kb][wr + fr][0]);
      bf16x8 ah1 = *reinterpret_cast<const bf16x8*>(&sAh[kb][wr + 16 + fr][0]);
      bf16x8 al0 = *reinterpret_cast<const bf16x8*>(&sAl[kb][wr + fr][0]);
      bf16x8 al1 = *reinterpret_cast<const bf16x8*>(&sAl[kb][wr + 16 + fr][0]);
      bf16x8 bh0 = *reinterpret_cast<const bf16x8*>(&sBh[kb][wc + fr][0]);
      bf16x8 bh1 = *reinterpret_cast<const bf16x8*>(&sBh[kb][wc + 16 + fr][0]);
      bf16x8 bl0 = *reinterpret_cast<const bf16x8*>(&sBl[kb][wc + fr][0]);
      bf16x8 bl1 = *reinterpret_cast<const bf16x8*>(&sBl[kb][wc + 16 + fr][0]);
      acc[0][0] = __builtin_amdgcn_mfma_f32_16x16x32_bf16(al0, bh0, acc[0][0], 0, 0, 0);
      acc[0][0] = __builtin_amdgcn_mfma_f32_16x16x32_bf16(ah0, bl0, acc[0][0], 0, 0, 0);
      acc[0][0] = __builtin_amdgcn_mfma_f32_16x16x32_bf16(ah0, bh0, acc[0][0], 0, 0, 0);
      acc[0][1] = __builtin_amdgcn_mfma_f32_16x16x32_bf16(al0, bh1, acc[0][1], 0, 0, 0);
      acc[0][1] = __builtin_amdgcn_mfma_f32_16x16x32_bf16(ah0, bl1, acc[0][1], 0, 0, 0);
      acc[0][1] = __builtin_amdgcn_mfma_f32_16x16x32_bf16(ah0, bh1, acc[0][1], 0, 0, 0);
      acc[1][0] = __builtin_amdgcn_mfma_f32_16x16x32_bf16(al1, bh0, acc[1][0], 0, 0, 0);
      acc[1][0] = __builtin_amdgcn_mfma_f32_16x16x32_bf16(ah1, bl0, acc[1][0], 0, 0, 0);
      acc[1][0] = __builtin_amdgcn_mfma_f32_16x16x32_bf16(ah1, bh0, acc[1][0], 0, 0, 0);
      acc[1][1] = __builtin_amdgcn_mfma_f32_16x16x32_bf16(al1, bh1, acc[1][1], 0, 0, 0);
      acc[1][1] = __builtin_amdgcn_mfma_f32_16x16x32_bf16(ah1, bl1, acc[1][1], 0, 0, 0);
      acc[1][1] = __builtin_amdgcn_mfma_f32_16x16x32_bf16(ah1, bh1, acc[1][1], 0, 0, 0);
    }
  }
  if (MODE == 1) {
    int head = bn >> 7;
    float ps[2][4] = {{0.f}}, pd[2][4] = {{0.f}};
#pragma unroll
    for (int j = 0; j < 2; j++) {
      int col = bn + wc + j * 16 + fr;
      float asc = att_s[col], adc = att_d[col];
#pragma unroll
      for (int i = 0; i < 2; i++) {
#pragma unroll
        for (int r = 0; r < 4; r++) {
          float v = acc[i][j][r];
          ps[i][r] += v * asc;
          pd[i][r] += v * adc;
          Cb[(size_t)(bm + wr + i * 16 + fk * 4 + r) * ldc + col] = f2bf_rne(v);
        }
      }
    }
#pragma unroll
    for (int o = 1; o < 16; o <<= 1) {
#pragma unroll
      for (int i = 0; i < 2; i++)
#pragma unroll
        for (int r = 0; r < 4; r++) {
          ps[i][r] += __shfl_xor(ps[i][r], o);
          pd[i][r] += __shfl_xor(pd[i][r], o);
        }
    }
    if (fr == 0) {
#pragma unroll
      for (int i = 0; i < 2; i++) {
#pragma unroll
        for (int r = 0; r < 4; r++) {
          int t = bm + wr + i * 16 + fk * 4 + r;
          int v = (t < BB) ? idx0[t] : NU + idx1[t - BB];
          if (mapv[v] == t) {   // rep task only (dups would double-count)
            atomicAdd(&a1s[(size_t)v * 2 + head], ps[i][r]);
            atomicAdd(&a1d[(size_t)v * 2 + head], pd[i][r]);
          }
        }
      }
    }
    return;
  }
#pragma unroll
  for (int j = 0; j < 2; j++) {
    int col = bn + wc + j * 16 + fr;
    float bj = bias ? bias[col] : 0.f;
#pragma unroll
    for (int i = 0; i < 2; i++) {
#pragma unroll
      for (int r = 0; r < 4; r++) {
        int row = bm + wr + i * 16 + fk * 4 + r;
        float v = acc[i][j][r] + bj;
        if (act == 1) v = fmaxf(v, 0.f);
        C[(size_t)row * ldc + col] = v;
      }
    }
  }
}

// ---------------- mega-setup: deg+winner atomics | weight split | Xa-emb+map ------
#define EB 2227    // ceil(ET/256)
#define SPLB 832   // (65536+65536+32768+49152)/256
#define XAB 4096   // NTASK/4
__global__ __launch_bounds__(256) void setup_kernel(
    const int* __restrict__ ei, const int* __restrict__ uid, const int* __restrict__ iid,
    int* __restrict__ deg, int* __restrict__ winner,
    const float* __restrict__ wc, unsigned short* wch, unsigned short* wcl,
    const float* __restrict__ w1, unsigned short* w1h, unsigned short* w1l,
    const float* __restrict__ w2, unsigned short* w2h, unsigned short* w2l,
    const float* __restrict__ pw1, unsigned short* p1h, unsigned short* p1l,
    const float* __restrict__ uemb, const float* __restrict__ iemb,
    float* __restrict__ Xa, int* __restrict__ map) {
  int bid = blockIdx.x, tid = threadIdx.x;
  if (bid < EB) {
    int e = bid * 256 + tid;
    if (e < BB) atomicMax(&winner[iid[e]], e);
    if (e >= ET) return;
    int dst = (e < EE) ? ei[EE + e] : (e - EE);
    atomicAdd(&deg[dst], 1);
    return;
  }
  if (bid < EB + SPLB) {
    int i = (bid - EB) * 256 + tid;
    const float* w; unsigned short* h; unsigned short* l; int idx;
    if (i < 65536) { w = wc; h = wch; l = wcl; idx = i; }
    else if (i < 131072) { w = w1; h = w1h; l = w1l; idx = i - 65536; }
    else if (i < 163840) { w = w2; h = w2h; l = w2l; idx = i - 131072; }
    else { w = pw1; h = p1h; l = p1l; idx = i - 163840; }
    float f = w[idx];
    unsigned short hh = f2bf_rne(f);
    h[idx] = hh;
    l[idx] = (unsigned short)(__builtin_bit_cast(unsigned int, f - bf2f(hh)) >> 16);
    return;
  }
  // Xa embedding parts + map (content section filled later by gather-A GEMM)
  int t = (bid - EB - SPLB) * 4 + (tid >> 6);
  int lane = tid & 63;
  int c4 = lane * 4;
  if (t < BB) {
    int u = uid[t];
    float4 v = make_float4(0.f, 0.f, 0.f, 0.f);
    if (c4 < DD) v = *reinterpret_cast<const float4*>(&uemb[(size_t)u * DD + c4]);
    *reinterpret_cast<float4*>(&Xa[(size_t)t * 256 + c4]) = v;
    if (lane == 0) map[u] = t;
  } else {
    int it = iid[t - BB];
    if (c4 < DD) {
      float4 v = *reinterpret_cast<const float4*>(&iemb[(size_t)it * DD + c4]);
      *reinterpret_cast<float4*>(&Xa[(size_t)t * 256 + c4]) = v;
    }
    if (lane == 0) map[NU + it] = t;
  }
}

// rowstart + widx; last block computes the conv2 q-vectors.
__global__ void rowstart_kernel(const int* __restrict__ deg, const int* __restrict__ winner,
                                const int* __restrict__ iid,
                                int* __restrict__ rowstart, int* __restrict__ fill,
                                int* __restrict__ counter, int* __restrict__ widx,
                                const float* __restrict__ w2,
                                const float* __restrict__ att2s, const float* __restrict__ att2d,
                                float* __restrict__ qs, float* __restrict__ qd) {
  int blk = blockIdx.x;
  if (blk == (NN + 255) / 256) {
    int k = threadIdx.x;  // 0..255
    float s = 0.f, d = 0.f;
#pragma unroll 4
    for (int j = 0; j < DD; j++) {
      float w = w2[(size_t)j * 256 + k];
      s += att2s[j] * w;
      d += att2d[j] * w;
    }
    qs[k] = s;
    qd[k] = d;
    return;
  }
  int v = blk * 256 + threadIdx.x;
  if (v < BB) widx[v] = winner[iid[v]];
  if (v >= NN) return;
  int s = atomicAdd(counter, deg[v]);
  rowstart[v] = s;
  fill[v] = s;
}

// CSR fill + needed-mark (sources of batch-dst edges), one edge pass
__global__ void fill_mark_kernel(const int* __restrict__ ei, int* __restrict__ fill,
                                 int* __restrict__ col, const int* __restrict__ map,
                                 unsigned char* __restrict__ needed) {
  int e = blockIdx.x * 256 + threadIdx.x;
  if (e >= ET) return;
  int src, dst;
  if (e < EE) { src = ei[e]; dst = ei[EE + e]; }
  else { src = e - EE; dst = src; }
  int pos = atomicAdd(&fill[dst], 1);
  col[pos] = src;
  if (map[dst] >= 0) needed[src] = 1;
}

// conv1 aggregation: bf16 Hb gather (512B rows), needed-skip, fused a2 scores.
__global__ __launch_bounds__(256) void conv1_agg_kernel(
    const int* __restrict__ col, const int* __restrict__ rowstart,
    const int* __restrict__ deg, const unsigned short* __restrict__ Hb,
    const int* __restrict__ map, const unsigned char* __restrict__ needed,
    const float* __restrict__ a1s, const float* __restrict__ a1d,
    const float* __restrict__ bias,
    const float* __restrict__ qs, const float* __restrict__ qd,
    unsigned short* __restrict__ x1b, float* __restrict__ a2s, float* __restrict__ a2d) {
  int v = blockIdx.x * 4 + (threadIdx.x >> 6);
  int lane = threadIdx.x & 63;
  if (!needed[v]) return;
  int head = lane >> 5;
  int d = deg[v], s0 = rowstart[v];
  float2 adv = *reinterpret_cast<const float2*>(&a1d[(size_t)v * 2]);
  float4 acc = make_float4(0.f, 0.f, 0.f, 0.f);
  float den;
  if (d <= 64) {
    bool act = lane < d;
    int ci = act ? col[s0 + lane] : 0;
    float2 asv = make_float2(0.f, 0.f);
    int ri = -1;
    if (act) {
      asv = *reinterpret_cast<const float2*>(&a1s[(size_t)ci * 2]);
      ri = map[ci];
    }
    float al0 = act ? lrelu(asv.x + adv.x) : -1e30f;
    float al1 = act ? lrelu(asv.y + adv.y) : -1e30f;
    float m0 = al0, m1 = al1;
#pragma unroll
    for (int o = 1; o < 64; o <<= 1) {
      m0 = fmaxf(m0, __shfl_xor(m0, o));
      m1 = fmaxf(m1, __shfl_xor(m1, o));
    }
    float ex0 = act ? __expf(al0 - m0) : 0.f;
    float ex1 = act ? __expf(al1 - m1) : 0.f;
    float cs0 = ex0, cs1 = ex1;
#pragma unroll
    for (int o = 1; o < 64; o <<= 1) {
      cs0 += __shfl_xor(cs0, o);
      cs1 += __shfl_xor(cs1, o);
    }
    den = head ? cs1 : cs0;
    for (int i2 = 0; i2 < d; i2++) {
      int r = __shfl(ri, i2);
      if (r >= 0) {
        float e0 = __shfl(ex0, i2), e1 = __shfl(ex1, i2);
        float ex = head ? e1 : e0;
        ushort4 hv = *reinterpret_cast<const ushort4*>(&Hb[((size_t)r << 8) + (lane << 2)]);
        acc.x += ex * bf2f(hv.x); acc.y += ex * bf2f(hv.y);
        acc.z += ex * bf2f(hv.z); acc.w += ex * bf2f(hv.w);
      }
    }
  } else {
    float m0 = -1e30f, m1 = -1e30f, den0 = 0.f, den1 = 0.f;
    for (int c0 = 0; c0 < d; c0 += 64) {
      int i = c0 + lane;
      bool act = i < d;
      int ci = act ? col[s0 + i] : 0;
      float2 asv = make_float2(0.f, 0.f);
      int ri = -1;
      if (act) {
        asv = *reinterpret_cast<const float2*>(&a1s[(size_t)ci * 2]);
        ri = map[ci];
      }
      float al0 = act ? lrelu(asv.x + adv.x) : -1e30f;
      float al1 = act ? lrelu(asv.y + adv.y) : -1e30f;
      float cm0 = al0, cm1 = al1;
#pragma unroll
      for (int o = 1; o < 64; o <<= 1) {
        cm0 = fmaxf(cm0, __shfl_xor(cm0, o));
        cm1 = fmaxf(cm1, __shfl_xor(cm1, o));
      }
      float nm0 = fmaxf(m0, cm0), nm1 = fmaxf(m1, cm1);
      float ex0 = act ? __expf(al0 - nm0) : 0.f;
      float ex1 = act ? __expf(al1 - nm1) : 0.f;
      float s0f = __expf(m0 - nm0), s1f = __expf(m1 - nm1);
      float cs0 = ex0, cs1 = ex1;
#pragma unroll
      for (int o = 1; o < 64; o <<= 1) {
        cs0 += __shfl_xor(cs0, o);
        cs1 += __shfl_xor(cs1, o);
      }
      den0 = den0 * s0f + cs0;
      den1 = den1 * s1f + cs1;
      float sc = head ? s1f : s0f;
      acc.x *= sc; acc.y *= sc; acc.z *= sc; acc.w *= sc;
      int n = min(64, d - c0);
      for (int i2 = 0; i2 < n; i2++) {
        int r = __shfl(ri, i2);
        if (r >= 0) {
          float e0 = __shfl(ex0, i2), e1 = __shfl(ex1, i2);
          float ex = head ? e1 : e0;
          ushort4 hv = *reinterpret_cast<const ushort4*>(&Hb[((size_t)r << 8) + (lane << 2)]);
          acc.x += ex * bf2f(hv.x); acc.y += ex * bf2f(hv.y);
          acc.z += ex * bf2f(hv.z); acc.w += ex * bf2f(hv.w);
        }
      }
      m0 = nm0; m1 = nm1;
    }
    den = head ? den1 : den0;
  }
  float inv = 1.f / den;
  float4 b4 = *reinterpret_cast<const float4*>(&bias[lane << 2]);
  float4 o;
  o.x = fmaf(acc.x, inv, b4.x);
  o.y = fmaf(acc.y, inv, b4.y);
  o.z = fmaf(acc.z, inv, b4.z);
  o.w = fmaf(acc.w, inv, b4.w);
  o.x = o.x > 0.f ? o.x : __expf(o.x) - 1.f;
  o.y = o.y > 0.f ? o.y : __expf(o.y) - 1.f;
  o.z = o.z > 0.f ? o.z : __expf(o.z) - 1.f;
  o.w = o.w > 0.f ? o.w : __expf(o.w) - 1.f;
  ushort4 st;
  st.x = f2bf_rne(o.x); st.y = f2bf_rne(o.y);
  st.z = f2bf_rne(o.z); st.w = f2bf_rne(o.w);
  *reinterpret_cast<ushort4*>(&x1b[((size_t)v << 8) + (lane << 2)]) = st;
  float4 sv = *reinterpret_cast<const float4*>(&qs[lane << 2]);
  float4 dv = *reinterpret_cast<const float4*>(&qd[lane << 2]);
  float ps = o.x * sv.x + o.y * sv.y + o.z * sv.z + o.w * sv.w;
  float pd = o.x * dv.x + o.y * dv.y + o.z * dv.z + o.w * dv.w;
#pragma unroll
  for (int of = 1; of < 64; of <<= 1) { ps += __shfl_xor(ps, of); pd += __shfl_xor(pd, of); }
  if (lane == 0) { a2s[v] = ps; a2d[v] = pd; }
}

// conv2 aggregation, representative tasks only (map[v]==t); bf16 x1 gather.
__global__ __launch_bounds__(256) void conv2_agg_kernel(
    const int* __restrict__ uid, const int* __restrict__ iid,
    const int* __restrict__ col, const int* __restrict__ rowstart,
    const int* __restrict__ deg, const int* __restrict__ map,
    const unsigned short* __restrict__ x1b,
    const float* __restrict__ a2s, const float* __restrict__ a2d,
    float* __restrict__ agg) {
  int t = blockIdx.x * 4 + (threadIdx.x >> 6);
  int lane = threadIdx.x & 63;
  int v = (t < BB) ? uid[t] : NU + iid[t - BB];
  if (map[v] != t) return;  // duplicates gather the rep's row via map in the ph GEMM
  int d = deg[v], s0 = rowstart[v];
  float ad = a2d[v];
  float4 acc = make_float4(0.f, 0.f, 0.f, 0.f);
  float den;
  if (d <= 64) {
    bool act = lane < d;
    int ci = act ? col[s0 + lane] : 0;
    float as = act ? a2s[ci] : 0.f;
    float al = act ? lrelu(as + ad) : -1e30f;
    float m = al;
#pragma unroll
    for (int o = 1; o < 64; o <<= 1) m = fmaxf(m, __shfl_xor(m, o));
    float ex = act ? __expf(al - m) : 0.f;
    float cs = ex;
#pragma unroll
    for (int o = 1; o < 64; o <<= 1) cs += __shfl_xor(cs, o);
    den = cs;
    for (int i2 = 0; i2 < d; i2++) {
      int r = __shfl(ci, i2);
      float e = __shfl(ex, i2);
      ushort4 hv = *reinterpret_cast<const ushort4*>(&x1b[((size_t)r << 8) + (lane << 2)]);
      acc.x += e * bf2f(hv.x); acc.y += e * bf2f(hv.y);
      acc.z += e * bf2f(hv.z); acc.w += e * bf2f(hv.w);
    }
  } else {
    float m = -1e30f; den = 0.f;
    for (int c0 = 0; c0 < d; c0 += 64) {
      int i = c0 + lane;
      bool act = i < d;
      int ci = act ? col[s0 + i] : 0;
      float as = act ? a2s[ci] : 0.f;
      float al = act ? lrelu(as + ad) : -1e30f;
      float cm = al;
#pragma unroll
      for (int o = 1; o < 64; o <<= 1) cm = fmaxf(cm, __shfl_xor(cm, o));
      float nm = fmaxf(m, cm);
      float ex = act ? __expf(al - nm) : 0.f;
      float sf = __expf(m - nm);
      float cs = ex;
#pragma unroll
      for (int o = 1; o < 64; o <<= 1) cs += __shfl_xor(cs, o);
      den = den * sf + cs;
      acc.x *= sf; acc.y *= sf; acc.z *= sf; acc.w *= sf;
      int n = min(64, d - c0);
      for (int i2 = 0; i2 < n; i2++) {
        int r = __shfl(ci, i2);
        float e = __shfl(ex, i2);
        ushort4 hv = *reinterpret_cast<const ushort4*>(&x1b[((size_t)r << 8) + (lane << 2)]);
        acc.x += e * bf2f(hv.x); acc.y += e * bf2f(hv.y);
        acc.z += e * bf2f(hv.z); acc.w += e * bf2f(hv.w);
      }
      m = nm;
    }
  }
  float inv = 1.f / den;
  float4 o = make_float4(acc.x * inv, acc.y * inv, acc.z * inv, acc.w * inv);
  *reinterpret_cast<float4*>(&agg[((size_t)t << 8) + (lane << 2)]) = o;
}

__global__ __launch_bounds__(256) void final_kernel(
    const float* __restrict__ ph, const float* __restrict__ w2,
    const float* __restrict__ b2, float* __restrict__ out) {
  int b = blockIdx.x * 4 + (threadIdx.x >> 6);
  int lane = threadIdx.x & 63;
  float2 hv = *reinterpret_cast<const float2*>(&ph[((size_t)b << 7) + (lane << 1)]);
  float2 wv = *reinterpret_cast<const float2*>(&w2[lane << 1]);
  float s = hv.x * wv.x + hv.y * wv.y;
  for (int o = 1; o < 64; o <<= 1) s += __shfl_xor(s, o);
  if (lane == 0) out[b] = s + b2[0];
}

// ---------------- launcher ----------------
extern "C" void kernel_launch(void* const* d_in, const int* in_sizes, int n_in,
                              void* d_out, int out_size, void* d_ws, size_t ws_size,
                              hipStream_t stream) {
  const int* uid = (const int*)d_in[0];
  const int* iid = (const int*)d_in[1];
  const float* content = (const float*)d_in[2];
  const int* ei = (const int*)d_in[3];
  const float* uemb = (const float*)d_in[4];
  const float* iemb = (const float*)d_in[5];
  const float* wc = (const float*)d_in[6];
  const float* bc = (const float*)d_in[7];
  const float* w1 = (const float*)d_in[8];
  const float* att1s = (const float*)d_in[9];
  const float* att1d = (const float*)d_in[10];
  const float* b1 = (const float*)d_in[11];
  const float* w2 = (const float*)d_in[12];
  const float* att2s = (const float*)d_in[13];
  const float* att2d = (const float*)d_in[14];
  const float* b2c = (const float*)d_in[15];
  const float* pw1 = (const float*)d_in[16];
  const float* pb1 = (const float*)d_in[17];
  const float* pw2 = (const float*)d_in[18];
  const float* pb2 = (const float*)d_in[19];
  float* out = (float*)d_out;
  char* ws = (char*)d_ws;

  size_t off = 0;
  auto alloc = [&](size_t bytes) {
    size_t o = off;
    off += (bytes + 255) & ~(size_t)255;
    return o;
  };
  size_t o_winner  = alloc(NI * 4);
  size_t o_map     = alloc(NN * 4);
  size_t o_a1s     = alloc((size_t)NN * 2 * 4);
  size_t o_a1d     = alloc((size_t)NN * 2 * 4);
  size_t o_deg     = alloc(NN * 4);
  size_t o_rs      = alloc(NN * 4);
  size_t o_fill    = alloc(NN * 4);
  size_t o_cnt     = alloc(4);
  size_t o_needed  = alloc(NN);
  size_t o_col     = alloc((size_t)ET * 4);
  size_t o_a2s     = alloc(NN * 4);
  size_t o_a2d     = alloc(NN * 4);
  size_t o_qs      = alloc(256 * 4);
  size_t o_qd      = alloc(256 * 4);
  size_t o_widx    = alloc(BB * 4);
  // split weights (bf16 hi/lo)
  size_t o_wch = alloc(65536 * 2),  o_wcl = alloc(65536 * 2);
  size_t o_w1h = alloc(65536 * 2),  o_w1l = alloc(65536 * 2);
  size_t o_w2h = alloc(32768 * 2),  o_w2l = alloc(32768 * 2);
  size_t o_p1h = alloc(49152 * 2),  o_p1l = alloc(49152 * 2);
  // region R1 (25.2MB): Xa f32 (16.78M) | Hb bf16 (8.39M)
  // reuse: agg @ Xa (Xa dead after Ha GEMM); out2c @ Hb (Hb dead after conv1);
  //        ph @ agg (agg dead after out2c GEMM)
  size_t o_r1    = alloc(16777216 + 8388608);
  size_t o_xa    = o_r1;
  size_t o_hb    = o_r1 + 16777216;
  size_t o_agg   = o_r1;
  size_t o_out2c = o_r1 + 16777216;
  size_t o_ph    = o_r1;
  // region R2: x1 bf16 [NN,256]
  size_t o_x1b   = alloc((size_t)NN * 256 * 2);
  (void)ws_size; (void)in_sizes; (void)n_in; (void)out_size;

  int*   winner = (int*)(ws + o_winner);
  int*   map    = (int*)(ws + o_map);
  float* a1s    = (float*)(ws + o_a1s);
  float* a1d    = (float*)(ws + o_a1d);
  int*   deg    = (int*)(ws + o_deg);
  int*   rs     = (int*)(ws + o_rs);
  int*   fill   = (int*)(ws + o_fill);
  int*   cnt    = (int*)(ws + o_cnt);
  unsigned char* needed = (unsigned char*)(ws + o_needed);
  int*   col    = (int*)(ws + o_col);
  float* a2s    = (float*)(ws + o_a2s);
  float* a2d    = (float*)(ws + o_a2d);
  float* qs     = (float*)(ws + o_qs);
  float* qd     = (float*)(ws + o_qd);
  int*   widx   = (int*)(ws + o_widx);
  unsigned short* wch = (unsigned short*)(ws + o_wch);
  unsigned short* wcl = (unsigned short*)(ws + o_wcl);
  unsigned short* w1h = (unsigned short*)(ws + o_w1h);
  unsigned short* w1l = (unsigned short*)(ws + o_w1l);
  unsigned short* w2h = (unsigned short*)(ws + o_w2h);
  unsigned short* w2l = (unsigned short*)(ws + o_w2l);
  unsigned short* p1h = (unsigned short*)(ws + o_p1h);
  unsigned short* p1l = (unsigned short*)(ws + o_p1l);
  float* Xa     = (float*)(ws + o_xa);
  unsigned short* Hb = (unsigned short*)(ws + o_hb);
  float* agg    = (float*)(ws + o_agg);
  float* out2c  = (float*)(ws + o_out2c);
  float* ph     = (float*)(ws + o_ph);
  unsigned short* x1b = (unsigned short*)(ws + o_x1b);

  // merged memsets over adjacent regions (pad bytes are don't-care)
  hipMemsetAsync(ws + o_winner, 0xFF, o_map - o_winner + (size_t)NN * 4, stream);   // winner|map
  hipMemsetAsync(ws + o_a1s, 0, o_a1d - o_a1s + (size_t)NN * 2 * 4, stream);         // a1s|a1d (atomic targets)
  hipMemsetAsync(ws + o_deg, 0, o_needed - o_deg + NN, stream);                      // deg|rs|fill|cnt|needed

  // mega-setup: edge deg+winner | weight split | Xa emb parts + map
  setup_kernel<<<EB + SPLB + XAB, 256, 0, stream>>>(
      ei, uid, iid, deg, winner,
      wc, wch, wcl, w1, w1h, w1l, w2, w2h, w2l, pw1, p1h, p1l,
      uemb, iemb, Xa, map);
  rowstart_kernel<<<(NN + 255) / 256 + 1, 256, 0, stream>>>(
      deg, winner, iid, rs, fill, cnt, widx, w2, att2s, att2d, qs, qd);
  // content section of Xa: rows BB..2BB, cols 128..256 = content[widx[r]] @ Wc^T + bc
  {
    dim3 g(BB / 64, DD / 64);
    gemm_mfma<2, 0><<<g, 256, 0, stream>>>(
        nullptr, wch, wcl, bc, Xa + (size_t)BB * 256 + 128, nullptr, 256,
        BB, DD, 512, 0, widx, nullptr, nullptr, content, nullptr,
        nullptr, nullptr, nullptr, nullptr);
  }
  fill_mark_kernel<<<(ET + 255) / 256, 256, 0, stream>>>(ei, fill, col, map, needed);
  // Hb = bf16(Xa @ W1^T), with fused a1 score atomics
  {
    dim3 g(NTASK / 64, 256 / 64);
    gemm_mfma<0, 1><<<g, 256, 0, stream>>>(
        Xa, w1h, w1l, nullptr, nullptr, Hb, 256,
        NTASK, 256, 256, 0, uid, iid, map, nullptr, nullptr,
        att1s, att1d, a1s, a1d);
  }
  conv1_agg_kernel<<<NN / 4, 256, 0, stream>>>(col, rs, deg, Hb, map, needed,
                                               a1s, a1d, b1, qs, qd, x1b, a2s, a2d);
  conv2_agg_kernel<<<NTASK / 4, 256, 0, stream>>>(uid, iid, col, rs, deg, map,
                                                  x1b, a2s, a2d, agg);
  // out2c = agg @ W2^T + b2c (non-rep rows are garbage, never read downstream)
  {
    dim3 g(NTASK / 64, DD / 64);
    gemm_mfma<0, 0><<<g, 256, 0, stream>>>(
        agg, w2h, w2l, b2c, out2c, nullptr, 128,
        NTASK, DD, 256, 0, nullptr, nullptr, nullptr, nullptr, nullptr,
        nullptr, nullptr, nullptr, nullptr);
  }
  // ph = relu([uemb[uid] | out2c[map[item]] | out2c[map[user]]] @ pw1^T + pb1)
  {
    dim3 g(BB / 64, DD / 64);
    gemm_mfma<1, 0><<<g, 256, 0, stream>>>(
        nullptr, p1h, p1l, pb1, ph, nullptr, 128,
        BB, DD, 384, 1, uid, iid, map, uemb, out2c,
        nullptr, nullptr, nullptr, nullptr);
  }
  final_kernel<<<BB / 4, 256, 0, stream>>>(ph, pw2, pb2, out);
}

// Round 9
// 212.521 us; speedup vs baseline: 2.1063x; 1.0377x over previous
//
#include <hip/hip_runtime.h>
#include <hip/hip_bf16.h>

#define NU 50000
#define NI 20000
#define NN 70000
#define DD 128
#define BB 8192
#define EE 500000
#define ET 570000   // EE + NN self loops
#define NTASK 16384 // 2*BB

__device__ __forceinline__ float lrelu(float x) { return x > 0.f ? x : 0.2f * x; }

typedef __attribute__((ext_vector_type(8))) short bf16x8;   // 8 bf16 = 4 VGPRs
typedef __attribute__((ext_vector_type(8))) unsigned short u16x8;
typedef __attribute__((ext_vector_type(4))) float f32x4;

__device__ __forceinline__ unsigned short f2bf_rne(float f) {
  unsigned int u = __builtin_bit_cast(unsigned int, f);
  u += 0x7FFFu + ((u >> 16) & 1u);
  return (unsigned short)(u >> 16);
}
__device__ __forceinline__ float bf2f(unsigned short h) {
  unsigned int u = ((unsigned int)h) << 16;
  return __builtin_bit_cast(float, u);
}

// ---------------- MFMA GEMM core (device fn): C[M,N] = A * Bt^T (+bias)(+relu) ----
// GATHER=0: A linear. GATHER=1: ph-style 3-section row gather. GATHER=2: row gather.
// MODE=0: f32 C. MODE=1: bf16 Cb + fused a1 attention-score atomics.
template <int GATHER, int MODE>
__device__ __forceinline__ void gemm_core(
    int bm, int bn,
    const float* __restrict__ A,
    const unsigned short* __restrict__ Bh, const unsigned short* __restrict__ Bl,
    const float* __restrict__ bias, float* __restrict__ C,
    unsigned short* __restrict__ Cb, int ldc,
    int M, int N, int K, int act,
    const int* __restrict__ idx0, const int* __restrict__ idx1,
    const int* __restrict__ mapv,
    const float* __restrict__ gA0, const float* __restrict__ gA1,
    const float* __restrict__ att_s, const float* __restrict__ att_d,
    float* __restrict__ a1s, float* __restrict__ a1d) {
  __shared__ __align__(16) unsigned short sAh[8][64][8];
  __shared__ __align__(16) unsigned short sAl[8][64][8];
  __shared__ __align__(16) unsigned short sBh[8][64][8];
  __shared__ __align__(16) unsigned short sBl[8][64][8];
  int tid = threadIdx.x;
  int lane = tid & 63, w = tid >> 6;
  int wr = (w >> 1) * 32, wc = (w & 1) * 32;
  int fr = lane & 15, fk = lane >> 4;
  f32x4 acc[2][2] = {};

  for (int k0 = 0; k0 < K; k0 += 64) {
    __syncthreads();
#pragma unroll
    for (int t = 0; t < 2; t++) {
      int f = tid + t * 256;
      int row = f >> 3, kb = f & 7;
      int kg = k0 + kb * 8;
      const float* ap;
      if (GATHER == 1) {
        int sec = kg >> 7;           // 64-tiles never straddle 128-col sections
        int kc = kg & 127;
        int r = bm + row;
        if (sec == 0)      ap = &gA0[(size_t)idx0[r] * 128 + kc];
        else if (sec == 1) ap = &gA1[(size_t)mapv[NU + idx1[r]] * 128 + kc];
        else               ap = &gA1[(size_t)mapv[idx0[r]] * 128 + kc];
      } else if (GATHER == 2) {
        ap = &gA0[(size_t)idx0[bm + row] * K + kg];
      } else {
        ap = &A[(size_t)(bm + row) * K + kg];
      }
      float4 v0 = *reinterpret_cast<const float4*>(ap);
      float4 v1 = *reinterpret_cast<const float4*>(ap + 4);
      float vv[8] = {v0.x, v0.y, v0.z, v0.w, v1.x, v1.y, v1.z, v1.w};
      u16x8 hv, lv;
#pragma unroll
      for (int j = 0; j < 8; j++) {
        unsigned short hh = f2bf_rne(vv[j]);
        hv[j] = hh;
        lv[j] = (unsigned short)(__builtin_bit_cast(unsigned int, vv[j] - bf2f(hh)) >> 16);
      }
      *reinterpret_cast<u16x8*>(&sAh[kb][row][0]) = hv;
      *reinterpret_cast<u16x8*>(&sAl[kb][row][0]) = lv;
    }
#pragma unroll
    for (int t = 0; t < 2; t++) {
      int f = tid + t * 256;
      int row = f >> 3, kb = f & 7;
      int kg = k0 + kb * 8;
      *reinterpret_cast<u16x8*>(&sBh[kb][row][0]) =
          *reinterpret_cast<const u16x8*>(&Bh[(size_t)(bn + row) * K + kg]);
      *reinterpret_cast<u16x8*>(&sBl[kb][row][0]) =
          *reinterpret_cast<const u16x8*>(&Bl[(size_t)(bn + row) * K + kg]);
    }
    __syncthreads();
#pragma unroll
    for (int s = 0; s < 2; s++) {
      int kb = s * 4 + fk;
      bf16x8 ah0 = *reinterpret_cast<const bf16x8*>(&sAh[kb][wr + fr][0]);
      bf16x8 ah1 = *reinterpret_cast<const bf16x8*>(&sAh[kb][wr + 16 + fr][0]);
      bf16x8 al0 = *reinterpret_cast<const bf16x8*>(&sAl[kb][wr + fr][0]);
      bf16x8 al1 = *reinterpret_cast<const bf16x8*>(&sAl[kb][wr + 16 + fr][0]);
      bf16x8 bh0 = *reinterpret_cast<const bf16x8*>(&sBh[kb][wc + fr][0]);
      bf16x8 bh1 = *reinterpret_cast<const bf16x8*>(&sBh[kb][wc + 16 + fr][0]);
      bf16x8 bl0 = *reinterpret_cast<const bf16x8*>(&sBl[kb][wc + fr][0]);
      bf16x8 bl1 = *reinterpret_cast<const bf16x8*>(&sBl[kb][wc + 16 + fr][0]);
      acc[0][0] = __builtin_amdgcn_mfma_f32_16x16x32_bf16(al0, bh0, acc[0][0], 0, 0, 0);
      acc[0][0] = __builtin_amdgcn_mfma_f32_16x16x32_bf16(ah0, bl0, acc[0][0], 0, 0, 0);
      acc[0][0] = __builtin_amdgcn_mfma_f32_16x16x32_bf16(ah0, bh0, acc[0][0], 0, 0, 0);
      acc[0][1] = __builtin_amdgcn_mfma_f32_16x16x32_bf16(al0, bh1, acc[0][1], 0, 0, 0);
      acc[0][1] = __builtin_amdgcn_mfma_f32_16x16x32_bf16(ah0, bl1, acc[0][1], 0, 0, 0);
      acc[0][1] = __builtin_amdgcn_mfma_f32_16x16x32_bf16(ah0, bh1, acc[0][1], 0, 0, 0);
      acc[1][0] = __builtin_amdgcn_mfma_f32_16x16x32_bf16(al1, bh0, acc[1][0], 0, 0, 0);
      acc[1][0] = __builtin_amdgcn_mfma_f32_16x16x32_bf16(ah1, bl0, acc[1][0], 0, 0, 0);
      acc[1][0] = __builtin_amdgcn_mfma_f32_16x16x32_bf16(ah1, bh0, acc[1][0], 0, 0, 0);
      acc[1][1] = __builtin_amdgcn_mfma_f32_16x16x32_bf16(al1, bh1, acc[1][1], 0, 0, 0);
      acc[1][1] = __builtin_amdgcn_mfma_f32_16x16x32_bf16(ah1, bl1, acc[1][1], 0, 0, 0);
      acc[1][1] = __builtin_amdgcn_mfma_f32_16x16x32_bf16(ah1, bh1, acc[1][1], 0, 0, 0);
    }
  }
  if (MODE == 1) {
    int head = bn >> 7;
    float ps[2][4] = {{0.f}}, pd[2][4] = {{0.f}};
#pragma unroll
    for (int j = 0; j < 2; j++) {
      int col = bn + wc + j * 16 + fr;
      float asc = att_s[col], adc = att_d[col];
#pragma unroll
      for (int i = 0; i < 2; i++) {
#pragma unroll
        for (int r = 0; r < 4; r++) {
          float v = acc[i][j][r];
          ps[i][r] += v * asc;
          pd[i][r] += v * adc;
          Cb[(size_t)(bm + wr + i * 16 + fk * 4 + r) * ldc + col] = f2bf_rne(v);
        }
      }
    }
#pragma unroll
    for (int o = 1; o < 16; o <<= 1) {
#pragma unroll
      for (int i = 0; i < 2; i++)
#pragma unroll
        for (int r = 0; r < 4; r++) {
          ps[i][r] += __shfl_xor(ps[i][r], o);
          pd[i][r] += __shfl_xor(pd[i][r], o);
        }
    }
    if (fr == 0) {
#pragma unroll
      for (int i = 0; i < 2; i++) {
#pragma unroll
        for (int r = 0; r < 4; r++) {
          int t = bm + wr + i * 16 + fk * 4 + r;
          int v = (t < BB) ? idx0[t] : NU + idx1[t - BB];
          if (mapv[v] == t) {   // rep task only (dups would double-count)
            atomicAdd(&a1s[(size_t)v * 2 + head], ps[i][r]);
            atomicAdd(&a1d[(size_t)v * 2 + head], pd[i][r]);
          }
        }
      }
    }
    return;
  }
#pragma unroll
  for (int j = 0; j < 2; j++) {
    int col = bn + wc + j * 16 + fr;
    float bj = bias ? bias[col] : 0.f;
#pragma unroll
    for (int i = 0; i < 2; i++) {
#pragma unroll
      for (int r = 0; r < 4; r++) {
        int row = bm + wr + i * 16 + fk * 4 + r;
        float v = acc[i][j][r] + bj;
        if (act == 1) v = fmaxf(v, 0.f);
        C[(size_t)row * ldc + col] = v;
      }
    }
  }
}

template <int GATHER, int MODE>
__global__ __launch_bounds__(256) void gemm_mfma(
    const float* __restrict__ A,
    const unsigned short* __restrict__ Bh, const unsigned short* __restrict__ Bl,
    const float* __restrict__ bias, float* __restrict__ C,
    unsigned short* __restrict__ Cb, int ldc,
    int M, int N, int K, int act,
    const int* __restrict__ idx0, const int* __restrict__ idx1,
    const int* __restrict__ mapv,
    const float* __restrict__ gA0, const float* __restrict__ gA1,
    const float* __restrict__ att_s, const float* __restrict__ att_d,
    float* __restrict__ a1s, float* __restrict__ a1d) {
  gemm_core<GATHER, MODE>(blockIdx.x * 64, blockIdx.y * 64,
                          A, Bh, Bl, bias, C, Cb, ldc, M, N, K, act,
                          idx0, idx1, mapv, gA0, gA1, att_s, att_d, a1s, a1d);
}

// cemb GEMM (gather-A) + CSR fill + needed-mark in ONE launch (independent work).
#define GEMMB 256  // (BB/64) * (DD/64)
__global__ __launch_bounds__(256) void cembfill_kernel(
    const unsigned short* __restrict__ wch, const unsigned short* __restrict__ wcl,
    const float* __restrict__ bc, float* __restrict__ XaC,
    const int* __restrict__ widx, const float* __restrict__ content,
    const int* __restrict__ ei, int* __restrict__ fill, int* __restrict__ col,
    const int* __restrict__ mapv, unsigned char* __restrict__ needed) {
  int bid = blockIdx.x;
  if (bid < GEMMB) {
    gemm_core<2, 0>((bid >> 1) * 64, (bid & 1) * 64,
                    nullptr, wch, wcl, bc, XaC, nullptr, 256,
                    BB, DD, 512, 0, widx, nullptr, nullptr, content, nullptr,
                    nullptr, nullptr, nullptr, nullptr);
    return;
  }
  int e = (bid - GEMMB) * 256 + threadIdx.x;
  if (e >= ET) return;
  int src, dst;
  if (e < EE) { src = ei[e]; dst = ei[EE + e]; }
  else { src = e - EE; dst = src; }
  int pos = atomicAdd(&fill[dst], 1);
  col[pos] = src;
  if (mapv[dst] >= 0) needed[src] = 1;
}

// ---------------- mega-setup: deg+winner atomics | weight split | Xa-emb+map ------
#define EB 2227    // ceil(ET/256)
#define SPLB 832   // (65536+65536+32768+49152)/256
#define XAB 4096   // NTASK/4
__global__ __launch_bounds__(256) void setup_kernel(
    const int* __restrict__ ei, const int* __restrict__ uid, const int* __restrict__ iid,
    int* __restrict__ deg, int* __restrict__ winner,
    const float* __restrict__ wc, unsigned short* wch, unsigned short* wcl,
    const float* __restrict__ w1, unsigned short* w1h, unsigned short* w1l,
    const float* __restrict__ w2, unsigned short* w2h, unsigned short* w2l,
    const float* __restrict__ pw1, unsigned short* p1h, unsigned short* p1l,
    const float* __restrict__ uemb, const float* __restrict__ iemb,
    float* __restrict__ Xa, int* __restrict__ map) {
  int bid = blockIdx.x, tid = threadIdx.x;
  if (bid < EB) {
    int e = bid * 256 + tid;
    if (e < BB) atomicMax(&winner[iid[e]], e);
    if (e >= ET) return;
    int dst = (e < EE) ? ei[EE + e] : (e - EE);
    atomicAdd(&deg[dst], 1);
    return;
  }
  if (bid < EB + SPLB) {
    int i = (bid - EB) * 256 + tid;
    const float* w; unsigned short* h; unsigned short* l; int idx;
    if (i < 65536) { w = wc; h = wch; l = wcl; idx = i; }
    else if (i < 131072) { w = w1; h = w1h; l = w1l; idx = i - 65536; }
    else if (i < 163840) { w = w2; h = w2h; l = w2l; idx = i - 131072; }
    else { w = pw1; h = p1h; l = p1l; idx = i - 163840; }
    float f = w[idx];
    unsigned short hh = f2bf_rne(f);
    h[idx] = hh;
    l[idx] = (unsigned short)(__builtin_bit_cast(unsigned int, f - bf2f(hh)) >> 16);
    return;
  }
  // Xa embedding parts + map (content section filled later by gather-A GEMM)
  int t = (bid - EB - SPLB) * 4 + (tid >> 6);
  int lane = tid & 63;
  int c4 = lane * 4;
  if (t < BB) {
    int u = uid[t];
    float4 v = make_float4(0.f, 0.f, 0.f, 0.f);
    if (c4 < DD) v = *reinterpret_cast<const float4*>(&uemb[(size_t)u * DD + c4]);
    *reinterpret_cast<float4*>(&Xa[(size_t)t * 256 + c4]) = v;
    if (lane == 0) map[u] = t;
  } else {
    int it = iid[t - BB];
    if (c4 < DD) {
      float4 v = *reinterpret_cast<const float4*>(&iemb[(size_t)it * DD + c4]);
      *reinterpret_cast<float4*>(&Xa[(size_t)t * 256 + c4]) = v;
    }
    if (lane == 0) map[NU + it] = t;
  }
}

// rowstart + widx; last block computes the conv2 q-vectors.
__global__ void rowstart_kernel(const int* __restrict__ deg, const int* __restrict__ winner,
                                const int* __restrict__ iid,
                                int* __restrict__ rowstart, int* __restrict__ fill,
                                int* __restrict__ counter, int* __restrict__ widx,
                                const float* __restrict__ w2,
                                const float* __restrict__ att2s, const float* __restrict__ att2d,
                                float* __restrict__ qs, float* __restrict__ qd) {
  int blk = blockIdx.x;
  if (blk == (NN + 255) / 256) {
    int k = threadIdx.x;  // 0..255
    float s = 0.f, d = 0.f;
#pragma unroll 4
    for (int j = 0; j < DD; j++) {
      float w = w2[(size_t)j * 256 + k];
      s += att2s[j] * w;
      d += att2d[j] * w;
    }
    qs[k] = s;
    qd[k] = d;
    return;
  }
  int v = blk * 256 + threadIdx.x;
  if (v < BB) widx[v] = winner[iid[v]];
  if (v >= NN) return;
  int s = atomicAdd(counter, deg[v]);
  rowstart[v] = s;
  fill[v] = s;
}

// conv1 aggregation: 2-edges/iter, 32 lanes x 8 channels each, 16B Hb loads.
__global__ __launch_bounds__(256) void conv1_agg_kernel(
    const int* __restrict__ col, const int* __restrict__ rowstart,
    const int* __restrict__ deg, const unsigned short* __restrict__ Hb,
    const int* __restrict__ map, const unsigned char* __restrict__ needed,
    const float* __restrict__ a1s, const float* __restrict__ a1d,
    const float* __restrict__ bias,
    const float* __restrict__ qs, const float* __restrict__ qd,
    unsigned short* __restrict__ x1b, float* __restrict__ a2s, float* __restrict__ a2d) {
  int v = blockIdx.x * 4 + (threadIdx.x >> 6);
  int lane = threadIdx.x & 63;
  if (!needed[v]) return;
  int half = lane >> 5;     // which edge of the pair this lane processes
  int sub = lane & 31;      // channel group: ch = sub*8 .. +7
  int chead = sub >> 4;     // head of my channels
  int d = deg[v], s0 = rowstart[v];
  float2 adv = *reinterpret_cast<const float2*>(&a1d[(size_t)v * 2]);
  float acc[8] = {};
  float den;
  if (d <= 64) {
    bool act = lane < d;
    int ci = act ? col[s0 + lane] : 0;
    float2 asv = make_float2(0.f, 0.f);
    int ri = -1;
    if (act) {
      asv = *reinterpret_cast<const float2*>(&a1s[(size_t)ci * 2]);
      ri = map[ci];
    }
    float al0 = act ? lrelu(asv.x + adv.x) : -1e30f;
    float al1 = act ? lrelu(asv.y + adv.y) : -1e30f;
    float m0 = al0, m1 = al1;
#pragma unroll
    for (int o = 1; o < 64; o <<= 1) {
      m0 = fmaxf(m0, __shfl_xor(m0, o));
      m1 = fmaxf(m1, __shfl_xor(m1, o));
    }
    float ex0 = act ? __expf(al0 - m0) : 0.f;
    float ex1 = act ? __expf(al1 - m1) : 0.f;
    float cs0 = ex0, cs1 = ex1;
#pragma unroll
    for (int o = 1; o < 64; o <<= 1) {
      cs0 += __shfl_xor(cs0, o);
      cs1 += __shfl_xor(cs1, o);
    }
    den = chead ? cs1 : cs0;
    int nIt = (d + 1) >> 1;
    for (int i2 = 0; i2 < nIt; i2++) {
      int s = 2 * i2 + half;
      int r = __shfl(ri, s);              // lanes >= d carry ri=-1
      float e0 = __shfl(ex0, s), e1 = __shfl(ex1, s);
      float ex = chead ? e1 : e0;
      if (r >= 0) {
        u16x8 hv = *reinterpret_cast<const u16x8*>(&Hb[((size_t)r << 8) + (sub << 3)]);
#pragma unroll
        for (int k = 0; k < 8; k++) acc[k] += ex * bf2f(hv[k]);
      }
    }
  } else {
    float m0 = -1e30f, m1 = -1e30f, den0 = 0.f, den1 = 0.f;
    for (int c0 = 0; c0 < d; c0 += 64) {
      int i = c0 + lane;
      bool act = i < d;
      int ci = act ? col[s0 + i] : 0;
      float2 asv = make_float2(0.f, 0.f);
      int ri = -1;
      if (act) {
        asv = *reinterpret_cast<const float2*>(&a1s[(size_t)ci * 2]);
        ri = map[ci];
      }
      float al0 = act ? lrelu(asv.x + adv.x) : -1e30f;
      float al1 = act ? lrelu(asv.y + adv.y) : -1e30f;
      float cm0 = al0, cm1 = al1;
#pragma unroll
      for (int o = 1; o < 64; o <<= 1) {
        cm0 = fmaxf(cm0, __shfl_xor(cm0, o));
        cm1 = fmaxf(cm1, __shfl_xor(cm1, o));
      }
      float nm0 = fmaxf(m0, cm0), nm1 = fmaxf(m1, cm1);
      float ex0 = act ? __expf(al0 - nm0) : 0.f;
      float ex1 = act ? __expf(al1 - nm1) : 0.f;
      float s0f = __expf(m0 - nm0), s1f = __expf(m1 - nm1);
      float cs0 = ex0, cs1 = ex1;
#pragma unroll
      for (int o = 1; o < 64; o <<= 1) {
        cs0 += __shfl_xor(cs0, o);
        cs1 += __shfl_xor(cs1, o);
      }
      den0 = den0 * s0f + cs0;
      den1 = den1 * s1f + cs1;
      float sc = chead ? s1f : s0f;
#pragma unroll
      for (int k = 0; k < 8; k++) acc[k] *= sc;
      int n = min(64, d - c0);
      int nIt = (n + 1) >> 1;
      for (int i2 = 0; i2 < nIt; i2++) {
        int s = 2 * i2 + half;
        int r = __shfl(ri, s);
        float e0 = __shfl(ex0, s), e1 = __shfl(ex1, s);
        float ex = chead ? e1 : e0;
        if (r >= 0) {
          u16x8 hv = *reinterpret_cast<const u16x8*>(&Hb[((size_t)r << 8) + (sub << 3)]);
#pragma unroll
          for (int k = 0; k < 8; k++) acc[k] += ex * bf2f(hv[k]);
        }
      }
      m0 = nm0; m1 = nm1;
    }
    den = chead ? den1 : den0;
  }
  // merge the two edge-halves (lane <-> lane^32 hold same channels)
#pragma unroll
  for (int k = 0; k < 8; k++) acc[k] += __shfl_xor(acc[k], 32);
  float inv = 1.f / den;
  float o[8];
  float4 b4a = *reinterpret_cast<const float4*>(&bias[sub << 3]);
  float4 b4b = *reinterpret_cast<const float4*>(&bias[(sub << 3) + 4]);
  float bb[8] = {b4a.x, b4a.y, b4a.z, b4a.w, b4b.x, b4b.y, b4b.z, b4b.w};
#pragma unroll
  for (int k = 0; k < 8; k++) {
    float t = fmaf(acc[k], inv, bb[k]);
    o[k] = t > 0.f ? t : __expf(t) - 1.f;
  }
  // store bf16 x1 row: lane writes its half's 4-channel slice
  ushort4 st;
  st.x = f2bf_rne(o[half * 4 + 0]); st.y = f2bf_rne(o[half * 4 + 1]);
  st.z = f2bf_rne(o[half * 4 + 2]); st.w = f2bf_rne(o[half * 4 + 3]);
  *reinterpret_cast<ushort4*>(&x1b[((size_t)v << 8) + (sub << 3) + half * 4]) = st;
  // fused conv2 scores (halves duplicate; reduce within 32 lanes)
  float ps = 0.f, pd = 0.f;
#pragma unroll
  for (int k = 0; k < 8; k++) {
    ps += o[k] * qs[(sub << 3) + k];
    pd += o[k] * qd[(sub << 3) + k];
  }
#pragma unroll
  for (int of = 1; of < 32; of <<= 1) { ps += __shfl_xor(ps, of); pd += __shfl_xor(pd, of); }
  if (lane == 0) { a2s[v] = ps; a2d[v] = pd; }
}

// conv2 aggregation: rep tasks only; 2-edges/iter, 16B x1b loads.
__global__ __launch_bounds__(256) void conv2_agg_kernel(
    const int* __restrict__ uid, const int* __restrict__ iid,
    const int* __restrict__ col, const int* __restrict__ rowstart,
    const int* __restrict__ deg, const int* __restrict__ map,
    const unsigned short* __restrict__ x1b,
    const float* __restrict__ a2s, const float* __restrict__ a2d,
    float* __restrict__ agg) {
  int t = blockIdx.x * 4 + (threadIdx.x >> 6);
  int lane = threadIdx.x & 63;
  int v = (t < BB) ? uid[t] : NU + iid[t - BB];
  if (map[v] != t) return;  // duplicates gather the rep's row via map in the ph GEMM
  int half = lane >> 5, sub = lane & 31;
  int d = deg[v], s0 = rowstart[v];
  float ad = a2d[v];
  float acc[8] = {};
  float den;
  if (d <= 64) {
    bool act = lane < d;
    int ci = act ? col[s0 + lane] : 0;
    float as = act ? a2s[ci] : 0.f;
    float al = act ? lrelu(as + ad) : -1e30f;
    float m = al;
#pragma unroll
    for (int o = 1; o < 64; o <<= 1) m = fmaxf(m, __shfl_xor(m, o));
    float ex = act ? __expf(al - m) : 0.f;
    float cs = ex;
#pragma unroll
    for (int o = 1; o < 64; o <<= 1) cs += __shfl_xor(cs, o);
    den = cs;
    int nIt = (d + 1) >> 1;
    for (int i2 = 0; i2 < nIt; i2++) {
      int s = 2 * i2 + half;
      int r = __shfl(ci, s);
      float e = __shfl(ex, s);   // lanes >= d carry ex=0
      u16x8 hv = *reinterpret_cast<const u16x8*>(&x1b[((size_t)r << 8) + (sub << 3)]);
#pragma unroll
      for (int k = 0; k < 8; k++) acc[k] += e * bf2f(hv[k]);
    }
  } else {
    float m = -1e30f; den = 0.f;
    for (int c0 = 0; c0 < d; c0 += 64) {
      int i = c0 + lane;
      bool act = i < d;
      int ci = act ? col[s0 + i] : 0;
      float as = act ? a2s[ci] : 0.f;
      float al = act ? lrelu(as + ad) : -1e30f;
      float cm = al;
#pragma unroll
      for (int o = 1; o < 64; o <<= 1) cm = fmaxf(cm, __shfl_xor(cm, o));
      float nm = fmaxf(m, cm);
      float ex = act ? __expf(al - nm) : 0.f;
      float sf = __expf(m - nm);
      float cs = ex;
#pragma unroll
      for (int o = 1; o < 64; o <<= 1) cs += __shfl_xor(cs, o);
      den = den * sf + cs;
#pragma unroll
      for (int k = 0; k < 8; k++) acc[k] *= sf;
      int n = min(64, d - c0);
      int nIt = (n + 1) >> 1;
      for (int i2 = 0; i2 < nIt; i2++) {
        int s = 2 * i2 + half;
        int r = __shfl(ci, s);
        float e = __shfl(ex, s);
        u16x8 hv = *reinterpret_cast<const u16x8*>(&x1b[((size_t)r << 8) + (sub << 3)]);
#pragma unroll
        for (int k = 0; k < 8; k++) acc[k] += e * bf2f(hv[k]);
      }
      m = nm;
    }
  }
#pragma unroll
  for (int k = 0; k < 8; k++) acc[k] += __shfl_xor(acc[k], 32);
  float inv = 1.f / den;
  float4 st;
  st.x = acc[half * 4 + 0] * inv; st.y = acc[half * 4 + 1] * inv;
  st.z = acc[half * 4 + 2] * inv; st.w = acc[half * 4 + 3] * inv;
  *reinterpret_cast<float4*>(&agg[((size_t)t << 8) + (sub << 3) + half * 4]) = st;
}

__global__ __launch_bounds__(256) void final_kernel(
    const float* __restrict__ ph, const float* __restrict__ w2,
    const float* __restrict__ b2, float* __restrict__ out) {
  int b = blockIdx.x * 4 + (threadIdx.x >> 6);
  int lane = threadIdx.x & 63;
  float2 hv = *reinterpret_cast<const float2*>(&ph[((size_t)b << 7) + (lane << 1)]);
  float2 wv = *reinterpret_cast<const float2*>(&w2[lane << 1]);
  float s = hv.x * wv.x + hv.y * wv.y;
  for (int o = 1; o < 64; o <<= 1) s += __shfl_xor(s, o);
  if (lane == 0) out[b] = s + b2[0];
}

// ---------------- launcher ----------------
extern "C" void kernel_launch(void* const* d_in, const int* in_sizes, int n_in,
                              void* d_out, int out_size, void* d_ws, size_t ws_size,
                              hipStream_t stream) {
  const int* uid = (const int*)d_in[0];
  const int* iid = (const int*)d_in[1];
  const float* content = (const float*)d_in[2];
  const int* ei = (const int*)d_in[3];
  const float* uemb = (const float*)d_in[4];
  const float* iemb = (const float*)d_in[5];
  const float* wc = (const float*)d_in[6];
  const float* bc = (const float*)d_in[7];
  const float* w1 = (const float*)d_in[8];
  const float* att1s = (const float*)d_in[9];
  const float* att1d = (const float*)d_in[10];
  const float* b1 = (const float*)d_in[11];
  const float* w2 = (const float*)d_in[12];
  const float* att2s = (const float*)d_in[13];
  const float* att2d = (const float*)d_in[14];
  const float* b2c = (const float*)d_in[15];
  const float* pw1 = (const float*)d_in[16];
  const float* pb1 = (const float*)d_in[17];
  const float* pw2 = (const float*)d_in[18];
  const float* pb2 = (const float*)d_in[19];
  float* out = (float*)d_out;
  char* ws = (char*)d_ws;

  size_t off = 0;
  auto alloc = [&](size_t bytes) {
    size_t o = off;
    off += (bytes + 255) & ~(size_t)255;
    return o;
  };
  size_t o_winner  = alloc(NI * 4);
  size_t o_map     = alloc(NN * 4);
  size_t o_a1s     = alloc((size_t)NN * 2 * 4);
  size_t o_a1d     = alloc((size_t)NN * 2 * 4);
  size_t o_deg     = alloc(NN * 4);
  size_t o_rs      = alloc(NN * 4);
  size_t o_fill    = alloc(NN * 4);
  size_t o_cnt     = alloc(4);
  size_t o_needed  = alloc(NN);
  size_t o_col     = alloc((size_t)ET * 4);
  size_t o_a2s     = alloc(NN * 4);
  size_t o_a2d     = alloc(NN * 4);
  size_t o_qs      = alloc(256 * 4);
  size_t o_qd      = alloc(256 * 4);
  size_t o_widx    = alloc(BB * 4);
  // split weights (bf16 hi/lo)
  size_t o_wch = alloc(65536 * 2),  o_wcl = alloc(65536 * 2);
  size_t o_w1h = alloc(65536 * 2),  o_w1l = alloc(65536 * 2);
  size_t o_w2h = alloc(32768 * 2),  o_w2l = alloc(32768 * 2);
  size_t o_p1h = alloc(49152 * 2),  o_p1l = alloc(49152 * 2);
  // region R1 (25.2MB): Xa f32 (16.78M) | Hb bf16 (8.39M)
  size_t o_r1    = alloc(16777216 + 8388608);
  size_t o_xa    = o_r1;
  size_t o_hb    = o_r1 + 16777216;
  size_t o_agg   = o_r1;
  size_t o_out2c = o_r1 + 16777216;
  size_t o_ph    = o_r1;
  // region R2: x1 bf16 [NN,256]
  size_t o_x1b   = alloc((size_t)NN * 256 * 2);
  (void)ws_size; (void)in_sizes; (void)n_in; (void)out_size;

  int*   winner = (int*)(ws + o_winner);
  int*   map    = (int*)(ws + o_map);
  float* a1s    = (float*)(ws + o_a1s);
  float* a1d    = (float*)(ws + o_a1d);
  int*   deg    = (int*)(ws + o_deg);
  int*   rs     = (int*)(ws + o_rs);
  int*   fill   = (int*)(ws + o_fill);
  int*   cnt    = (int*)(ws + o_cnt);
  unsigned char* needed = (unsigned char*)(ws + o_needed);
  int*   col    = (int*)(ws + o_col);
  float* a2s    = (float*)(ws + o_a2s);
  float* a2d    = (float*)(ws + o_a2d);
  float* qs     = (float*)(ws + o_qs);
  float* qd     = (float*)(ws + o_qd);
  int*   widx   = (int*)(ws + o_widx);
  unsigned short* wch = (unsigned short*)(ws + o_wch);
  unsigned short* wcl = (unsigned short*)(ws + o_wcl);
  unsigned short* w1h = (unsigned short*)(ws + o_w1h);
  unsigned short* w1l = (unsigned short*)(ws + o_w1l);
  unsigned short* w2h = (unsigned short*)(ws + o_w2h);
  unsigned short* w2l = (unsigned short*)(ws + o_w2l);
  unsigned short* p1h = (unsigned short*)(ws + o_p1h);
  unsigned short* p1l = (unsigned short*)(ws + o_p1l);
  float* Xa     = (float*)(ws + o_xa);
  unsigned short* Hb = (unsigned short*)(ws + o_hb);
  float* agg    = (float*)(ws + o_agg);
  float* out2c  = (float*)(ws + o_out2c);
  float* ph     = (float*)(ws + o_ph);
  unsigned short* x1b = (unsigned short*)(ws + o_x1b);

  // merged memsets over adjacent regions (pad bytes are don't-care)
  hipMemsetAsync(ws + o_winner, 0xFF, o_map - o_winner + (size_t)NN * 4, stream);   // winner|map
  hipMemsetAsync(ws + o_a1s, 0, o_a1d - o_a1s + (size_t)NN * 2 * 4, stream);         // a1s|a1d (atomic targets)
  hipMemsetAsync(ws + o_deg, 0, o_needed - o_deg + NN, stream);                      // deg|rs|fill|cnt|needed

  // mega-setup: edge deg+winner | weight split | Xa emb parts + map
  setup_kernel<<<EB + SPLB + XAB, 256, 0, stream>>>(
      ei, uid, iid, deg, winner,
      wc, wch, wcl, w1, w1h, w1l, w2, w2h, w2l, pw1, p1h, p1l,
      uemb, iemb, Xa, map);
  rowstart_kernel<<<(NN + 255) / 256 + 1, 256, 0, stream>>>(
      deg, winner, iid, rs, fill, cnt, widx, w2, att2s, att2d, qs, qd);
  // {content section of Xa via gather-A GEMM} + {CSR fill + needed-mark}, one launch
  cembfill_kernel<<<GEMMB + EB, 256, 0, stream>>>(
      wch, wcl, bc, Xa + (size_t)BB * 256 + 128, widx, content,
      ei, fill, col, map, needed);
  // Hb = bf16(Xa @ W1^T), with fused a1 score atomics
  {
    dim3 g(NTASK / 64, 256 / 64);
    gemm_mfma<0, 1><<<g, 256, 0, stream>>>(
        Xa, w1h, w1l, nullptr, nullptr, Hb, 256,
        NTASK, 256, 256, 0, uid, iid, map, nullptr, nullptr,
        att1s, att1d, a1s, a1d);
  }
  conv1_agg_kernel<<<NN / 4, 256, 0, stream>>>(col, rs, deg, Hb, map, needed,
                                               a1s, a1d, b1, qs, qd, x1b, a2s, a2d);
  conv2_agg_kernel<<<NTASK / 4, 256, 0, stream>>>(uid, iid, col, rs, deg, map,
                                                  x1b, a2s, a2d, agg);
  // out2c = agg @ W2^T + b2c (non-rep rows are garbage, never read downstream)
  {
    dim3 g(NTASK / 64, DD / 64);
    gemm_mfma<0, 0><<<g, 256, 0, stream>>>(
        agg, w2h, w2l, b2c, out2c, nullptr, 128,
        NTASK, DD, 256, 0, nullptr, nullptr, nullptr, nullptr, nullptr,
        nullptr, nullptr, nullptr, nullptr);
  }
  // ph = relu([uemb[uid] | out2c[map[item]] | out2c[map[user]]] @ pw1^T + pb1)
  {
    dim3 g(BB / 64, DD / 64);
    gemm_mfma<1, 0><<<g, 256, 0, stream>>>(
        nullptr, p1h, p1l, pb1, ph, nullptr, 128,
        BB, DD, 384, 1, uid, iid, map, uemb, out2c,
        nullptr, nullptr, nullptr, nullptr);
  }
  final_kernel<<<BB / 4, 256, 0, stream>>>(ph, pw2, pb2, out);
}